// Round 2
// baseline (1303.806 us; speedup 1.0000x reference)
//
#include <hip/hip_runtime.h>
#include <hip/hip_bf16.h>

#define B_ 4
#define L_ 4096
#define DM_ 1024
#define NH_ 8
#define DK_ 128
#define NR_ 4
#define NC_ 64
#define NEGV -1.0e9f
#define SELFP -1.0e5f
#define SQRTDK 11.313708498984761f
#define TAU 1.0e-3f
#define FCAP 524288

typedef __attribute__((ext_vector_type(8))) short short8;
typedef __attribute__((ext_vector_type(4))) float f32x4;

__device__ __forceinline__ unsigned short f2bf(float x) {
  unsigned u = __float_as_uint(x);
  u += 0x7FFFu + ((u >> 16) & 1u);
  return (unsigned short)(u >> 16);
}
__device__ __forceinline__ float bf2f(unsigned short h) {
  return __uint_as_float(((unsigned)h) << 16);
}
__device__ __forceinline__ float wlo(unsigned w) { return __uint_as_float(w << 16); }
__device__ __forceinline__ float whi(unsigned w) { return __uint_as_float(w & 0xFFFF0000u); }
__device__ __forceinline__ unsigned packbf(float a, float b) {
  return (unsigned)f2bf(a) | (((unsigned)f2bf(b)) << 16);
}
// truncation split: hi = upper 16 bits, residual lo = x - hi (|lo| <= 2^-8|x|)
__device__ __forceinline__ unsigned packhi(float a, float b) {
  return (__float_as_uint(a) >> 16) | (__float_as_uint(b) & 0xFFFF0000u);
}
__device__ __forceinline__ float resid(float a) {
  return a - __uint_as_float(__float_as_uint(a) & 0xFFFF0000u);
}

// ---------------- weight transpose+convert: Wt[n][k] bf16 = W[k][n] ----------
__global__ __launch_bounds__(256) void cvtw_k(const float* __restrict__ W,
                                              unsigned short* __restrict__ Wt) {
  __shared__ float tile[64][65];
  const int t = threadIdx.x;
  const int bx = blockIdx.x & 15, by = blockIdx.x >> 4;
  const int c = t & 63, r4 = t >> 6;
#pragma unroll
  for (int i = 0; i < 16; i++) {
    int r = r4 * 16 + i;
    tile[r][c] = W[(size_t)(by * 64 + r) * DM_ + bx * 64 + c];
  }
  __syncthreads();
#pragma unroll
  for (int i = 0; i < 16; i++) {
    int r = r4 * 16 + i;
    Wt[(size_t)(bx * 64 + r) * DM_ + by * 64 + c] = f2bf(tile[c][r]);
  }
}

// ---------------- weight transpose+SPLIT: Whi/Wlo[n][k] bf16 ----------------
// hi = round-nearest bf16(W), lo = round-nearest bf16(W - hi)
__global__ __launch_bounds__(256) void cvtw2_k(const float* __restrict__ W,
                                               unsigned short* __restrict__ Whi,
                                               unsigned short* __restrict__ Wlo) {
  __shared__ float tile[64][65];
  const int t = threadIdx.x;
  const int bx = blockIdx.x & 15, by = blockIdx.x >> 4;
  const int c = t & 63, r4 = t >> 6;
#pragma unroll
  for (int i = 0; i < 16; i++) {
    int r = r4 * 16 + i;
    tile[r][c] = W[(size_t)(by * 64 + r) * DM_ + bx * 64 + c];
  }
  __syncthreads();
#pragma unroll
  for (int i = 0; i < 16; i++) {
    int r = r4 * 16 + i;
    float v = tile[c][r];
    unsigned short h = f2bf(v);
    float lo = v - bf2f(h);
    size_t o = (size_t)(bx * 64 + r) * DM_ + by * 64 + c;
    Whi[o] = h;
    Wlo[o] = f2bf(lo);
  }
}

// ---------------- Wproj precompute: Wp[h][r][n][k] = sum_d wq[k][h*128+d]*rot[d][r][n]
__global__ __launch_bounds__(256) void wproj_k(const float* __restrict__ W,
                                               const float* __restrict__ rot,
                                               float* __restrict__ Wp,
                                               int* __restrict__ cnt) {
  __shared__ float rs[128][32];
  const int t = threadIdx.x;
  const int h = blockIdx.x >> 2, r = blockIdx.x & 3;
  if (blockIdx.x == 0 && t == 0) *cnt = 0;
  for (int i = t; i < 4096; i += 256) {
    int d = i >> 5, n = i & 31;
    rs[d][n] = rot[(size_t)d * 128 + r * 32 + n];
  }
  __syncthreads();
  const int n = t & 31, kq = t >> 5;
  for (int j = 0; j < 128; j++) {
    int k = kq * 128 + j;
    const float* wrow = W + (size_t)k * DM_ + h * 128;
    float s = 0.f;
#pragma unroll
    for (int d = 0; d < 128; d += 4) {
      float4 wv = *(const float4*)(wrow + d);
      s = fmaf(wv.x, rs[d][n],
          fmaf(wv.y, rs[d + 1][n], fmaf(wv.z, rs[d + 2][n], fmaf(wv.w, rs[d + 3][n], s))));
    }
    Wp[((size_t)(h * 4 + r) * 32 + n) * 1024 + k] = s;
  }
}

// ---------------- split-bf16 MFMA GEMM for q (3-term fp32 emulation) --------
// C[p][q] = sum_k W[p][k]*X[q][k]; W pre-split (hi/lo bf16), X split on the fly.
// out: qbuf f32 (b,h,l,d) + bias. 16B-granule XOR swizzle kills 8-way ds_read conflicts.
__global__ __launch_bounds__(256) void gemm_qs(const unsigned short* __restrict__ Whi,
                                               const unsigned short* __restrict__ Wlo,
                                               const float* __restrict__ X,
                                               const float* __restrict__ bias,
                                               float* __restrict__ outF) {
  __shared__ __align__(16) unsigned short Ph[128 * 32];
  __shared__ __align__(16) unsigned short Pl[128 * 32];
  __shared__ __align__(16) unsigned short Qh[128 * 32];
  __shared__ __align__(16) unsigned short Ql[128 * 32];
  __shared__ float bias_s[128];
  const int t = threadIdx.x;
  const int bi = blockIdx.x;
  const int pb = (bi & 7) << 7;   // output-dim block (head)
  const int qb = (bi >> 3) << 7;  // token block
  if (t < 128) bias_s[t] = bias[pb + t];
  const int srow = t >> 1, shalf = t & 1;
  const unsigned short* Ph_p = Whi + (size_t)(pb + srow) * DM_ + shalf * 16;
  const unsigned short* Pl_p = Wlo + (size_t)(pb + srow) * DM_ + shalf * 16;
  const float* Xf = X + (size_t)(qb + srow) * DM_ + shalf * 16;
  const int lane = t & 63, wid = t >> 6;
  const int lm = lane & 15, quad = lane >> 4;
  const int prw = (wid & 1) << 6, qcw = (wid >> 1) << 6;
  const int sg = (quad ^ (lm & 3)) << 3;  // swizzled granule offset for frag reads
  f32x4 acc[4][4];
#pragma unroll
  for (int i = 0; i < 4; i++)
#pragma unroll
    for (int j = 0; j < 4; j++) acc[i][j] = (f32x4){0.f, 0.f, 0.f, 0.f};
  uint4 phA, phB, plA, plB, qhA, qhB, qlA, qlB;
  {
    phA = *(const uint4*)(Ph_p);
    phB = *(const uint4*)(Ph_p + 8);
    plA = *(const uint4*)(Pl_p);
    plB = *(const uint4*)(Pl_p + 8);
    float4 f0 = *(const float4*)(Xf), f1 = *(const float4*)(Xf + 4);
    float4 f2 = *(const float4*)(Xf + 8), f3 = *(const float4*)(Xf + 12);
    qhA.x = packhi(f0.x, f0.y); qhA.y = packhi(f0.z, f0.w);
    qhA.z = packhi(f1.x, f1.y); qhA.w = packhi(f1.z, f1.w);
    qhB.x = packhi(f2.x, f2.y); qhB.y = packhi(f2.z, f2.w);
    qhB.z = packhi(f3.x, f3.y); qhB.w = packhi(f3.z, f3.w);
    qlA.x = packbf(resid(f0.x), resid(f0.y)); qlA.y = packbf(resid(f0.z), resid(f0.w));
    qlA.z = packbf(resid(f1.x), resid(f1.y)); qlA.w = packbf(resid(f1.z), resid(f1.w));
    qlB.x = packbf(resid(f2.x), resid(f2.y)); qlB.y = packbf(resid(f2.z), resid(f2.w));
    qlB.z = packbf(resid(f3.x), resid(f3.y)); qlB.w = packbf(resid(f3.z), resid(f3.w));
  }
  const int sw = srow & 3, g0 = shalf * 2;
  const int d0s = srow * 32 + ((g0 ^ sw) << 3);
  const int d1s = srow * 32 + (((g0 + 1) ^ sw) << 3);
  for (int kb = 0; kb < 32; ++kb) {
    __syncthreads();
    *(uint4*)&Ph[d0s] = phA; *(uint4*)&Ph[d1s] = phB;
    *(uint4*)&Pl[d0s] = plA; *(uint4*)&Pl[d1s] = plB;
    *(uint4*)&Qh[d0s] = qhA; *(uint4*)&Qh[d1s] = qhB;
    *(uint4*)&Ql[d0s] = qlA; *(uint4*)&Ql[d1s] = qlB;
    __syncthreads();
    if (kb < 31) {
      int ko = (kb + 1) * 32;
      phA = *(const uint4*)(Ph_p + ko);
      phB = *(const uint4*)(Ph_p + ko + 8);
      plA = *(const uint4*)(Pl_p + ko);
      plB = *(const uint4*)(Pl_p + ko + 8);
      const float* xp = Xf + ko;
      float4 f0 = *(const float4*)(xp), f1 = *(const float4*)(xp + 4);
      float4 f2 = *(const float4*)(xp + 8), f3 = *(const float4*)(xp + 12);
      qhA.x = packhi(f0.x, f0.y); qhA.y = packhi(f0.z, f0.w);
      qhA.z = packhi(f1.x, f1.y); qhA.w = packhi(f1.z, f1.w);
      qhB.x = packhi(f2.x, f2.y); qhB.y = packhi(f2.z, f2.w);
      qhB.z = packhi(f3.x, f3.y); qhB.w = packhi(f3.z, f3.w);
      qlA.x = packbf(resid(f0.x), resid(f0.y)); qlA.y = packbf(resid(f0.z), resid(f0.w));
      qlA.z = packbf(resid(f1.x), resid(f1.y)); qlA.w = packbf(resid(f1.z), resid(f1.w));
      qlB.x = packbf(resid(f2.x), resid(f2.y)); qlB.y = packbf(resid(f2.z), resid(f2.w));
      qlB.z = packbf(resid(f3.x), resid(f3.y)); qlB.w = packbf(resid(f3.z), resid(f3.w));
    }
    short8 ph[4], pl[4], qh[4], ql[4];
#pragma unroll
    for (int ti = 0; ti < 4; ti++) {
      int ro = (prw + ti * 16 + lm) * 32 + sg;
      ph[ti] = *(const short8*)&Ph[ro];
      pl[ti] = *(const short8*)&Pl[ro];
    }
#pragma unroll
    for (int tj = 0; tj < 4; tj++) {
      int ro = (qcw + tj * 16 + lm) * 32 + sg;
      qh[tj] = *(const short8*)&Qh[ro];
      ql[tj] = *(const short8*)&Ql[ro];
    }
#pragma unroll
    for (int ti = 0; ti < 4; ti++)
#pragma unroll
      for (int tj = 0; tj < 4; tj++) {
        f32x4 a = acc[ti][tj];
        a = __builtin_amdgcn_mfma_f32_16x16x32_bf16(ph[ti], qh[tj], a, 0, 0, 0);
        a = __builtin_amdgcn_mfma_f32_16x16x32_bf16(ph[ti], ql[tj], a, 0, 0, 0);
        a = __builtin_amdgcn_mfma_f32_16x16x32_bf16(pl[ti], qh[tj], a, 0, 0, 0);
        acc[ti][tj] = a;
      }
  }
  const int head = bi & 7;
#pragma unroll
  for (int tj = 0; tj < 4; tj++) {
    int mm = qb + qcw + tj * 16 + lm;
    int b = mm >> 12, l = mm & 4095;
    float* op = outF + ((size_t)(b * NH_ + head) * L_ + l) * DK_;
#pragma unroll
    for (int ti = 0; ti < 4; ti++) {
      int d0 = prw + ti * 16 + quad * 4;
      float4 w;
      w.x = acc[ti][tj][0] + bias_s[d0];
      w.y = acc[ti][tj][1] + bias_s[d0 + 1];
      w.z = acc[ti][tj][2] + bias_s[d0 + 2];
      w.w = acc[ti][tj][3] + bias_s[d0 + 3];
      *(float4*)(op + d0) = w;
    }
  }
}

// ---------------- bf16 MFMA GEMM ----------------
// C[p][q] = sum_k P[p][k] * Q[q][k]  (both operands row-major-K)
// MODE 0: P = aout bf16 rows(m), Q = Wt_o rows(n); C[m][n] f32 + bias[n] -> outF
// MODE 2: P = Wt_v rows(n=d of head), Q = x2 f32 rows(m); C^T -> bf16 (b,h,l,d)
template <int MODE>
__global__ __launch_bounds__(256) void gemm_bf(const unsigned short* __restrict__ Pm,
                                               const void* __restrict__ Qv,
                                               const float* __restrict__ bias,
                                               float* __restrict__ outF,
                                               unsigned int* __restrict__ outW) {
  __shared__ __align__(16) unsigned short Ps[128 * 32];
  __shared__ __align__(16) unsigned short Qs[128 * 32];
  __shared__ float bias_s[128];
  const int t = threadIdx.x;
  const int bi = blockIdx.x;
  const int pb = (MODE == 0) ? ((bi >> 3) << 7) : ((bi & 7) << 7);
  const int qb = (MODE == 0) ? ((bi & 7) << 7) : ((bi >> 3) << 7);
  if (t < 128) bias_s[t] = bias[((MODE == 0) ? qb : pb) + t];
  const int srow = t >> 1, shalf = t & 1;
  const unsigned short* Pp = Pm + (size_t)(pb + srow) * DM_ + shalf * 16;
  const float* Qf = (const float*)Qv + (size_t)(qb + srow) * DM_ + shalf * 16;
  const unsigned short* Qh = (const unsigned short*)Qv + (size_t)(qb + srow) * DM_ + shalf * 16;
  const int lane = t & 63, wid = t >> 6;
  const int lm = lane & 15, quad = lane >> 4;
  const int prw = (wid & 1) << 6, qcw = (wid >> 1) << 6;
  f32x4 acc[4][4];
#pragma unroll
  for (int i = 0; i < 4; i++)
#pragma unroll
    for (int j = 0; j < 4; j++) acc[i][j] = (f32x4){0.f, 0.f, 0.f, 0.f};
  uint4 pA, pB, qA, qB;
  {  // preload kb=0
    pA = *(const uint4*)(Pp);
    pB = *(const uint4*)(Pp + 8);
    if (MODE == 2) {
      float4 f0 = *(const float4*)(Qf), f1 = *(const float4*)(Qf + 4);
      float4 f2 = *(const float4*)(Qf + 8), f3 = *(const float4*)(Qf + 12);
      qA.x = packbf(f0.x, f0.y); qA.y = packbf(f0.z, f0.w);
      qA.z = packbf(f1.x, f1.y); qA.w = packbf(f1.z, f1.w);
      qB.x = packbf(f2.x, f2.y); qB.y = packbf(f2.z, f2.w);
      qB.z = packbf(f3.x, f3.y); qB.w = packbf(f3.z, f3.w);
    } else {
      qA = *(const uint4*)(Qh);
      qB = *(const uint4*)(Qh + 8);
    }
  }
  const int sdst = srow * 32 + shalf * 16;
  for (int kb = 0; kb < 32; ++kb) {
    __syncthreads();
    *(uint4*)&Ps[sdst] = pA;
    *(uint4*)&Ps[sdst + 8] = pB;
    *(uint4*)&Qs[sdst] = qA;
    *(uint4*)&Qs[sdst + 8] = qB;
    __syncthreads();
    if (kb < 31) {
      int ko = (kb + 1) * 32;
      pA = *(const uint4*)(Pp + ko);
      pB = *(const uint4*)(Pp + ko + 8);
      if (MODE == 2) {
        const float* qp = Qf + ko;
        float4 f0 = *(const float4*)(qp), f1 = *(const float4*)(qp + 4);
        float4 f2 = *(const float4*)(qp + 8), f3 = *(const float4*)(qp + 12);
        qA.x = packbf(f0.x, f0.y); qA.y = packbf(f0.z, f0.w);
        qA.z = packbf(f1.x, f1.y); qA.w = packbf(f1.z, f1.w);
        qB.x = packbf(f2.x, f2.y); qB.y = packbf(f2.z, f2.w);
        qB.z = packbf(f3.x, f3.y); qB.w = packbf(f3.z, f3.w);
      } else {
        qA = *(const uint4*)(Qh + ko);
        qB = *(const uint4*)(Qh + ko + 8);
      }
    }
    short8 pf[4], qf[4];
#pragma unroll
    for (int ti = 0; ti < 4; ti++)
      pf[ti] = *(const short8*)&Ps[(prw + ti * 16 + lm) * 32 + quad * 8];
#pragma unroll
    for (int tj = 0; tj < 4; tj++)
      qf[tj] = *(const short8*)&Qs[(qcw + tj * 16 + lm) * 32 + quad * 8];
#pragma unroll
    for (int ti = 0; ti < 4; ti++)
#pragma unroll
      for (int tj = 0; tj < 4; tj++)
        acc[ti][tj] = __builtin_amdgcn_mfma_f32_16x16x32_bf16(pf[ti], qf[tj], acc[ti][tj], 0, 0, 0);
  }
  if (MODE == 0) {
#pragma unroll
    for (int ti = 0; ti < 4; ti++) {
      int m = pb + prw + ti * 16 + quad * 4;
#pragma unroll
      for (int tj = 0; tj < 4; tj++) {
        int nn = qcw + tj * 16 + lm;
        float bn = bias_s[nn];
        float* op = outF + (size_t)m * DM_ + qb + nn;
#pragma unroll
        for (int r = 0; r < 4; r++) op[(size_t)r * DM_] = acc[ti][tj][r] + bn;
      }
    }
  } else {
    const int head = bi & 7;
#pragma unroll
    for (int tj = 0; tj < 4; tj++) {
      int mm = qb + qcw + tj * 16 + lm;
      int b = mm >> 12, l = mm & 4095;
#pragma unroll
      for (int ti = 0; ti < 4; ti++) {
        int d0 = prw + ti * 16 + quad * 4;
        uint2 ov;
        ov.x = packbf(acc[ti][tj][0] + bias_s[d0], acc[ti][tj][1] + bias_s[d0 + 1]);
        ov.y = packbf(acc[ti][tj][2] + bias_s[d0 + 2], acc[ti][tj][3] + bias_s[d0 + 3]);
        *(uint2*)(outW + ((size_t)(b * NH_ + head) * L_ + l) * 64 + (d0 >> 1)) = ov;
      }
    }
  }
}

// ---------------- Hashing: argmax_n |q . rot| + near-tie flagging ----------
__global__ __launch_bounds__(256) void hash_k(const float* __restrict__ q,
                                              const float* __restrict__ rot,
                                              unsigned char* __restrict__ hout,
                                              int* __restrict__ cnt,
                                              int* __restrict__ flags) {
  __shared__ float qs[2][128];
  __shared__ float val[256];
  __shared__ float val2[256];
  __shared__ int vidx[256];
  const int t = threadIdx.x;
  const int bh = blockIdx.x >> 11;
  const int lp = blockIdx.x & 2047;
  const int lh = t >> 7;
  const int l = (lp << 1) + lh;
  const int sub = t & 127;  // r*32+n
  qs[lh][sub] = q[((size_t)bh * L_ + l) * DK_ + sub];
  __syncthreads();
  float p = 0.f;
  for (int d = 0; d < 128; d++) p = fmaf(qs[lh][d], rot[d * 128 + sub], p);
  const int n = sub & 31;
  val[t] = fabsf(p);
  val2[t] = -3.0e38f;
  vidx[t] = (p >= 0.f) ? n : (n + 32);
  __syncthreads();
#pragma unroll
  for (int off = 16; off > 0; off >>= 1) {
    if ((t & 31) < off) {
      float v1a = val[t], v2a = val2[t];
      int i1a = vidx[t];
      float v1b = val[t + off], v2b = val2[t + off];
      int i1b = vidx[t + off];
      if (v1b > v1a || (v1b == v1a && i1b < i1a)) {
        val[t] = v1b; vidx[t] = i1b; val2[t] = fmaxf(v1a, v2b);
      } else {
        val2[t] = fmaxf(v1b, v2a);
      }
    }
    __syncthreads();
  }
  if ((t & 31) == 0) {
    int r = sub >> 5;
    hout[((size_t)(bh * NR_ + r)) * L_ + l] = (unsigned char)vidx[t];
    if (val[t] - val2[t] < TAU) {
      int slot = atomicAdd(cnt, 1);
      if (slot < FCAP) flags[slot] = (((bh << 2) | r) << 12) | l;
    }
  }
}

// ---------------- exact f32 recompute of flagged (near-tie) hashes ---------
__global__ __launch_bounds__(256) void fixup_k(const int* __restrict__ cnt,
                                               const int* __restrict__ flags,
                                               const float* __restrict__ X,
                                               const float* __restrict__ Wp,
                                               unsigned char* __restrict__ hout) {
  __shared__ float xs[1024];
  __shared__ float pv[32];
  int nflag = *cnt;
  if (nflag > FCAP) nflag = FCAP;
  const int t = threadIdx.x;
  for (int i = blockIdx.x; i < nflag; i += gridDim.x) {
    int f = flags[i];
    int l = f & 4095, r = (f >> 12) & 3, bh = f >> 14;
    int b = bh >> 3, h = bh & 7;
    __syncthreads();  // protect xs/pv from previous iteration readers
    ((float4*)xs)[t] = ((const float4*)(X + ((size_t)b * L_ + l) * DM_))[t];
    __syncthreads();
    const int nn = t >> 3, kl = t & 7;
    const float* wrow = Wp + ((size_t)(h * 4 + r) * 32 + nn) * 1024 + kl * 4;
    float s = 0.f;
#pragma unroll 8
    for (int k0 = 0; k0 < 1024; k0 += 32) {
      float4 wv = *(const float4*)(wrow + k0);
      float4 xv = *(const float4*)(xs + k0 + kl * 4);
      s = fmaf(wv.x, xv.x, fmaf(wv.y, xv.y, fmaf(wv.z, xv.z, fmaf(wv.w, xv.w, s))));
    }
    s += __shfl_xor(s, 1);
    s += __shfl_xor(s, 2);
    s += __shfl_xor(s, 4);
    if (kl == 0) pv[nn] = s;
    __syncthreads();
    if (t == 0) {
      float bestv = -1.f;
      int besti = 0;
      for (int j = 0; j < 32; j++) {
        float p = pv[j];
        float ap = fabsf(p);
        int idx = (p >= 0.f) ? j : (j + 32);
        if (ap > bestv || (ap == bestv && idx < besti)) { bestv = ap; besti = idx; }
      }
      hout[((size_t)(bh * NR_ + r)) * L_ + l] = (unsigned char)besti;
    }
  }
}

// ---------------- Stable counting sort per (b,h,r) ----------------
__global__ __launch_bounds__(256) void sort_k(const unsigned char* __restrict__ hsh,
                                              int* __restrict__ sidx) {
  __shared__ unsigned char seg[256 * 64];
  __shared__ unsigned short grp[16 * 64];
  __shared__ int offs[64];
  __shared__ int tot[64];
  const int t = threadIdx.x;
  const int bhr = blockIdx.x;
  uint4 hv = ((const uint4*)(hsh + (size_t)bhr * L_))[t];
  unsigned hb[4] = {hv.x, hv.y, hv.z, hv.w};
  unsigned int* seg32 = (unsigned int*)seg;
#pragma unroll
  for (int i = 0; i < 16; i++) seg32[t * 16 + i] = 0;
  ((unsigned int*)grp)[t * 2] = 0;
  ((unsigned int*)grp)[t * 2 + 1] = 0;
  __syncthreads();
#pragma unroll
  for (int k = 0; k < 16; k++) {
    int h = (hb[k >> 2] >> ((k & 3) * 8)) & 0xFF;
    seg[t * 64 + h] = (unsigned char)(seg[t * 64 + h] + 1);
  }
  __syncthreads();
  {
    int h = t & 63;
    for (int g = (t >> 6); g < 16; g += 4) {
      int run = 0;
      for (int s = 0; s < 16; s++) {
        int idx = ((g << 4) + s) * 64 + h;
        int c = seg[idx];
        seg[idx] = (unsigned char)run;
        run += c;
      }
      grp[g * 64 + h] = (unsigned short)run;
    }
  }
  __syncthreads();
  if (t < 64) {
    int run = 0;
    for (int g = 0; g < 16; g++) {
      int c = grp[g * 64 + t];
      grp[g * 64 + t] = (unsigned short)run;
      run += c;
    }
    tot[t] = run;
  }
  __syncthreads();
  if (t == 0) {
    int run = 0;
    for (int h = 0; h < 64; h++) { offs[h] = run; run += tot[h]; }
  }
  __syncthreads();
  const int gbase = (t >> 4) * 64;
  int* outp = sidx + (size_t)bhr * L_;
#pragma unroll
  for (int k = 0; k < 16; k++) {
    int h = (hb[k >> 2] >> ((k & 3) * 8)) & 0xFF;
    int pos = offs[h] + grp[gbase + h] + seg[t * 64 + h];
    seg[t * 64 + h] = (unsigned char)(seg[t * 64 + h] + 1);
    outp[pos] = t * 16 + k;
  }
}

// ---------------- Chunked look-back attention (MFMA) ----------------
#define KSTR 136
__global__ __launch_bounds__(256) void attn_k(const float* __restrict__ q,
                                              const unsigned int* __restrict__ vwg,
                                              const int* __restrict__ sidx,
                                              float* __restrict__ lseG,
                                              unsigned int* __restrict__ oW) {
  __shared__ __align__(16) unsigned short R1[128 * KSTR];
  __shared__ __align__(16) unsigned short R2[64 * KSTR];
  __shared__ int idxs[128];
  __shared__ float rowsum[64];
  const int t = threadIdx.x;
  const int c = blockIdx.x & 63;
  const int bhr = blockIdx.x >> 6;
  const int bh = bhr >> 2;
  const int pc = (c + 63) & 63;
  if (t < 128) {
    int sp = (t < 64) ? (pc * 64 + t) : (c * 64 + t - 64);
    idxs[t] = sidx[(size_t)bhr * L_ + sp];
  }
  __syncthreads();
  {
    const int row = t >> 1, half = t & 1;
    const float4* qp = (const float4*)(q + ((size_t)bh * L_ + idxs[row]) * DK_ + half * 64);
    float4 f[16];
    float ss = 0.f;
#pragma unroll
    for (int u = 0; u < 16; u++) {
      f[u] = qp[u];
      ss = fmaf(f[u].x, f[u].x, fmaf(f[u].y, f[u].y, fmaf(f[u].z, f[u].z, fmaf(f[u].w, f[u].w, ss))));
    }
    ss += __shfl_xor(ss, 1);
    float rn = 1.f / (sqrtf(ss) + 1e-9f);
    unsigned short* kr = R1 + row * KSTR + half * 64;
#pragma unroll
    for (int u = 0; u < 8; u++) {
      uint4 w4;
      w4.x = packbf(f[2 * u].x * rn, f[2 * u].y * rn);
      w4.y = packbf(f[2 * u].z * rn, f[2 * u].w * rn);
      w4.z = packbf(f[2 * u + 1].x * rn, f[2 * u + 1].y * rn);
      w4.w = packbf(f[2 * u + 1].z * rn, f[2 * u + 1].w * rn);
      *(uint4*)(kr + u * 8) = w4;
    }
    if (row >= 64) {
      unsigned short* qr = R2 + (row - 64) * KSTR + half * 64;
#pragma unroll
      for (int u = 0; u < 8; u++) {
        uint4 w4;
        w4.x = packbf(f[2 * u].x, f[2 * u].y);
        w4.y = packbf(f[2 * u].z, f[2 * u].w);
        w4.z = packbf(f[2 * u + 1].x, f[2 * u + 1].y);
        w4.w = packbf(f[2 * u + 1].z, f[2 * u + 1].w);
        *(uint4*)(qr + u * 8) = w4;
      }
    }
  }
  __syncthreads();
  const int lane = t & 63, wv = t >> 6;
  const int m0 = wv * 16;
  const int lm = lane & 15, quad = lane >> 4;
  f32x4 acc[8];
  {
    short8 af[4];
#pragma unroll
    for (int ks = 0; ks < 4; ks++)
      af[ks] = *(const short8*)(R2 + (m0 + lm) * KSTR + ks * 32 + quad * 8);
#pragma unroll
    for (int n = 0; n < 8; n++) {
      f32x4 a = {0.f, 0.f, 0.f, 0.f};
#pragma unroll
      for (int ks = 0; ks < 4; ks++) {
        short8 bf = *(const short8*)(R1 + (n * 16 + lm) * KSTR + ks * 32 + quad * 8);
        a = __builtin_amdgcn_mfma_f32_16x16x32_bf16(af[ks], bf, a, 0, 0, 0);
      }
      acc[n] = a;
    }
  }
  {
    int qp4[4];
#pragma unroll
    for (int r = 0; r < 4; r++) qp4[r] = idxs[64 + m0 + quad * 4 + r];
#pragma unroll
    for (int n = 0; n < 8; n++) {
      int key = n * 16 + lm;
      int kp = idxs[key];
#pragma unroll
      for (int r = 0; r < 4; r++) {
        float s = acc[n][r] * (1.f / SQRTDK);
        s = (kp > qp4[r]) ? NEGV : ((kp == qp4[r]) ? SELFP : s);
        R2[(m0 + quad * 4 + r) * KSTR + key] = f2bf(s);
      }
    }
  }
  uint4 vv[8];
  {
    const int key = t >> 1, half = t & 1;
    const uint4* vp = (const uint4*)(vwg + ((size_t)bh * L_ + idxs[key]) * 64 + half * 32);
#pragma unroll
    for (int u = 0; u < 8; u++) vv[u] = vp[u];
  }
  {
    const int row = t >> 2, seg = t & 3;
    unsigned short* sp = R2 + row * KSTR + seg * 32;
    uint4 sv4[4];
    float m = -3.0e38f;
#pragma unroll
    for (int u = 0; u < 4; u++) {
      sv4[u] = *(uint4*)(sp + u * 8);
      unsigned wd[4] = {sv4[u].x, sv4[u].y, sv4[u].z, sv4[u].w};
#pragma unroll
      for (int cc = 0; cc < 4; cc++) {
        m = fmaxf(m, wlo(wd[cc]));
        m = fmaxf(m, whi(wd[cc]));
      }
    }
    m = fmaxf(m, __shfl_xor(m, 1));
    m = fmaxf(m, __shfl_xor(m, 2));
    float sum = 0.f;
#pragma unroll
    for (int u = 0; u < 4; u++) {
      unsigned wd[4] = {sv4[u].x, sv4[u].y, sv4[u].z, sv4[u].w};
      unsigned ow[4];
#pragma unroll
      for (int cc = 0; cc < 4; cc++) {
        float e0 = expf(wlo(wd[cc]) - m);
        float e1 = expf(whi(wd[cc]) - m);
        unsigned short b0 = f2bf(e0), b1 = f2bf(e1);
        sum += bf2f(b0) + bf2f(b1);
        ow[cc] = (unsigned)b0 | (((unsigned)b1) << 16);
      }
      uint4 o4;
      o4.x = ow[0]; o4.y = ow[1]; o4.z = ow[2]; o4.w = ow[3];
      *(uint4*)(sp + u * 8) = o4;
    }
    sum += __shfl_xor(sum, 1);
    sum += __shfl_xor(sum, 2);
    if (seg == 0) {
      rowsum[row] = sum;
      lseG[(size_t)bhr * L_ + idxs[64 + row]] = m + logf(sum);
    }
  }
  __syncthreads();
  {
    const int key = t >> 1, half = t & 1;
#pragma unroll
    for (int u = 0; u < 8; u++) {
      unsigned wd[4] = {vv[u].x, vv[u].y, vv[u].z, vv[u].w};
#pragma unroll
      for (int cc = 0; cc < 4; cc++) {
        int w = half * 32 + u * 4 + cc;
        R1[(2 * w) * KSTR + key] = (unsigned short)(wd[cc] & 0xFFFFu);
        R1[(2 * w + 1) * KSTR + key] = (unsigned short)(wd[cc] >> 16);
      }
    }
  }
  __syncthreads();
  f32x4 acc2[8];
  {
    short8 af[4];
#pragma unroll
    for (int ks = 0; ks < 4; ks++)
      af[ks] = *(const short8*)(R2 + (m0 + lm) * KSTR + ks * 32 + quad * 8);
#pragma unroll
    for (int n = 0; n < 8; n++) {
      f32x4 a = {0.f, 0.f, 0.f, 0.f};
#pragma unroll
      for (int ks = 0; ks < 4; ks++) {
        short8 bf = *(const short8*)(R1 + (n * 16 + lm) * KSTR + ks * 32 + quad * 8);
        a = __builtin_amdgcn_mfma_f32_16x16x32_bf16(af[ks], bf, a, 0, 0, 0);
      }
      acc2[n] = a;
    }
  }
  {
    float inv[4];
#pragma unroll
    for (int r = 0; r < 4; r++) inv[r] = 1.f / rowsum[m0 + quad * 4 + r];
#pragma unroll
    for (int n = 0; n < 8; n++)
#pragma unroll
      for (int r = 0; r < 4; r++)
        R2[(m0 + quad * 4 + r) * KSTR + n * 16 + lm] = f2bf(acc2[n][r] * inv[r]);
  }
  __syncthreads();
  {
    const int row = t >> 2, seg = t & 3;
    int l = idxs[64 + row];
    unsigned int* op = oW + ((size_t)bhr * L_ + l) * 64 + seg * 16;
    const unsigned short* rp = R2 + row * KSTR + seg * 32;
#pragma unroll
    for (int u = 0; u < 4; u++) *(uint4*)(op + u * 4) = *(const uint4*)(rp + u * 8);
  }
}

// ---------------- Round-softmax merge -> bf16 aout words ----------------
__global__ __launch_bounds__(256) void comb_k(const float* __restrict__ lse,
                                              const unsigned int* __restrict__ oW,
                                              unsigned int* __restrict__ aoutW) {
  size_t g = (size_t)blockIdx.x * 256 + threadIdx.x;
  int w = (int)(g & 63);
  int l = (int)((g >> 6) & 4095);
  int bh = (int)(g >> 18);
  float ls[4];
#pragma unroll
  for (int r = 0; r < 4; r++) ls[r] = lse[((size_t)(bh * 4 + r)) * L_ + l];
  float m = fmaxf(fmaxf(ls[0], ls[1]), fmaxf(ls[2], ls[3]));
  float wsum = 0.f, a0 = 0.f, a1 = 0.f;
#pragma unroll
  for (int r = 0; r < 4; r++) {
    float e = expf(ls[r] - m);
    wsum += e;
    unsigned ow = oW[(((size_t)(bh * 4 + r)) * L_ + l) * 64 + w];
    a0 = fmaf(e, wlo(ow), a0);
    a1 = fmaf(e, whi(ow), a1);
  }
  float inv = 1.f / wsum;
  int b = bh >> 3, h = bh & 7;
  // aout bf16 row-major [m][k] as words: m*512 + h*64 + w
  aoutW[((size_t)b * L_ + l) * 512 + h * 64 + w] = packbf(a0 * inv, a1 * inv);
}

// ---------------- LayerNorm + residual + x2 passthrough ----------------
__global__ __launch_bounds__(256) void ln_k(const float* __restrict__ a,
                                            const float* __restrict__ x1,
                                            const float* __restrict__ x2,
                                            const float* __restrict__ gamma,
                                            const float* __restrict__ beta,
                                            float* __restrict__ out) {
  __shared__ float red[256];
  __shared__ float red2[256];
  const int t = threadIdx.x;
  const size_t row = blockIdx.x;
  float4 av = *(const float4*)(a + row * DM_ + t * 4);
  red[t] = av.x + av.y + av.z + av.w;
  red2[t] = av.x * av.x + av.y * av.y + av.z * av.z + av.w * av.w;
  __syncthreads();
  for (int off = 128; off > 0; off >>= 1) {
    if (t < off) { red[t] += red[t + off]; red2[t] += red2[t + off]; }
    __syncthreads();
  }
  float mu = red[0] * (1.f / 1024.f);
  float var = red2[0] * (1.f / 1024.f) - mu * mu;
  float rstd = rsqrtf(var + 1e-5f);
  float4 g4 = *(const float4*)(gamma + t * 4);
  float4 b4 = *(const float4*)(beta + t * 4);
  float4 x14 = *(const float4*)(x1 + row * DM_ + t * 4);
  float4 o4;
  o4.x = x14.x + (av.x - mu) * rstd * g4.x + b4.x;
  o4.y = x14.y + (av.y - mu) * rstd * g4.y + b4.y;
  o4.z = x14.z + (av.z - mu) * rstd * g4.z + b4.z;
  o4.w = x14.w + (av.w - mu) * rstd * g4.w + b4.w;
  *(float4*)(out + row * DM_ + t * 4) = o4;
  float4 x24 = *(const float4*)(x2 + row * DM_ + t * 4);
  *(float4*)(out + (size_t)B_ * L_ * DM_ + row * DM_ + t * 4) = x24;
}

extern "C" void kernel_launch(void* const* d_in, const int* in_sizes, int n_in,
                              void* d_out, int out_size, void* d_ws, size_t ws_size,
                              hipStream_t stream) {
  const float* x1 = (const float*)d_in[0];
  const float* x2 = (const float*)d_in[1];
  const float* wq = (const float*)d_in[2];
  const float* bq = (const float*)d_in[3];
  const float* wv = (const float*)d_in[4];
  const float* bv = (const float*)d_in[5];
  const float* wo = (const float*)d_in[6];
  const float* bo = (const float*)d_in[7];
  const float* gamma = (const float*)d_in[8];
  const float* beta = (const float*)d_in[9];
  const float* rot = (const float*)d_in[10];

  char* ws = (char*)d_ws;
  float* qbuf = (float*)ws;                                 // 64 MB f32 q (b,h,l,d)
  unsigned int* vbuf = (unsigned int*)(ws + 67108864);      // 32 MB bf16 v (b,h,l,d)
  unsigned char* hbuf = (unsigned char*)(ws + 100663296);   // 512 KB hashes
  int* sbuf = (int*)(ws + 101187584);                       // 2 MB sort_idx
  float* lbuf = (float*)(ws + 103284736);                   // 2 MB lse
  unsigned int* obuf = (unsigned int*)(ws + 105381888);     // 128 MB bf16 o
  float* abuf = (float*)(ws + 105381888);                   // 64 MB f32 (alias obuf head)
  // dead-phase buffers inside obuf range (all consumed before attn_k writes obuf):
  unsigned short* wtqh = (unsigned short*)(ws + 105381888); // 2 MB wq hi bf16 [n][k]
  unsigned short* wtql = (unsigned short*)(ws + 107479040); // 2 MB wq lo bf16 [n][k]
  float* wproj = (float*)(ws + 109576192);                  // 4 MB Wproj [h][r][n][k]
  int* flags = (int*)(ws + 113770496);                      // 2 MB flag list
  int* cntb = (int*)(ws + 115867648);                       // 4 B flag counter
  unsigned short* wtv = (unsigned short*)(ws + 172490752);  // 2 MB (obuf tail, dead phase)
  unsigned short* wto = (unsigned short*)(ws + 174587904);  // 2 MB (obuf tail, dead phase)
  unsigned int* aoutW = (unsigned int*)ws;                  // 32 MB bf16 aout (alias qbuf)
  float* out = (float*)d_out;

  dim3 blk(256);
  cvtw2_k<<<dim3(256), blk, 0, stream>>>(wq, wtqh, wtql);
  wproj_k<<<dim3(32), blk, 0, stream>>>(wq, rot, wproj, cntb);
  gemm_qs<<<dim3(1024), blk, 0, stream>>>(wtqh, wtql, x2, bq, qbuf);
  cvtw_k<<<dim3(256), blk, 0, stream>>>(wv, wtv);
  gemm_bf<2><<<dim3(1024), blk, 0, stream>>>(wtv, (const void*)x2, bv, nullptr, vbuf);
  hash_k<<<dim3(65536), blk, 0, stream>>>(qbuf, rot, hbuf, cntb, flags);
  fixup_k<<<dim3(1024), blk, 0, stream>>>(cntb, flags, x2, wproj, hbuf);
  sort_k<<<dim3(128), blk, 0, stream>>>(hbuf, sbuf);
  attn_k<<<dim3(8192), blk, 0, stream>>>(qbuf, vbuf, sbuf, lbuf, obuf);
  comb_k<<<dim3(32768), blk, 0, stream>>>(lbuf, obuf, aoutW);
  cvtw_k<<<dim3(256), blk, 0, stream>>>(wo, wto);
  gemm_bf<0><<<dim3(1024), blk, 0, stream>>>((const unsigned short*)aoutW, (const void*)wto,
                                             bo, abuf, nullptr);
  ln_k<<<dim3(16384), blk, 0, stream>>>(abuf, x1, x2, gamma, beta, out);
}

// Round 3
// 1013.421 us; speedup vs baseline: 1.2865x; 1.2865x over previous
//
#include <hip/hip_runtime.h>
#include <hip/hip_bf16.h>

#define B_ 4
#define L_ 4096
#define DM_ 1024
#define NH_ 8
#define DK_ 128
#define NR_ 4
#define NC_ 64
#define NEGV -1.0e9f
#define SELFP -1.0e5f
#define SQRTDK 11.313708498984761f
#define TAU 1.0e-3f
#define FCAP 524288

typedef __attribute__((ext_vector_type(8))) short short8;
typedef __attribute__((ext_vector_type(4))) float f32x4;

__device__ __forceinline__ unsigned short f2bf(float x) {
  unsigned u = __float_as_uint(x);
  u += 0x7FFFu + ((u >> 16) & 1u);
  return (unsigned short)(u >> 16);
}
__device__ __forceinline__ float bf2f(unsigned short h) {
  return __uint_as_float(((unsigned)h) << 16);
}
__device__ __forceinline__ float wlo(unsigned w) { return __uint_as_float(w << 16); }
__device__ __forceinline__ float whi(unsigned w) { return __uint_as_float(w & 0xFFFF0000u); }
__device__ __forceinline__ unsigned packbf(float a, float b) {
  return (unsigned)f2bf(a) | (((unsigned)f2bf(b)) << 16);
}
// truncation split: hi = upper 16 bits, residual lo = x - hi (|lo| <= 2^-8|x|)
__device__ __forceinline__ unsigned packhi(float a, float b) {
  return (__float_as_uint(a) >> 16) | (__float_as_uint(b) & 0xFFFF0000u);
}
__device__ __forceinline__ float resid(float a) {
  return a - __uint_as_float(__float_as_uint(a) & 0xFFFF0000u);
}

// ---------------- weight transpose+convert: Wt[n][k] bf16 = W[k][n] ----------
__global__ __launch_bounds__(256) void cvtw_k(const float* __restrict__ W,
                                              unsigned short* __restrict__ Wt) {
  __shared__ float tile[64][65];
  const int t = threadIdx.x;
  const int bx = blockIdx.x & 15, by = blockIdx.x >> 4;
  const int c = t & 63, r4 = t >> 6;
#pragma unroll
  for (int i = 0; i < 16; i++) {
    int r = r4 * 16 + i;
    tile[r][c] = W[(size_t)(by * 64 + r) * DM_ + bx * 64 + c];
  }
  __syncthreads();
#pragma unroll
  for (int i = 0; i < 16; i++) {
    int r = r4 * 16 + i;
    Wt[(size_t)(bx * 64 + r) * DM_ + by * 64 + c] = f2bf(tile[c][r]);
  }
}

// ---------------- weight transpose+SPLIT: Whi/Wlo[n][k] bf16 ----------------
// hi = round-nearest bf16(W), lo = round-nearest bf16(W - hi)
__global__ __launch_bounds__(256) void cvtw2_k(const float* __restrict__ W,
                                               unsigned short* __restrict__ Whi,
                                               unsigned short* __restrict__ Wlo) {
  __shared__ float tile[64][65];
  const int t = threadIdx.x;
  const int bx = blockIdx.x & 15, by = blockIdx.x >> 4;
  const int c = t & 63, r4 = t >> 6;
#pragma unroll
  for (int i = 0; i < 16; i++) {
    int r = r4 * 16 + i;
    tile[r][c] = W[(size_t)(by * 64 + r) * DM_ + bx * 64 + c];
  }
  __syncthreads();
#pragma unroll
  for (int i = 0; i < 16; i++) {
    int r = r4 * 16 + i;
    float v = tile[c][r];
    unsigned short h = f2bf(v);
    float lo = v - bf2f(h);
    size_t o = (size_t)(bx * 64 + r) * DM_ + by * 64 + c;
    Whi[o] = h;
    Wlo[o] = f2bf(lo);
  }
}

// ---------------- Wproj precompute: Wp[h][r][n][k] = sum_d wq[k][h*128+d]*rot[d][r][n]
// grid 4096 = (hr 32) x (k-chunk 128); block 256 = (k8 8) x (n 32); 1 output/thread.
__global__ __launch_bounds__(256) void wproj_k(const float* __restrict__ W,
                                               const float* __restrict__ rot,
                                               float* __restrict__ Wp,
                                               int* __restrict__ cnt) {
  __shared__ float ws_[8][128];
  __shared__ float rs[128][33];
  const int t = threadIdx.x;
  const int hr = blockIdx.x >> 7;   // 0..31
  const int kc = blockIdx.x & 127;  // k chunk of 8
  const int h = hr >> 2, r = hr & 3;
  if (blockIdx.x == 0 && t == 0) *cnt = 0;
  for (int i = t; i < 4096; i += 256) {
    int d = i >> 5, n = i & 31;
    rs[d][n] = rot[(size_t)d * 128 + r * 32 + n];
  }
  {
    int kk = t >> 5, dd = (t & 31) * 4;
    const float* wr = W + (size_t)(kc * 8 + kk) * DM_ + h * 128 + dd;
    float4 wv = *(const float4*)wr;
    ws_[kk][dd] = wv.x; ws_[kk][dd + 1] = wv.y;
    ws_[kk][dd + 2] = wv.z; ws_[kk][dd + 3] = wv.w;
  }
  __syncthreads();
  const int n = t & 31, kk = t >> 5;
  float s0 = 0.f, s1 = 0.f, s2 = 0.f, s3 = 0.f;
#pragma unroll
  for (int d = 0; d < 128; d += 4) {
    s0 = fmaf(ws_[kk][d], rs[d][n], s0);
    s1 = fmaf(ws_[kk][d + 1], rs[d + 1][n], s1);
    s2 = fmaf(ws_[kk][d + 2], rs[d + 2][n], s2);
    s3 = fmaf(ws_[kk][d + 3], rs[d + 3][n], s3);
  }
  Wp[((size_t)(h * 4 + r) * 32 + n) * 1024 + kc * 8 + kk] = (s0 + s1) + (s2 + s3);
}

// ---------------- split-bf16 MFMA GEMM for q (3-term fp32 emulation) --------
// C[p][q] = sum_k W[p][k]*X[q][k]; W pre-split (hi/lo bf16), X split on the fly.
// out: qbuf f32 (b,h,l,d) + bias. 16B-granule XOR swizzle kills 8-way ds_read conflicts.
__global__ __launch_bounds__(256) void gemm_qs(const unsigned short* __restrict__ Whi,
                                               const unsigned short* __restrict__ Wlo,
                                               const float* __restrict__ X,
                                               const float* __restrict__ bias,
                                               float* __restrict__ outF) {
  __shared__ __align__(16) unsigned short Ph[128 * 32];
  __shared__ __align__(16) unsigned short Pl[128 * 32];
  __shared__ __align__(16) unsigned short Qh[128 * 32];
  __shared__ __align__(16) unsigned short Ql[128 * 32];
  __shared__ float bias_s[128];
  const int t = threadIdx.x;
  const int bi = blockIdx.x;
  const int pb = (bi & 7) << 7;   // output-dim block (head)
  const int qb = (bi >> 3) << 7;  // token block
  if (t < 128) bias_s[t] = bias[pb + t];
  const int srow = t >> 1, shalf = t & 1;
  const unsigned short* Ph_p = Whi + (size_t)(pb + srow) * DM_ + shalf * 16;
  const unsigned short* Pl_p = Wlo + (size_t)(pb + srow) * DM_ + shalf * 16;
  const float* Xf = X + (size_t)(qb + srow) * DM_ + shalf * 16;
  const int lane = t & 63, wid = t >> 6;
  const int lm = lane & 15, quad = lane >> 4;
  const int prw = (wid & 1) << 6, qcw = (wid >> 1) << 6;
  const int sg = (quad ^ (lm & 3)) << 3;  // swizzled granule offset for frag reads
  f32x4 acc[4][4];
#pragma unroll
  for (int i = 0; i < 4; i++)
#pragma unroll
    for (int j = 0; j < 4; j++) acc[i][j] = (f32x4){0.f, 0.f, 0.f, 0.f};
  uint4 phA, phB, plA, plB, qhA, qhB, qlA, qlB;
  {
    phA = *(const uint4*)(Ph_p);
    phB = *(const uint4*)(Ph_p + 8);
    plA = *(const uint4*)(Pl_p);
    plB = *(const uint4*)(Pl_p + 8);
    float4 f0 = *(const float4*)(Xf), f1 = *(const float4*)(Xf + 4);
    float4 f2 = *(const float4*)(Xf + 8), f3 = *(const float4*)(Xf + 12);
    qhA.x = packhi(f0.x, f0.y); qhA.y = packhi(f0.z, f0.w);
    qhA.z = packhi(f1.x, f1.y); qhA.w = packhi(f1.z, f1.w);
    qhB.x = packhi(f2.x, f2.y); qhB.y = packhi(f2.z, f2.w);
    qhB.z = packhi(f3.x, f3.y); qhB.w = packhi(f3.z, f3.w);
    qlA.x = packbf(resid(f0.x), resid(f0.y)); qlA.y = packbf(resid(f0.z), resid(f0.w));
    qlA.z = packbf(resid(f1.x), resid(f1.y)); qlA.w = packbf(resid(f1.z), resid(f1.w));
    qlB.x = packbf(resid(f2.x), resid(f2.y)); qlB.y = packbf(resid(f2.z), resid(f2.w));
    qlB.z = packbf(resid(f3.x), resid(f3.y)); qlB.w = packbf(resid(f3.z), resid(f3.w));
  }
  const int sw = srow & 3, g0 = shalf * 2;
  const int d0s = srow * 32 + ((g0 ^ sw) << 3);
  const int d1s = srow * 32 + (((g0 + 1) ^ sw) << 3);
  for (int kb = 0; kb < 32; ++kb) {
    __syncthreads();
    *(uint4*)&Ph[d0s] = phA; *(uint4*)&Ph[d1s] = phB;
    *(uint4*)&Pl[d0s] = plA; *(uint4*)&Pl[d1s] = plB;
    *(uint4*)&Qh[d0s] = qhA; *(uint4*)&Qh[d1s] = qhB;
    *(uint4*)&Ql[d0s] = qlA; *(uint4*)&Ql[d1s] = qlB;
    __syncthreads();
    if (kb < 31) {
      int ko = (kb + 1) * 32;
      phA = *(const uint4*)(Ph_p + ko);
      phB = *(const uint4*)(Ph_p + ko + 8);
      plA = *(const uint4*)(Pl_p + ko);
      plB = *(const uint4*)(Pl_p + ko + 8);
      const float* xp = Xf + ko;
      float4 f0 = *(const float4*)(xp), f1 = *(const float4*)(xp + 4);
      float4 f2 = *(const float4*)(xp + 8), f3 = *(const float4*)(xp + 12);
      qhA.x = packhi(f0.x, f0.y); qhA.y = packhi(f0.z, f0.w);
      qhA.z = packhi(f1.x, f1.y); qhA.w = packhi(f1.z, f1.w);
      qhB.x = packhi(f2.x, f2.y); qhB.y = packhi(f2.z, f2.w);
      qhB.z = packhi(f3.x, f3.y); qhB.w = packhi(f3.z, f3.w);
      qlA.x = packbf(resid(f0.x), resid(f0.y)); qlA.y = packbf(resid(f0.z), resid(f0.w));
      qlA.z = packbf(resid(f1.x), resid(f1.y)); qlA.w = packbf(resid(f1.z), resid(f1.w));
      qlB.x = packbf(resid(f2.x), resid(f2.y)); qlB.y = packbf(resid(f2.z), resid(f2.w));
      qlB.z = packbf(resid(f3.x), resid(f3.y)); qlB.w = packbf(resid(f3.z), resid(f3.w));
    }
    short8 ph[4], pl[4], qh[4], ql[4];
#pragma unroll
    for (int ti = 0; ti < 4; ti++) {
      int ro = (prw + ti * 16 + lm) * 32 + sg;
      ph[ti] = *(const short8*)&Ph[ro];
      pl[ti] = *(const short8*)&Pl[ro];
    }
#pragma unroll
    for (int tj = 0; tj < 4; tj++) {
      int ro = (qcw + tj * 16 + lm) * 32 + sg;
      qh[tj] = *(const short8*)&Qh[ro];
      ql[tj] = *(const short8*)&Ql[ro];
    }
#pragma unroll
    for (int ti = 0; ti < 4; ti++)
#pragma unroll
      for (int tj = 0; tj < 4; tj++) {
        f32x4 a = acc[ti][tj];
        a = __builtin_amdgcn_mfma_f32_16x16x32_bf16(ph[ti], qh[tj], a, 0, 0, 0);
        a = __builtin_amdgcn_mfma_f32_16x16x32_bf16(ph[ti], ql[tj], a, 0, 0, 0);
        a = __builtin_amdgcn_mfma_f32_16x16x32_bf16(pl[ti], qh[tj], a, 0, 0, 0);
        acc[ti][tj] = a;
      }
  }
  const int head = bi & 7;
#pragma unroll
  for (int tj = 0; tj < 4; tj++) {
    int mm = qb + qcw + tj * 16 + lm;
    int b = mm >> 12, l = mm & 4095;
    float* op = outF + ((size_t)(b * NH_ + head) * L_ + l) * DK_;
#pragma unroll
    for (int ti = 0; ti < 4; ti++) {
      int d0 = prw + ti * 16 + quad * 4;
      float4 w;
      w.x = acc[ti][tj][0] + bias_s[d0];
      w.y = acc[ti][tj][1] + bias_s[d0 + 1];
      w.z = acc[ti][tj][2] + bias_s[d0 + 2];
      w.w = acc[ti][tj][3] + bias_s[d0 + 3];
      *(float4*)(op + d0) = w;
    }
  }
}

// ---------------- bf16 MFMA GEMM ----------------
// C[p][q] = sum_k P[p][k] * Q[q][k]  (both operands row-major-K)
// MODE 0: P = aout bf16 rows(m), Q = Wt_o rows(n); C[m][n] f32 + bias[n] -> outF
// MODE 2: P = Wt_v rows(n=d of head), Q = x2 f32 rows(m); C^T -> bf16 (b,h,l,d)
template <int MODE>
__global__ __launch_bounds__(256) void gemm_bf(const unsigned short* __restrict__ Pm,
                                               const void* __restrict__ Qv,
                                               const float* __restrict__ bias,
                                               float* __restrict__ outF,
                                               unsigned int* __restrict__ outW) {
  __shared__ __align__(16) unsigned short Ps[128 * 32];
  __shared__ __align__(16) unsigned short Qs[128 * 32];
  __shared__ float bias_s[128];
  const int t = threadIdx.x;
  const int bi = blockIdx.x;
  const int pb = (MODE == 0) ? ((bi >> 3) << 7) : ((bi & 7) << 7);
  const int qb = (MODE == 0) ? ((bi & 7) << 7) : ((bi >> 3) << 7);
  if (t < 128) bias_s[t] = bias[((MODE == 0) ? qb : pb) + t];
  const int srow = t >> 1, shalf = t & 1;
  const unsigned short* Pp = Pm + (size_t)(pb + srow) * DM_ + shalf * 16;
  const float* Qf = (const float*)Qv + (size_t)(qb + srow) * DM_ + shalf * 16;
  const unsigned short* Qh = (const unsigned short*)Qv + (size_t)(qb + srow) * DM_ + shalf * 16;
  const int lane = t & 63, wid = t >> 6;
  const int lm = lane & 15, quad = lane >> 4;
  const int prw = (wid & 1) << 6, qcw = (wid >> 1) << 6;
  f32x4 acc[4][4];
#pragma unroll
  for (int i = 0; i < 4; i++)
#pragma unroll
    for (int j = 0; j < 4; j++) acc[i][j] = (f32x4){0.f, 0.f, 0.f, 0.f};
  uint4 pA, pB, qA, qB;
  {  // preload kb=0
    pA = *(const uint4*)(Pp);
    pB = *(const uint4*)(Pp + 8);
    if (MODE == 2) {
      float4 f0 = *(const float4*)(Qf), f1 = *(const float4*)(Qf + 4);
      float4 f2 = *(const float4*)(Qf + 8), f3 = *(const float4*)(Qf + 12);
      qA.x = packbf(f0.x, f0.y); qA.y = packbf(f0.z, f0.w);
      qA.z = packbf(f1.x, f1.y); qA.w = packbf(f1.z, f1.w);
      qB.x = packbf(f2.x, f2.y); qB.y = packbf(f2.z, f2.w);
      qB.z = packbf(f3.x, f3.y); qB.w = packbf(f3.z, f3.w);
    } else {
      qA = *(const uint4*)(Qh);
      qB = *(const uint4*)(Qh + 8);
    }
  }
  const int sdst = srow * 32 + shalf * 16;
  for (int kb = 0; kb < 32; ++kb) {
    __syncthreads();
    *(uint4*)&Ps[sdst] = pA;
    *(uint4*)&Ps[sdst + 8] = pB;
    *(uint4*)&Qs[sdst] = qA;
    *(uint4*)&Qs[sdst + 8] = qB;
    __syncthreads();
    if (kb < 31) {
      int ko = (kb + 1) * 32;
      pA = *(const uint4*)(Pp + ko);
      pB = *(const uint4*)(Pp + ko + 8);
      if (MODE == 2) {
        const float* qp = Qf + ko;
        float4 f0 = *(const float4*)(qp), f1 = *(const float4*)(qp + 4);
        float4 f2 = *(const float4*)(qp + 8), f3 = *(const float4*)(qp + 12);
        qA.x = packbf(f0.x, f0.y); qA.y = packbf(f0.z, f0.w);
        qA.z = packbf(f1.x, f1.y); qA.w = packbf(f1.z, f1.w);
        qB.x = packbf(f2.x, f2.y); qB.y = packbf(f2.z, f2.w);
        qB.z = packbf(f3.x, f3.y); qB.w = packbf(f3.z, f3.w);
      } else {
        qA = *(const uint4*)(Qh + ko);
        qB = *(const uint4*)(Qh + ko + 8);
      }
    }
    short8 pf[4], qf[4];
#pragma unroll
    for (int ti = 0; ti < 4; ti++)
      pf[ti] = *(const short8*)&Ps[(prw + ti * 16 + lm) * 32 + quad * 8];
#pragma unroll
    for (int tj = 0; tj < 4; tj++)
      qf[tj] = *(const short8*)&Qs[(qcw + tj * 16 + lm) * 32 + quad * 8];
#pragma unroll
    for (int ti = 0; ti < 4; ti++)
#pragma unroll
      for (int tj = 0; tj < 4; tj++)
        acc[ti][tj] = __builtin_amdgcn_mfma_f32_16x16x32_bf16(pf[ti], qf[tj], acc[ti][tj], 0, 0, 0);
  }
  if (MODE == 0) {
#pragma unroll
    for (int ti = 0; ti < 4; ti++) {
      int m = pb + prw + ti * 16 + quad * 4;
#pragma unroll
      for (int tj = 0; tj < 4; tj++) {
        int nn = qcw + tj * 16 + lm;
        float bn = bias_s[nn];
        float* op = outF + (size_t)m * DM_ + qb + nn;
#pragma unroll
        for (int r = 0; r < 4; r++) op[(size_t)r * DM_] = acc[ti][tj][r] + bn;
      }
    }
  } else {
    const int head = bi & 7;
#pragma unroll
    for (int tj = 0; tj < 4; tj++) {
      int mm = qb + qcw + tj * 16 + lm;
      int b = mm >> 12, l = mm & 4095;
#pragma unroll
      for (int ti = 0; ti < 4; ti++) {
        int d0 = prw + ti * 16 + quad * 4;
        uint2 ov;
        ov.x = packbf(acc[ti][tj][0] + bias_s[d0], acc[ti][tj][1] + bias_s[d0 + 1]);
        ov.y = packbf(acc[ti][tj][2] + bias_s[d0 + 2], acc[ti][tj][3] + bias_s[d0 + 3]);
        *(uint2*)(outW + ((size_t)(b * NH_ + head) * L_ + l) * 64 + (d0 >> 1)) = ov;
      }
    }
  }
}

// ---------------- Hashing: argmax_n |q . rot| + near-tie flagging ----------
__global__ __launch_bounds__(256) void hash_k(const float* __restrict__ q,
                                              const float* __restrict__ rot,
                                              unsigned char* __restrict__ hout,
                                              int* __restrict__ cnt,
                                              int* __restrict__ flags) {
  __shared__ float qs[2][128];
  __shared__ float val[256];
  __shared__ float val2[256];
  __shared__ int vidx[256];
  const int t = threadIdx.x;
  const int bh = blockIdx.x >> 11;
  const int lp = blockIdx.x & 2047;
  const int lh = t >> 7;
  const int l = (lp << 1) + lh;
  const int sub = t & 127;  // r*32+n
  qs[lh][sub] = q[((size_t)bh * L_ + l) * DK_ + sub];
  __syncthreads();
  float p = 0.f;
  for (int d = 0; d < 128; d++) p = fmaf(qs[lh][d], rot[d * 128 + sub], p);
  const int n = sub & 31;
  val[t] = fabsf(p);
  val2[t] = -3.0e38f;
  vidx[t] = (p >= 0.f) ? n : (n + 32);
  __syncthreads();
#pragma unroll
  for (int off = 16; off > 0; off >>= 1) {
    if ((t & 31) < off) {
      float v1a = val[t], v2a = val2[t];
      int i1a = vidx[t];
      float v1b = val[t + off], v2b = val2[t + off];
      int i1b = vidx[t + off];
      if (v1b > v1a || (v1b == v1a && i1b < i1a)) {
        val[t] = v1b; vidx[t] = i1b; val2[t] = fmaxf(v1a, v2b);
      } else {
        val2[t] = fmaxf(v1b, v2a);
      }
    }
    __syncthreads();
  }
  if ((t & 31) == 0) {
    int r = sub >> 5;
    hout[((size_t)(bh * NR_ + r)) * L_ + l] = (unsigned char)vidx[t];
    if (val[t] - val2[t] < TAU) {
      int slot = atomicAdd(cnt, 1);
      if (slot < FCAP) flags[slot] = (((bh << 2) | r) << 12) | l;
    }
  }
}

// ---------------- exact f32 recompute of flagged (near-tie) hashes ---------
__global__ __launch_bounds__(256) void fixup_k(const int* __restrict__ cnt,
                                               const int* __restrict__ flags,
                                               const float* __restrict__ X,
                                               const float* __restrict__ Wp,
                                               unsigned char* __restrict__ hout) {
  __shared__ float xs[1024];
  __shared__ float pv[32];
  int nflag = *cnt;
  if (nflag > FCAP) nflag = FCAP;
  const int t = threadIdx.x;
  for (int i = blockIdx.x; i < nflag; i += gridDim.x) {
    int f = flags[i];
    int l = f & 4095, r = (f >> 12) & 3, bh = f >> 14;
    int b = bh >> 3, h = bh & 7;
    __syncthreads();  // protect xs/pv from previous iteration readers
    ((float4*)xs)[t] = ((const float4*)(X + ((size_t)b * L_ + l) * DM_))[t];
    __syncthreads();
    const int nn = t >> 3, kl = t & 7;
    const float* wrow = Wp + ((size_t)(h * 4 + r) * 32 + nn) * 1024 + kl * 4;
    float s = 0.f;
#pragma unroll 8
    for (int k0 = 0; k0 < 1024; k0 += 32) {
      float4 wv = *(const float4*)(wrow + k0);
      float4 xv = *(const float4*)(xs + k0 + kl * 4);
      s = fmaf(wv.x, xv.x, fmaf(wv.y, xv.y, fmaf(wv.z, xv.z, fmaf(wv.w, xv.w, s))));
    }
    s += __shfl_xor(s, 1);
    s += __shfl_xor(s, 2);
    s += __shfl_xor(s, 4);
    if (kl == 0) pv[nn] = s;
    __syncthreads();
    if (t == 0) {
      float bestv = -1.f;
      int besti = 0;
      for (int j = 0; j < 32; j++) {
        float p = pv[j];
        float ap = fabsf(p);
        int idx = (p >= 0.f) ? j : (j + 32);
        if (ap > bestv || (ap == bestv && idx < besti)) { bestv = ap; besti = idx; }
      }
      hout[((size_t)(bh * NR_ + r)) * L_ + l] = (unsigned char)besti;
    }
  }
}

// ---------------- Stable counting sort per (b,h,r) ----------------
__global__ __launch_bounds__(256) void sort_k(const unsigned char* __restrict__ hsh,
                                              int* __restrict__ sidx) {
  __shared__ unsigned char seg[256 * 64];
  __shared__ unsigned short grp[16 * 64];
  __shared__ int offs[64];
  __shared__ int tot[64];
  const int t = threadIdx.x;
  const int bhr = blockIdx.x;
  uint4 hv = ((const uint4*)(hsh + (size_t)bhr * L_))[t];
  unsigned hb[4] = {hv.x, hv.y, hv.z, hv.w};
  unsigned int* seg32 = (unsigned int*)seg;
#pragma unroll
  for (int i = 0; i < 16; i++) seg32[t * 16 + i] = 0;
  ((unsigned int*)grp)[t * 2] = 0;
  ((unsigned int*)grp)[t * 2 + 1] = 0;
  __syncthreads();
#pragma unroll
  for (int k = 0; k < 16; k++) {
    int h = (hb[k >> 2] >> ((k & 3) * 8)) & 0xFF;
    seg[t * 64 + h] = (unsigned char)(seg[t * 64 + h] + 1);
  }
  __syncthreads();
  {
    int h = t & 63;
    for (int g = (t >> 6); g < 16; g += 4) {
      int run = 0;
      for (int s = 0; s < 16; s++) {
        int idx = ((g << 4) + s) * 64 + h;
        int c = seg[idx];
        seg[idx] = (unsigned char)run;
        run += c;
      }
      grp[g * 64 + h] = (unsigned short)run;
    }
  }
  __syncthreads();
  if (t < 64) {
    int run = 0;
    for (int g = 0; g < 16; g++) {
      int c = grp[g * 64 + t];
      grp[g * 64 + t] = (unsigned short)run;
      run += c;
    }
    tot[t] = run;
  }
  __syncthreads();
  if (t == 0) {
    int run = 0;
    for (int h = 0; h < 64; h++) { offs[h] = run; run += tot[h]; }
  }
  __syncthreads();
  const int gbase = (t >> 4) * 64;
  int* outp = sidx + (size_t)bhr * L_;
#pragma unroll
  for (int k = 0; k < 16; k++) {
    int h = (hb[k >> 2] >> ((k & 3) * 8)) & 0xFF;
    int pos = offs[h] + grp[gbase + h] + seg[t * 64 + h];
    seg[t * 64 + h] = (unsigned char)(seg[t * 64 + h] + 1);
    outp[pos] = t * 16 + k;
  }
}

// ---------------- Chunked look-back attention (MFMA) ----------------
#define KSTR 136
__global__ __launch_bounds__(256) void attn_k(const float* __restrict__ q,
                                              const unsigned int* __restrict__ vwg,
                                              const int* __restrict__ sidx,
                                              float* __restrict__ lseG,
                                              unsigned int* __restrict__ oW) {
  __shared__ __align__(16) unsigned short R1[128 * KSTR];
  __shared__ __align__(16) unsigned short R2[64 * KSTR];
  __shared__ int idxs[128];
  __shared__ float rowsum[64];
  const int t = threadIdx.x;
  const int c = blockIdx.x & 63;
  const int bhr = blockIdx.x >> 6;
  const int bh = bhr >> 2;
  const int pc = (c + 63) & 63;
  if (t < 128) {
    int sp = (t < 64) ? (pc * 64 + t) : (c * 64 + t - 64);
    idxs[t] = sidx[(size_t)bhr * L_ + sp];
  }
  __syncthreads();
  {
    const int row = t >> 1, half = t & 1;
    const float4* qp = (const float4*)(q + ((size_t)bh * L_ + idxs[row]) * DK_ + half * 64);
    float4 f[16];
    float ss = 0.f;
#pragma unroll
    for (int u = 0; u < 16; u++) {
      f[u] = qp[u];
      ss = fmaf(f[u].x, f[u].x, fmaf(f[u].y, f[u].y, fmaf(f[u].z, f[u].z, fmaf(f[u].w, f[u].w, ss))));
    }
    ss += __shfl_xor(ss, 1);
    float rn = 1.f / (sqrtf(ss) + 1e-9f);
    unsigned short* kr = R1 + row * KSTR + half * 64;
#pragma unroll
    for (int u = 0; u < 8; u++) {
      uint4 w4;
      w4.x = packbf(f[2 * u].x * rn, f[2 * u].y * rn);
      w4.y = packbf(f[2 * u].z * rn, f[2 * u].w * rn);
      w4.z = packbf(f[2 * u + 1].x * rn, f[2 * u + 1].y * rn);
      w4.w = packbf(f[2 * u + 1].z * rn, f[2 * u + 1].w * rn);
      *(uint4*)(kr + u * 8) = w4;
    }
    if (row >= 64) {
      unsigned short* qr = R2 + (row - 64) * KSTR + half * 64;
#pragma unroll
      for (int u = 0; u < 8; u++) {
        uint4 w4;
        w4.x = packbf(f[2 * u].x, f[2 * u].y);
        w4.y = packbf(f[2 * u].z, f[2 * u].w);
        w4.z = packbf(f[2 * u + 1].x, f[2 * u + 1].y);
        w4.w = packbf(f[2 * u + 1].z, f[2 * u + 1].w);
        *(uint4*)(qr + u * 8) = w4;
      }
    }
  }
  __syncthreads();
  const int lane = t & 63, wv = t >> 6;
  const int m0 = wv * 16;
  const int lm = lane & 15, quad = lane >> 4;
  f32x4 acc[8];
  {
    short8 af[4];
#pragma unroll
    for (int ks = 0; ks < 4; ks++)
      af[ks] = *(const short8*)(R2 + (m0 + lm) * KSTR + ks * 32 + quad * 8);
#pragma unroll
    for (int n = 0; n < 8; n++) {
      f32x4 a = {0.f, 0.f, 0.f, 0.f};
#pragma unroll
      for (int ks = 0; ks < 4; ks++) {
        short8 bf = *(const short8*)(R1 + (n * 16 + lm) * KSTR + ks * 32 + quad * 8);
        a = __builtin_amdgcn_mfma_f32_16x16x32_bf16(af[ks], bf, a, 0, 0, 0);
      }
      acc[n] = a;
    }
  }
  {
    int qp4[4];
#pragma unroll
    for (int r = 0; r < 4; r++) qp4[r] = idxs[64 + m0 + quad * 4 + r];
#pragma unroll
    for (int n = 0; n < 8; n++) {
      int key = n * 16 + lm;
      int kp = idxs[key];
#pragma unroll
      for (int r = 0; r < 4; r++) {
        float s = acc[n][r] * (1.f / SQRTDK);
        s = (kp > qp4[r]) ? NEGV : ((kp == qp4[r]) ? SELFP : s);
        R2[(m0 + quad * 4 + r) * KSTR + key] = f2bf(s);
      }
    }
  }
  uint4 vv[8];
  {
    const int key = t >> 1, half = t & 1;
    const uint4* vp = (const uint4*)(vwg + ((size_t)bh * L_ + idxs[key]) * 64 + half * 32);
#pragma unroll
    for (int u = 0; u < 8; u++) vv[u] = vp[u];
  }
  {
    const int row = t >> 2, seg = t & 3;
    unsigned short* sp = R2 + row * KSTR + seg * 32;
    uint4 sv4[4];
    float m = -3.0e38f;
#pragma unroll
    for (int u = 0; u < 4; u++) {
      sv4[u] = *(uint4*)(sp + u * 8);
      unsigned wd[4] = {sv4[u].x, sv4[u].y, sv4[u].z, sv4[u].w};
#pragma unroll
      for (int cc = 0; cc < 4; cc++) {
        m = fmaxf(m, wlo(wd[cc]));
        m = fmaxf(m, whi(wd[cc]));
      }
    }
    m = fmaxf(m, __shfl_xor(m, 1));
    m = fmaxf(m, __shfl_xor(m, 2));
    float sum = 0.f;
#pragma unroll
    for (int u = 0; u < 4; u++) {
      unsigned wd[4] = {sv4[u].x, sv4[u].y, sv4[u].z, sv4[u].w};
      unsigned ow[4];
#pragma unroll
      for (int cc = 0; cc < 4; cc++) {
        float e0 = expf(wlo(wd[cc]) - m);
        float e1 = expf(whi(wd[cc]) - m);
        unsigned short b0 = f2bf(e0), b1 = f2bf(e1);
        sum += bf2f(b0) + bf2f(b1);
        ow[cc] = (unsigned)b0 | (((unsigned)b1) << 16);
      }
      uint4 o4;
      o4.x = ow[0]; o4.y = ow[1]; o4.z = ow[2]; o4.w = ow[3];
      *(uint4*)(sp + u * 8) = o4;
    }
    sum += __shfl_xor(sum, 1);
    sum += __shfl_xor(sum, 2);
    if (seg == 0) {
      rowsum[row] = sum;
      lseG[(size_t)bhr * L_ + idxs[64 + row]] = m + logf(sum);
    }
  }
  __syncthreads();
  {
    const int key = t >> 1, half = t & 1;
#pragma unroll
    for (int u = 0; u < 8; u++) {
      unsigned wd[4] = {vv[u].x, vv[u].y, vv[u].z, vv[u].w};
#pragma unroll
      for (int cc = 0; cc < 4; cc++) {
        int w = half * 32 + u * 4 + cc;
        R1[(2 * w) * KSTR + key] = (unsigned short)(wd[cc] & 0xFFFFu);
        R1[(2 * w + 1) * KSTR + key] = (unsigned short)(wd[cc] >> 16);
      }
    }
  }
  __syncthreads();
  f32x4 acc2[8];
  {
    short8 af[4];
#pragma unroll
    for (int ks = 0; ks < 4; ks++)
      af[ks] = *(const short8*)(R2 + (m0 + lm) * KSTR + ks * 32 + quad * 8);
#pragma unroll
    for (int n = 0; n < 8; n++) {
      f32x4 a = {0.f, 0.f, 0.f, 0.f};
#pragma unroll
      for (int ks = 0; ks < 4; ks++) {
        short8 bf = *(const short8*)(R1 + (n * 16 + lm) * KSTR + ks * 32 + quad * 8);
        a = __builtin_amdgcn_mfma_f32_16x16x32_bf16(af[ks], bf, a, 0, 0, 0);
      }
      acc2[n] = a;
    }
  }
  {
    float inv[4];
#pragma unroll
    for (int r = 0; r < 4; r++) inv[r] = 1.f / rowsum[m0 + quad * 4 + r];
#pragma unroll
    for (int n = 0; n < 8; n++)
#pragma unroll
      for (int r = 0; r < 4; r++)
        R2[(m0 + quad * 4 + r) * KSTR + n * 16 + lm] = f2bf(acc2[n][r] * inv[r]);
  }
  __syncthreads();
  {
    const int row = t >> 2, seg = t & 3;
    int l = idxs[64 + row];
    unsigned int* op = oW + ((size_t)bhr * L_ + l) * 64 + seg * 16;
    const unsigned short* rp = R2 + row * KSTR + seg * 32;
#pragma unroll
    for (int u = 0; u < 4; u++) *(uint4*)(op + u * 4) = *(const uint4*)(rp + u * 8);
  }
}

// ---------------- Round-softmax merge -> bf16 aout words ----------------
__global__ __launch_bounds__(256) void comb_k(const float* __restrict__ lse,
                                              const unsigned int* __restrict__ oW,
                                              unsigned int* __restrict__ aoutW) {
  size_t g = (size_t)blockIdx.x * 256 + threadIdx.x;
  int w = (int)(g & 63);
  int l = (int)((g >> 6) & 4095);
  int bh = (int)(g >> 18);
  float ls[4];
#pragma unroll
  for (int r = 0; r < 4; r++) ls[r] = lse[((size_t)(bh * 4 + r)) * L_ + l];
  float m = fmaxf(fmaxf(ls[0], ls[1]), fmaxf(ls[2], ls[3]));
  float wsum = 0.f, a0 = 0.f, a1 = 0.f;
#pragma unroll
  for (int r = 0; r < 4; r++) {
    float e = expf(ls[r] - m);
    wsum += e;
    unsigned ow = oW[(((size_t)(bh * 4 + r)) * L_ + l) * 64 + w];
    a0 = fmaf(e, wlo(ow), a0);
    a1 = fmaf(e, whi(ow), a1);
  }
  float inv = 1.f / wsum;
  int b = bh >> 3, h = bh & 7;
  // aout bf16 row-major [m][k] as words: m*512 + h*64 + w
  aoutW[((size_t)b * L_ + l) * 512 + h * 64 + w] = packbf(a0 * inv, a1 * inv);
}

// ---------------- LayerNorm + residual + x2 passthrough ----------------
__global__ __launch_bounds__(256) void ln_k(const float* __restrict__ a,
                                            const float* __restrict__ x1,
                                            const float* __restrict__ x2,
                                            const float* __restrict__ gamma,
                                            const float* __restrict__ beta,
                                            float* __restrict__ out) {
  __shared__ float red[256];
  __shared__ float red2[256];
  const int t = threadIdx.x;
  const size_t row = blockIdx.x;
  float4 av = *(const float4*)(a + row * DM_ + t * 4);
  red[t] = av.x + av.y + av.z + av.w;
  red2[t] = av.x * av.x + av.y * av.y + av.z * av.z + av.w * av.w;
  __syncthreads();
  for (int off = 128; off > 0; off >>= 1) {
    if (t < off) { red[t] += red[t + off]; red2[t] += red2[t + off]; }
    __syncthreads();
  }
  float mu = red[0] * (1.f / 1024.f);
  float var = red2[0] * (1.f / 1024.f) - mu * mu;
  float rstd = rsqrtf(var + 1e-5f);
  float4 g4 = *(const float4*)(gamma + t * 4);
  float4 b4 = *(const float4*)(beta + t * 4);
  float4 x14 = *(const float4*)(x1 + row * DM_ + t * 4);
  float4 o4;
  o4.x = x14.x + (av.x - mu) * rstd * g4.x + b4.x;
  o4.y = x14.y + (av.y - mu) * rstd * g4.y + b4.y;
  o4.z = x14.z + (av.z - mu) * rstd * g4.z + b4.z;
  o4.w = x14.w + (av.w - mu) * rstd * g4.w + b4.w;
  *(float4*)(out + row * DM_ + t * 4) = o4;
  float4 x24 = *(const float4*)(x2 + row * DM_ + t * 4);
  *(float4*)(out + (size_t)B_ * L_ * DM_ + row * DM_ + t * 4) = x24;
}

extern "C" void kernel_launch(void* const* d_in, const int* in_sizes, int n_in,
                              void* d_out, int out_size, void* d_ws, size_t ws_size,
                              hipStream_t stream) {
  const float* x1 = (const float*)d_in[0];
  const float* x2 = (const float*)d_in[1];
  const float* wq = (const float*)d_in[2];
  const float* bq = (const float*)d_in[3];
  const float* wv = (const float*)d_in[4];
  const float* bv = (const float*)d_in[5];
  const float* wo = (const float*)d_in[6];
  const float* bo = (const float*)d_in[7];
  const float* gamma = (const float*)d_in[8];
  const float* beta = (const float*)d_in[9];
  const float* rot = (const float*)d_in[10];

  char* ws = (char*)d_ws;
  float* qbuf = (float*)ws;                                 // 64 MB f32 q (b,h,l,d)
  unsigned int* vbuf = (unsigned int*)(ws + 67108864);      // 32 MB bf16 v (b,h,l,d)
  unsigned char* hbuf = (unsigned char*)(ws + 100663296);   // 512 KB hashes
  int* sbuf = (int*)(ws + 101187584);                       // 2 MB sort_idx
  float* lbuf = (float*)(ws + 103284736);                   // 2 MB lse
  unsigned int* obuf = (unsigned int*)(ws + 105381888);     // 128 MB bf16 o
  float* abuf = (float*)(ws + 105381888);                   // 64 MB f32 (alias obuf head)
  // dead-phase buffers inside obuf range (all consumed before attn_k writes obuf):
  unsigned short* wtqh = (unsigned short*)(ws + 105381888); // 2 MB wq hi bf16 [n][k]
  unsigned short* wtql = (unsigned short*)(ws + 107479040); // 2 MB wq lo bf16 [n][k]
  float* wproj = (float*)(ws + 109576192);                  // 4 MB Wproj [h][r][n][k]
  int* flags = (int*)(ws + 113770496);                      // 2 MB flag list
  int* cntb = (int*)(ws + 115867648);                       // 4 B flag counter
  unsigned short* wtv = (unsigned short*)(ws + 172490752);  // 2 MB (obuf tail, dead phase)
  unsigned short* wto = (unsigned short*)(ws + 174587904);  // 2 MB (obuf tail, dead phase)
  unsigned int* aoutW = (unsigned int*)ws;                  // 32 MB bf16 aout (alias qbuf)
  float* out = (float*)d_out;

  dim3 blk(256);
  cvtw2_k<<<dim3(256), blk, 0, stream>>>(wq, wtqh, wtql);
  wproj_k<<<dim3(4096), blk, 0, stream>>>(wq, rot, wproj, cntb);
  gemm_qs<<<dim3(1024), blk, 0, stream>>>(wtqh, wtql, x2, bq, qbuf);
  cvtw_k<<<dim3(256), blk, 0, stream>>>(wv, wtv);
  gemm_bf<2><<<dim3(1024), blk, 0, stream>>>(wtv, (const void*)x2, bv, nullptr, vbuf);
  hash_k<<<dim3(65536), blk, 0, stream>>>(qbuf, rot, hbuf, cntb, flags);
  fixup_k<<<dim3(1024), blk, 0, stream>>>(cntb, flags, x2, wproj, hbuf);
  sort_k<<<dim3(128), blk, 0, stream>>>(hbuf, sbuf);
  attn_k<<<dim3(8192), blk, 0, stream>>>(qbuf, vbuf, sbuf, lbuf, obuf);
  comb_k<<<dim3(32768), blk, 0, stream>>>(lbuf, obuf, aoutW);
  cvtw_k<<<dim3(256), blk, 0, stream>>>(wo, wto);
  gemm_bf<0><<<dim3(1024), blk, 0, stream>>>((const unsigned short*)aoutW, (const void*)wto,
                                             bo, abuf, nullptr);
  ln_k<<<dim3(16384), blk, 0, stream>>>(abuf, x1, x2, gamma, beta, out);
}

// Round 4
// 818.311 us; speedup vs baseline: 1.5933x; 1.2384x over previous
//
#include <hip/hip_runtime.h>
#include <hip/hip_bf16.h>

#define B_ 4
#define L_ 4096
#define DM_ 1024
#define NH_ 8
#define DK_ 128
#define NR_ 4
#define NC_ 64
#define NEGV -1.0e9f
#define SELFP -1.0e5f
#define SQRTDK 11.313708498984761f
#define TAU 1.0e-3f
#define FCAP 524288

typedef __attribute__((ext_vector_type(8))) short short8;
typedef __attribute__((ext_vector_type(4))) float f32x4;

__device__ __forceinline__ unsigned short f2bf(float x) {
  unsigned u = __float_as_uint(x);
  u += 0x7FFFu + ((u >> 16) & 1u);
  return (unsigned short)(u >> 16);
}
__device__ __forceinline__ float bf2f(unsigned short h) {
  return __uint_as_float(((unsigned)h) << 16);
}
__device__ __forceinline__ float wlo(unsigned w) { return __uint_as_float(w << 16); }
__device__ __forceinline__ float whi(unsigned w) { return __uint_as_float(w & 0xFFFF0000u); }
__device__ __forceinline__ unsigned packbf(float a, float b) {
  return (unsigned)f2bf(a) | (((unsigned)f2bf(b)) << 16);
}
// truncation split: hi = upper 16 bits, residual lo = x - hi (|lo| <= 2^-8|x|)
__device__ __forceinline__ unsigned packhi(float a, float b) {
  return (__float_as_uint(a) >> 16) | (__float_as_uint(b) & 0xFFFF0000u);
}
__device__ __forceinline__ float resid(float a) {
  return a - __uint_as_float(__float_as_uint(a) & 0xFFFF0000u);
}

// ---------------- weight transpose+convert: Wt[n][k] bf16 = W[k][n] ----------
__global__ __launch_bounds__(256) void cvtw_k(const float* __restrict__ W,
                                              unsigned short* __restrict__ Wt) {
  __shared__ float tile[64][65];
  const int t = threadIdx.x;
  const int bx = blockIdx.x & 15, by = blockIdx.x >> 4;
  const int c = t & 63, r4 = t >> 6;
#pragma unroll
  for (int i = 0; i < 16; i++) {
    int r = r4 * 16 + i;
    tile[r][c] = W[(size_t)(by * 64 + r) * DM_ + bx * 64 + c];
  }
  __syncthreads();
#pragma unroll
  for (int i = 0; i < 16; i++) {
    int r = r4 * 16 + i;
    Wt[(size_t)(bx * 64 + r) * DM_ + by * 64 + c] = f2bf(tile[c][r]);
  }
}

// ---------------- weight transpose+SPLIT: Whi/Wlo[n][k] bf16 ----------------
// hi = round-nearest bf16(W), lo = round-nearest bf16(W - hi)
__global__ __launch_bounds__(256) void cvtw2_k(const float* __restrict__ W,
                                               unsigned short* __restrict__ Whi,
                                               unsigned short* __restrict__ Wlo) {
  __shared__ float tile[64][65];
  const int t = threadIdx.x;
  const int bx = blockIdx.x & 15, by = blockIdx.x >> 4;
  const int c = t & 63, r4 = t >> 6;
#pragma unroll
  for (int i = 0; i < 16; i++) {
    int r = r4 * 16 + i;
    tile[r][c] = W[(size_t)(by * 64 + r) * DM_ + bx * 64 + c];
  }
  __syncthreads();
#pragma unroll
  for (int i = 0; i < 16; i++) {
    int r = r4 * 16 + i;
    float v = tile[c][r];
    unsigned short h = f2bf(v);
    float lo = v - bf2f(h);
    size_t o = (size_t)(bx * 64 + r) * DM_ + by * 64 + c;
    Whi[o] = h;
    Wlo[o] = f2bf(lo);
  }
}

// ---------------- rot transpose+SPLIT: Rhi/Rlo[n'][d] bf16 = rot[d][n'] -----
__global__ __launch_bounds__(256) void cvtrot_k(const float* __restrict__ rot,
                                                unsigned short* __restrict__ Rhi,
                                                unsigned short* __restrict__ Rlo) {
  int i = blockIdx.x * 256 + threadIdx.x;  // 64 blocks x 256 = 16384
  float v = rot[i];
  unsigned short h = f2bf(v);
  float lo = v - bf2f(h);
  int d = i >> 7, np = i & 127;
  Rhi[np * 128 + d] = h;
  Rlo[np * 128 + d] = f2bf(lo);
}

// ---------------- Wproj precompute: Wp[h][r][n][k] = sum_d wq[k][h*128+d]*rot[d][r][n]
// grid 4096 = (hr 32) x (k-chunk 128); block 256 = (k8 8) x (n 32); 1 output/thread.
__global__ __launch_bounds__(256) void wproj_k(const float* __restrict__ W,
                                               const float* __restrict__ rot,
                                               float* __restrict__ Wp,
                                               int* __restrict__ cnt) {
  __shared__ float ws_[8][128];
  __shared__ float rs[128][33];
  const int t = threadIdx.x;
  const int hr = blockIdx.x >> 7;   // 0..31
  const int kc = blockIdx.x & 127;  // k chunk of 8
  const int h = hr >> 2, r = hr & 3;
  if (blockIdx.x == 0 && t == 0) *cnt = 0;
  for (int i = t; i < 4096; i += 256) {
    int d = i >> 5, n = i & 31;
    rs[d][n] = rot[(size_t)d * 128 + r * 32 + n];
  }
  {
    int kk = t >> 5, dd = (t & 31) * 4;
    const float* wr = W + (size_t)(kc * 8 + kk) * DM_ + h * 128 + dd;
    float4 wv = *(const float4*)wr;
    ws_[kk][dd] = wv.x; ws_[kk][dd + 1] = wv.y;
    ws_[kk][dd + 2] = wv.z; ws_[kk][dd + 3] = wv.w;
  }
  __syncthreads();
  const int n = t & 31, kk = t >> 5;
  float s0 = 0.f, s1 = 0.f, s2 = 0.f, s3 = 0.f;
#pragma unroll
  for (int d = 0; d < 128; d += 4) {
    s0 = fmaf(ws_[kk][d], rs[d][n], s0);
    s1 = fmaf(ws_[kk][d + 1], rs[d + 1][n], s1);
    s2 = fmaf(ws_[kk][d + 2], rs[d + 2][n], s2);
    s3 = fmaf(ws_[kk][d + 3], rs[d + 3][n], s3);
  }
  Wp[((size_t)(h * 4 + r) * 32 + n) * 1024 + kc * 8 + kk] = (s0 + s1) + (s2 + s3);
}

// ---------------- split-bf16 MFMA GEMM for q (3-term fp32 emulation) --------
// C[p][q] = sum_k W[p][k]*X[q][k]; W pre-split (hi/lo bf16), X split on the fly.
// out: qbuf f32 (b,h,l,d) + bias. 16B-granule XOR swizzle kills 8-way ds_read conflicts.
__global__ __launch_bounds__(256) void gemm_qs(const unsigned short* __restrict__ Whi,
                                               const unsigned short* __restrict__ Wlo,
                                               const float* __restrict__ X,
                                               const float* __restrict__ bias,
                                               float* __restrict__ outF) {
  __shared__ __align__(16) unsigned short Ph[128 * 32];
  __shared__ __align__(16) unsigned short Pl[128 * 32];
  __shared__ __align__(16) unsigned short Qh[128 * 32];
  __shared__ __align__(16) unsigned short Ql[128 * 32];
  __shared__ float bias_s[128];
  const int t = threadIdx.x;
  const int bi = blockIdx.x;
  const int pb = (bi & 7) << 7;   // output-dim block (head)
  const int qb = (bi >> 3) << 7;  // token block
  if (t < 128) bias_s[t] = bias[pb + t];
  const int srow = t >> 1, shalf = t & 1;
  const unsigned short* Ph_p = Whi + (size_t)(pb + srow) * DM_ + shalf * 16;
  const unsigned short* Pl_p = Wlo + (size_t)(pb + srow) * DM_ + shalf * 16;
  const float* Xf = X + (size_t)(qb + srow) * DM_ + shalf * 16;
  const int lane = t & 63, wid = t >> 6;
  const int lm = lane & 15, quad = lane >> 4;
  const int prw = (wid & 1) << 6, qcw = (wid >> 1) << 6;
  const int sg = (quad ^ (lm & 3)) << 3;  // swizzled granule offset for frag reads
  f32x4 acc[4][4];
#pragma unroll
  for (int i = 0; i < 4; i++)
#pragma unroll
    for (int j = 0; j < 4; j++) acc[i][j] = (f32x4){0.f, 0.f, 0.f, 0.f};
  uint4 phA, phB, plA, plB, qhA, qhB, qlA, qlB;
  {
    phA = *(const uint4*)(Ph_p);
    phB = *(const uint4*)(Ph_p + 8);
    plA = *(const uint4*)(Pl_p);
    plB = *(const uint4*)(Pl_p + 8);
    float4 f0 = *(const float4*)(Xf), f1 = *(const float4*)(Xf + 4);
    float4 f2 = *(const float4*)(Xf + 8), f3 = *(const float4*)(Xf + 12);
    qhA.x = packhi(f0.x, f0.y); qhA.y = packhi(f0.z, f0.w);
    qhA.z = packhi(f1.x, f1.y); qhA.w = packhi(f1.z, f1.w);
    qhB.x = packhi(f2.x, f2.y); qhB.y = packhi(f2.z, f2.w);
    qhB.z = packhi(f3.x, f3.y); qhB.w = packhi(f3.z, f3.w);
    qlA.x = packbf(resid(f0.x), resid(f0.y)); qlA.y = packbf(resid(f0.z), resid(f0.w));
    qlA.z = packbf(resid(f1.x), resid(f1.y)); qlA.w = packbf(resid(f1.z), resid(f1.w));
    qlB.x = packbf(resid(f2.x), resid(f2.y)); qlB.y = packbf(resid(f2.z), resid(f2.w));
    qlB.z = packbf(resid(f3.x), resid(f3.y)); qlB.w = packbf(resid(f3.z), resid(f3.w));
  }
  const int sw = srow & 3, g0 = shalf * 2;
  const int d0s = srow * 32 + ((g0 ^ sw) << 3);
  const int d1s = srow * 32 + (((g0 + 1) ^ sw) << 3);
  for (int kb = 0; kb < 32; ++kb) {
    __syncthreads();
    *(uint4*)&Ph[d0s] = phA; *(uint4*)&Ph[d1s] = phB;
    *(uint4*)&Pl[d0s] = plA; *(uint4*)&Pl[d1s] = plB;
    *(uint4*)&Qh[d0s] = qhA; *(uint4*)&Qh[d1s] = qhB;
    *(uint4*)&Ql[d0s] = qlA; *(uint4*)&Ql[d1s] = qlB;
    __syncthreads();
    if (kb < 31) {
      int ko = (kb + 1) * 32;
      phA = *(const uint4*)(Ph_p + ko);
      phB = *(const uint4*)(Ph_p + ko + 8);
      plA = *(const uint4*)(Pl_p + ko);
      plB = *(const uint4*)(Pl_p + ko + 8);
      const float* xp = Xf + ko;
      float4 f0 = *(const float4*)(xp), f1 = *(const float4*)(xp + 4);
      float4 f2 = *(const float4*)(xp + 8), f3 = *(const float4*)(xp + 12);
      qhA.x = packhi(f0.x, f0.y); qhA.y = packhi(f0.z, f0.w);
      qhA.z = packhi(f1.x, f1.y); qhA.w = packhi(f1.z, f1.w);
      qhB.x = packhi(f2.x, f2.y); qhB.y = packhi(f2.z, f2.w);
      qhB.z = packhi(f3.x, f3.y); qhB.w = packhi(f3.z, f3.w);
      qlA.x = packbf(resid(f0.x), resid(f0.y)); qlA.y = packbf(resid(f0.z), resid(f0.w));
      qlA.z = packbf(resid(f1.x), resid(f1.y)); qlA.w = packbf(resid(f1.z), resid(f1.w));
      qlB.x = packbf(resid(f2.x), resid(f2.y)); qlB.y = packbf(resid(f2.z), resid(f2.w));
      qlB.z = packbf(resid(f3.x), resid(f3.y)); qlB.w = packbf(resid(f3.z), resid(f3.w));
    }
    short8 ph[4], pl[4], qh[4], ql[4];
#pragma unroll
    for (int ti = 0; ti < 4; ti++) {
      int ro = (prw + ti * 16 + lm) * 32 + sg;
      ph[ti] = *(const short8*)&Ph[ro];
      pl[ti] = *(const short8*)&Pl[ro];
    }
#pragma unroll
    for (int tj = 0; tj < 4; tj++) {
      int ro = (qcw + tj * 16 + lm) * 32 + sg;
      qh[tj] = *(const short8*)&Qh[ro];
      ql[tj] = *(const short8*)&Ql[ro];
    }
#pragma unroll
    for (int ti = 0; ti < 4; ti++)
#pragma unroll
      for (int tj = 0; tj < 4; tj++) {
        f32x4 a = acc[ti][tj];
        a = __builtin_amdgcn_mfma_f32_16x16x32_bf16(ph[ti], qh[tj], a, 0, 0, 0);
        a = __builtin_amdgcn_mfma_f32_16x16x32_bf16(ph[ti], ql[tj], a, 0, 0, 0);
        a = __builtin_amdgcn_mfma_f32_16x16x32_bf16(pl[ti], qh[tj], a, 0, 0, 0);
        acc[ti][tj] = a;
      }
  }
  const int head = bi & 7;
#pragma unroll
  for (int tj = 0; tj < 4; tj++) {
    int mm = qb + qcw + tj * 16 + lm;
    int b = mm >> 12, l = mm & 4095;
    float* op = outF + ((size_t)(b * NH_ + head) * L_ + l) * DK_;
#pragma unroll
    for (int ti = 0; ti < 4; ti++) {
      int d0 = prw + ti * 16 + quad * 4;
      float4 w;
      w.x = acc[ti][tj][0] + bias_s[d0];
      w.y = acc[ti][tj][1] + bias_s[d0 + 1];
      w.z = acc[ti][tj][2] + bias_s[d0 + 2];
      w.w = acc[ti][tj][3] + bias_s[d0 + 3];
      *(float4*)(op + d0) = w;
    }
  }
}

// ---------------- bf16 MFMA GEMM ----------------
// C[p][q] = sum_k P[p][k] * Q[q][k]  (both operands row-major-K)
// MODE 0: P = aout bf16 rows(m), Q = Wt_o rows(n); C[m][n] f32 + bias[n] -> outF
// MODE 2: P = Wt_v rows(n=d of head), Q = x2 f32 rows(m); C^T -> bf16 (b,h,l,d)
template <int MODE>
__global__ __launch_bounds__(256) void gemm_bf(const unsigned short* __restrict__ Pm,
                                               const void* __restrict__ Qv,
                                               const float* __restrict__ bias,
                                               float* __restrict__ outF,
                                               unsigned int* __restrict__ outW) {
  __shared__ __align__(16) unsigned short Ps[128 * 32];
  __shared__ __align__(16) unsigned short Qs[128 * 32];
  __shared__ float bias_s[128];
  const int t = threadIdx.x;
  const int bi = blockIdx.x;
  const int pb = (MODE == 0) ? ((bi >> 3) << 7) : ((bi & 7) << 7);
  const int qb = (MODE == 0) ? ((bi & 7) << 7) : ((bi >> 3) << 7);
  if (t < 128) bias_s[t] = bias[((MODE == 0) ? qb : pb) + t];
  const int srow = t >> 1, shalf = t & 1;
  const unsigned short* Pp = Pm + (size_t)(pb + srow) * DM_ + shalf * 16;
  const float* Qf = (const float*)Qv + (size_t)(qb + srow) * DM_ + shalf * 16;
  const unsigned short* Qh = (const unsigned short*)Qv + (size_t)(qb + srow) * DM_ + shalf * 16;
  const int lane = t & 63, wid = t >> 6;
  const int lm = lane & 15, quad = lane >> 4;
  const int prw = (wid & 1) << 6, qcw = (wid >> 1) << 6;
  f32x4 acc[4][4];
#pragma unroll
  for (int i = 0; i < 4; i++)
#pragma unroll
    for (int j = 0; j < 4; j++) acc[i][j] = (f32x4){0.f, 0.f, 0.f, 0.f};
  uint4 pA, pB, qA, qB;
  {  // preload kb=0
    pA = *(const uint4*)(Pp);
    pB = *(const uint4*)(Pp + 8);
    if (MODE == 2) {
      float4 f0 = *(const float4*)(Qf), f1 = *(const float4*)(Qf + 4);
      float4 f2 = *(const float4*)(Qf + 8), f3 = *(const float4*)(Qf + 12);
      qA.x = packbf(f0.x, f0.y); qA.y = packbf(f0.z, f0.w);
      qA.z = packbf(f1.x, f1.y); qA.w = packbf(f1.z, f1.w);
      qB.x = packbf(f2.x, f2.y); qB.y = packbf(f2.z, f2.w);
      qB.z = packbf(f3.x, f3.y); qB.w = packbf(f3.z, f3.w);
    } else {
      qA = *(const uint4*)(Qh);
      qB = *(const uint4*)(Qh + 8);
    }
  }
  const int sdst = srow * 32 + shalf * 16;
  for (int kb = 0; kb < 32; ++kb) {
    __syncthreads();
    *(uint4*)&Ps[sdst] = pA;
    *(uint4*)&Ps[sdst + 8] = pB;
    *(uint4*)&Qs[sdst] = qA;
    *(uint4*)&Qs[sdst + 8] = qB;
    __syncthreads();
    if (kb < 31) {
      int ko = (kb + 1) * 32;
      pA = *(const uint4*)(Pp + ko);
      pB = *(const uint4*)(Pp + ko + 8);
      if (MODE == 2) {
        const float* qp = Qf + ko;
        float4 f0 = *(const float4*)(qp), f1 = *(const float4*)(qp + 4);
        float4 f2 = *(const float4*)(qp + 8), f3 = *(const float4*)(qp + 12);
        qA.x = packbf(f0.x, f0.y); qA.y = packbf(f0.z, f0.w);
        qA.z = packbf(f1.x, f1.y); qA.w = packbf(f1.z, f1.w);
        qB.x = packbf(f2.x, f2.y); qB.y = packbf(f2.z, f2.w);
        qB.z = packbf(f3.x, f3.y); qB.w = packbf(f3.z, f3.w);
      } else {
        qA = *(const uint4*)(Qh + ko);
        qB = *(const uint4*)(Qh + ko + 8);
      }
    }
    short8 pf[4], qf[4];
#pragma unroll
    for (int ti = 0; ti < 4; ti++)
      pf[ti] = *(const short8*)&Ps[(prw + ti * 16 + lm) * 32 + quad * 8];
#pragma unroll
    for (int tj = 0; tj < 4; tj++)
      qf[tj] = *(const short8*)&Qs[(qcw + tj * 16 + lm) * 32 + quad * 8];
#pragma unroll
    for (int ti = 0; ti < 4; ti++)
#pragma unroll
      for (int tj = 0; tj < 4; tj++)
        acc[ti][tj] = __builtin_amdgcn_mfma_f32_16x16x32_bf16(pf[ti], qf[tj], acc[ti][tj], 0, 0, 0);
  }
  if (MODE == 0) {
#pragma unroll
    for (int ti = 0; ti < 4; ti++) {
      int m = pb + prw + ti * 16 + quad * 4;
#pragma unroll
      for (int tj = 0; tj < 4; tj++) {
        int nn = qcw + tj * 16 + lm;
        float bn = bias_s[nn];
        float* op = outF + (size_t)m * DM_ + qb + nn;
#pragma unroll
        for (int r = 0; r < 4; r++) op[(size_t)r * DM_] = acc[ti][tj][r] + bn;
      }
    }
  } else {
    const int head = bi & 7;
#pragma unroll
    for (int tj = 0; tj < 4; tj++) {
      int mm = qb + qcw + tj * 16 + lm;
      int b = mm >> 12, l = mm & 4095;
#pragma unroll
      for (int ti = 0; ti < 4; ti++) {
        int d0 = prw + ti * 16 + quad * 4;
        uint2 ov;
        ov.x = packbf(acc[ti][tj][0] + bias_s[d0], acc[ti][tj][1] + bias_s[d0 + 1]);
        ov.y = packbf(acc[ti][tj][2] + bias_s[d0 + 2], acc[ti][tj][3] + bias_s[d0 + 3]);
        *(uint2*)(outW + ((size_t)(b * NH_ + head) * L_ + l) * 64 + (d0 >> 1)) = ov;
      }
    }
  }
}

// ---------------- Hash GEMM: proj = qbuf x rotT (split-bf16 MFMA), fused argmax
// grid 1024: token block of 128; per block full 128 proj values per token in LDS.
#define HSTR 132
__global__ __launch_bounds__(256) void hashg_k(const unsigned short* __restrict__ Rhi,
                                               const unsigned short* __restrict__ Rlo,
                                               const float* __restrict__ q,
                                               unsigned char* __restrict__ hout,
                                               int* __restrict__ cnt,
                                               int* __restrict__ flags) {
  __shared__ __align__(16) char smraw[128 * HSTR * 4];
  unsigned short* Ph = (unsigned short*)smraw;
  unsigned short* Pl = Ph + 4096;
  unsigned short* Qh = Ph + 8192;
  unsigned short* Ql = Ph + 12288;
  float* S = (float*)smraw;
  const int t = threadIdx.x;
  const int bi = blockIdx.x;
  const int srow = t >> 1, shalf = t & 1;
  const unsigned short* Php = Rhi + srow * 128 + shalf * 16;
  const unsigned short* Plp = Rlo + srow * 128 + shalf * 16;
  const float* Qf = q + (size_t)(bi * 128 + srow) * DK_ + shalf * 16;
  const int lane = t & 63, wid = t >> 6;
  const int lm = lane & 15, quad = lane >> 4;
  const int prw = (wid & 1) << 6, qcw = (wid >> 1) << 6;
  const int sg = (quad ^ (lm & 3)) << 3;
  f32x4 acc[4][4];
#pragma unroll
  for (int i = 0; i < 4; i++)
#pragma unroll
    for (int j = 0; j < 4; j++) acc[i][j] = (f32x4){0.f, 0.f, 0.f, 0.f};
  const int sw = srow & 3, g0 = shalf * 2;
  const int d0s = srow * 32 + ((g0 ^ sw) << 3);
  const int d1s = srow * 32 + (((g0 + 1) ^ sw) << 3);
  for (int kb = 0; kb < 4; ++kb) {
    const int ko = kb * 32;
    uint4 phA = *(const uint4*)(Php + ko);
    uint4 phB = *(const uint4*)(Php + ko + 8);
    uint4 plA = *(const uint4*)(Plp + ko);
    uint4 plB = *(const uint4*)(Plp + ko + 8);
    const float* xp = Qf + ko;
    float4 f0 = *(const float4*)(xp), f1 = *(const float4*)(xp + 4);
    float4 f2 = *(const float4*)(xp + 8), f3 = *(const float4*)(xp + 12);
    uint4 qhA, qhB, qlA, qlB;
    qhA.x = packhi(f0.x, f0.y); qhA.y = packhi(f0.z, f0.w);
    qhA.z = packhi(f1.x, f1.y); qhA.w = packhi(f1.z, f1.w);
    qhB.x = packhi(f2.x, f2.y); qhB.y = packhi(f2.z, f2.w);
    qhB.z = packhi(f3.x, f3.y); qhB.w = packhi(f3.z, f3.w);
    qlA.x = packbf(resid(f0.x), resid(f0.y)); qlA.y = packbf(resid(f0.z), resid(f0.w));
    qlA.z = packbf(resid(f1.x), resid(f1.y)); qlA.w = packbf(resid(f1.z), resid(f1.w));
    qlB.x = packbf(resid(f2.x), resid(f2.y)); qlB.y = packbf(resid(f2.z), resid(f2.w));
    qlB.z = packbf(resid(f3.x), resid(f3.y)); qlB.w = packbf(resid(f3.z), resid(f3.w));
    __syncthreads();
    *(uint4*)&Ph[d0s] = phA; *(uint4*)&Ph[d1s] = phB;
    *(uint4*)&Pl[d0s] = plA; *(uint4*)&Pl[d1s] = plB;
    *(uint4*)&Qh[d0s] = qhA; *(uint4*)&Qh[d1s] = qhB;
    *(uint4*)&Ql[d0s] = qlA; *(uint4*)&Ql[d1s] = qlB;
    __syncthreads();
    short8 ph[4], pl[4], qh[4], ql[4];
#pragma unroll
    for (int ti = 0; ti < 4; ti++) {
      int ro = (prw + ti * 16 + lm) * 32 + sg;
      ph[ti] = *(const short8*)&Ph[ro];
      pl[ti] = *(const short8*)&Pl[ro];
    }
#pragma unroll
    for (int tj = 0; tj < 4; tj++) {
      int ro = (qcw + tj * 16 + lm) * 32 + sg;
      qh[tj] = *(const short8*)&Qh[ro];
      ql[tj] = *(const short8*)&Ql[ro];
    }
#pragma unroll
    for (int ti = 0; ti < 4; ti++)
#pragma unroll
      for (int tj = 0; tj < 4; tj++) {
        f32x4 a = acc[ti][tj];
        a = __builtin_amdgcn_mfma_f32_16x16x32_bf16(ph[ti], qh[tj], a, 0, 0, 0);
        a = __builtin_amdgcn_mfma_f32_16x16x32_bf16(ph[ti], ql[tj], a, 0, 0, 0);
        a = __builtin_amdgcn_mfma_f32_16x16x32_bf16(pl[ti], qh[tj], a, 0, 0, 0);
        acc[ti][tj] = a;
      }
  }
  __syncthreads();
#pragma unroll
  for (int ti = 0; ti < 4; ti++)
#pragma unroll
    for (int tj = 0; tj < 4; tj++) {
      int nn = qcw + tj * 16 + lm;
#pragma unroll
      for (int r = 0; r < 4; r++)
        S[(prw + ti * 16 + quad * 4 + r) * HSTR + nn] = acc[ti][tj][r];
    }
  __syncthreads();
#pragma unroll
  for (int pp = t; pp < 512; pp += 256) {
    int tok = pp & 127, r = pp >> 7;
    float best = -1.f, second = -1.f;
    int bidx = 0;
#pragma unroll
    for (int n = 0; n < 32; n++) {
      float v = S[(r * 32 + n) * HSTR + tok];
      float av = fabsf(v);
      int idx = (v >= 0.f) ? n : (n + 32);
      if (av > best) {
        second = best; best = av; bidx = idx;
      } else {
        if (av == best && idx < bidx) bidx = idx;
        second = fmaxf(second, av);
      }
    }
    int mm = bi * 128 + tok;
    int bh = mm >> 12, l = mm & 4095;
    hout[((size_t)(bh * NR_ + r)) * L_ + l] = (unsigned char)bidx;
    if (best - second < TAU) {
      int slot = atomicAdd(cnt, 1);
      if (slot < FCAP) flags[slot] = (((bh << 2) | r) << 12) | l;
    }
  }
}

// ---------------- exact f32 recompute of flagged (near-tie) hashes ---------
__global__ __launch_bounds__(256) void fixup_k(const int* __restrict__ cnt,
                                               const int* __restrict__ flags,
                                               const float* __restrict__ X,
                                               const float* __restrict__ Wp,
                                               unsigned char* __restrict__ hout) {
  __shared__ float xs[1024];
  __shared__ float pv[32];
  int nflag = *cnt;
  if (nflag > FCAP) nflag = FCAP;
  const int t = threadIdx.x;
  for (int i = blockIdx.x; i < nflag; i += gridDim.x) {
    int f = flags[i];
    int l = f & 4095, r = (f >> 12) & 3, bh = f >> 14;
    int b = bh >> 3, h = bh & 7;
    __syncthreads();  // protect xs/pv from previous iteration readers
    ((float4*)xs)[t] = ((const float4*)(X + ((size_t)b * L_ + l) * DM_))[t];
    __syncthreads();
    const int nn = t >> 3, kl = t & 7;
    const float* wrow = Wp + ((size_t)(h * 4 + r) * 32 + nn) * 1024 + kl * 4;
    float s = 0.f;
#pragma unroll 8
    for (int k0 = 0; k0 < 1024; k0 += 32) {
      float4 wv = *(const float4*)(wrow + k0);
      float4 xv = *(const float4*)(xs + k0 + kl * 4);
      s = fmaf(wv.x, xv.x, fmaf(wv.y, xv.y, fmaf(wv.z, xv.z, fmaf(wv.w, xv.w, s))));
    }
    s += __shfl_xor(s, 1);
    s += __shfl_xor(s, 2);
    s += __shfl_xor(s, 4);
    if (kl == 0) pv[nn] = s;
    __syncthreads();
    if (t == 0) {
      float bestv = -1.f;
      int besti = 0;
      for (int j = 0; j < 32; j++) {
        float p = pv[j];
        float ap = fabsf(p);
        int idx = (p >= 0.f) ? j : (j + 32);
        if (ap > bestv || (ap == bestv && idx < besti)) { bestv = ap; besti = idx; }
      }
      hout[((size_t)(bh * NR_ + r)) * L_ + l] = (unsigned char)besti;
    }
  }
}

// ---------------- Stable counting sort per (b,h,r) ----------------
__global__ __launch_bounds__(256) void sort_k(const unsigned char* __restrict__ hsh,
                                              int* __restrict__ sidx) {
  __shared__ unsigned char seg[256 * 64];
  __shared__ unsigned short grp[16 * 64];
  __shared__ int offs[64];
  __shared__ int tot[64];
  const int t = threadIdx.x;
  const int bhr = blockIdx.x;
  uint4 hv = ((const uint4*)(hsh + (size_t)bhr * L_))[t];
  unsigned hb[4] = {hv.x, hv.y, hv.z, hv.w};
  unsigned int* seg32 = (unsigned int*)seg;
#pragma unroll
  for (int i = 0; i < 16; i++) seg32[t * 16 + i] = 0;
  ((unsigned int*)grp)[t * 2] = 0;
  ((unsigned int*)grp)[t * 2 + 1] = 0;
  __syncthreads();
#pragma unroll
  for (int k = 0; k < 16; k++) {
    int h = (hb[k >> 2] >> ((k & 3) * 8)) & 0xFF;
    seg[t * 64 + h] = (unsigned char)(seg[t * 64 + h] + 1);
  }
  __syncthreads();
  {
    int h = t & 63;
    for (int g = (t >> 6); g < 16; g += 4) {
      int run = 0;
      for (int s = 0; s < 16; s++) {
        int idx = ((g << 4) + s) * 64 + h;
        int c = seg[idx];
        seg[idx] = (unsigned char)run;
        run += c;
      }
      grp[g * 64 + h] = (unsigned short)run;
    }
  }
  __syncthreads();
  if (t < 64) {
    int run = 0;
    for (int g = 0; g < 16; g++) {
      int c = grp[g * 64 + t];
      grp[g * 64 + t] = (unsigned short)run;
      run += c;
    }
    tot[t] = run;
  }
  __syncthreads();
  if (t == 0) {
    int run = 0;
    for (int h = 0; h < 64; h++) { offs[h] = run; run += tot[h]; }
  }
  __syncthreads();
  const int gbase = (t >> 4) * 64;
  int* outp = sidx + (size_t)bhr * L_;
#pragma unroll
  for (int k = 0; k < 16; k++) {
    int h = (hb[k >> 2] >> ((k & 3) * 8)) & 0xFF;
    int pos = offs[h] + grp[gbase + h] + seg[t * 64 + h];
    seg[t * 64 + h] = (unsigned char)(seg[t * 64 + h] + 1);
    outp[pos] = t * 16 + k;
  }
}

// ---------------- Chunked look-back attention (MFMA) ----------------
#define KSTR 136
__global__ __launch_bounds__(256) void attn_k(const float* __restrict__ q,
                                              const unsigned int* __restrict__ vwg,
                                              const int* __restrict__ sidx,
                                              float* __restrict__ lseG,
                                              unsigned int* __restrict__ oW) {
  __shared__ __align__(16) unsigned short R1[128 * KSTR];
  __shared__ __align__(16) unsigned short R2[64 * KSTR];
  __shared__ int idxs[128];
  __shared__ float rowsum[64];
  const int t = threadIdx.x;
  const int c = blockIdx.x & 63;
  const int bhr = blockIdx.x >> 6;
  const int bh = bhr >> 2;
  const int pc = (c + 63) & 63;
  if (t < 128) {
    int sp = (t < 64) ? (pc * 64 + t) : (c * 64 + t - 64);
    idxs[t] = sidx[(size_t)bhr * L_ + sp];
  }
  __syncthreads();
  {
    const int row = t >> 1, half = t & 1;
    const float4* qp = (const float4*)(q + ((size_t)bh * L_ + idxs[row]) * DK_ + half * 64);
    float4 f[16];
    float ss = 0.f;
#pragma unroll
    for (int u = 0; u < 16; u++) {
      f[u] = qp[u];
      ss = fmaf(f[u].x, f[u].x, fmaf(f[u].y, f[u].y, fmaf(f[u].z, f[u].z, fmaf(f[u].w, f[u].w, ss))));
    }
    ss += __shfl_xor(ss, 1);
    float rn = 1.f / (sqrtf(ss) + 1e-9f);
    unsigned short* kr = R1 + row * KSTR + half * 64;
#pragma unroll
    for (int u = 0; u < 8; u++) {
      uint4 w4;
      w4.x = packbf(f[2 * u].x * rn, f[2 * u].y * rn);
      w4.y = packbf(f[2 * u].z * rn, f[2 * u].w * rn);
      w4.z = packbf(f[2 * u + 1].x * rn, f[2 * u + 1].y * rn);
      w4.w = packbf(f[2 * u + 1].z * rn, f[2 * u + 1].w * rn);
      *(uint4*)(kr + u * 8) = w4;
    }
    if (row >= 64) {
      unsigned short* qr = R2 + (row - 64) * KSTR + half * 64;
#pragma unroll
      for (int u = 0; u < 8; u++) {
        uint4 w4;
        w4.x = packbf(f[2 * u].x, f[2 * u].y);
        w4.y = packbf(f[2 * u].z, f[2 * u].w);
        w4.z = packbf(f[2 * u + 1].x, f[2 * u + 1].y);
        w4.w = packbf(f[2 * u + 1].z, f[2 * u + 1].w);
        *(uint4*)(qr + u * 8) = w4;
      }
    }
  }
  __syncthreads();
  const int lane = t & 63, wv = t >> 6;
  const int m0 = wv * 16;
  const int lm = lane & 15, quad = lane >> 4;
  f32x4 acc[8];
  {
    short8 af[4];
#pragma unroll
    for (int ks = 0; ks < 4; ks++)
      af[ks] = *(const short8*)(R2 + (m0 + lm) * KSTR + ks * 32 + quad * 8);
#pragma unroll
    for (int n = 0; n < 8; n++) {
      f32x4 a = {0.f, 0.f, 0.f, 0.f};
#pragma unroll
      for (int ks = 0; ks < 4; ks++) {
        short8 bf = *(const short8*)(R1 + (n * 16 + lm) * KSTR + ks * 32 + quad * 8);
        a = __builtin_amdgcn_mfma_f32_16x16x32_bf16(af[ks], bf, a, 0, 0, 0);
      }
      acc[n] = a;
    }
  }
  {
    int qp4[4];
#pragma unroll
    for (int r = 0; r < 4; r++) qp4[r] = idxs[64 + m0 + quad * 4 + r];
#pragma unroll
    for (int n = 0; n < 8; n++) {
      int key = n * 16 + lm;
      int kp = idxs[key];
#pragma unroll
      for (int r = 0; r < 4; r++) {
        float s = acc[n][r] * (1.f / SQRTDK);
        s = (kp > qp4[r]) ? NEGV : ((kp == qp4[r]) ? SELFP : s);
        R2[(m0 + quad * 4 + r) * KSTR + key] = f2bf(s);
      }
    }
  }
  uint4 vv[8];
  {
    const int key = t >> 1, half = t & 1;
    const uint4* vp = (const uint4*)(vwg + ((size_t)bh * L_ + idxs[key]) * 64 + half * 32);
#pragma unroll
    for (int u = 0; u < 8; u++) vv[u] = vp[u];
  }
  {
    const int row = t >> 2, seg = t & 3;
    unsigned short* sp = R2 + row * KSTR + seg * 32;
    uint4 sv4[4];
    float m = -3.0e38f;
#pragma unroll
    for (int u = 0; u < 4; u++) {
      sv4[u] = *(uint4*)(sp + u * 8);
      unsigned wd[4] = {sv4[u].x, sv4[u].y, sv4[u].z, sv4[u].w};
#pragma unroll
      for (int cc = 0; cc < 4; cc++) {
        m = fmaxf(m, wlo(wd[cc]));
        m = fmaxf(m, whi(wd[cc]));
      }
    }
    m = fmaxf(m, __shfl_xor(m, 1));
    m = fmaxf(m, __shfl_xor(m, 2));
    float sum = 0.f;
#pragma unroll
    for (int u = 0; u < 4; u++) {
      unsigned wd[4] = {sv4[u].x, sv4[u].y, sv4[u].z, sv4[u].w};
      unsigned ow[4];
#pragma unroll
      for (int cc = 0; cc < 4; cc++) {
        float e0 = expf(wlo(wd[cc]) - m);
        float e1 = expf(whi(wd[cc]) - m);
        unsigned short b0 = f2bf(e0), b1 = f2bf(e1);
        sum += bf2f(b0) + bf2f(b1);
        ow[cc] = (unsigned)b0 | (((unsigned)b1) << 16);
      }
      uint4 o4;
      o4.x = ow[0]; o4.y = ow[1]; o4.z = ow[2]; o4.w = ow[3];
      *(uint4*)(sp + u * 8) = o4;
    }
    sum += __shfl_xor(sum, 1);
    sum += __shfl_xor(sum, 2);
    if (seg == 0) {
      rowsum[row] = sum;
      lseG[(size_t)bhr * L_ + idxs[64 + row]] = m + logf(sum);
    }
  }
  __syncthreads();
  {
    const int key = t >> 1, half = t & 1;
#pragma unroll
    for (int u = 0; u < 8; u++) {
      unsigned wd[4] = {vv[u].x, vv[u].y, vv[u].z, vv[u].w};
#pragma unroll
      for (int cc = 0; cc < 4; cc++) {
        int w = half * 32 + u * 4 + cc;
        R1[(2 * w) * KSTR + key] = (unsigned short)(wd[cc] & 0xFFFFu);
        R1[(2 * w + 1) * KSTR + key] = (unsigned short)(wd[cc] >> 16);
      }
    }
  }
  __syncthreads();
  f32x4 acc2[8];
  {
    short8 af[4];
#pragma unroll
    for (int ks = 0; ks < 4; ks++)
      af[ks] = *(const short8*)(R2 + (m0 + lm) * KSTR + ks * 32 + quad * 8);
#pragma unroll
    for (int n = 0; n < 8; n++) {
      f32x4 a = {0.f, 0.f, 0.f, 0.f};
#pragma unroll
      for (int ks = 0; ks < 4; ks++) {
        short8 bf = *(const short8*)(R1 + (n * 16 + lm) * KSTR + ks * 32 + quad * 8);
        a = __builtin_amdgcn_mfma_f32_16x16x32_bf16(af[ks], bf, a, 0, 0, 0);
      }
      acc2[n] = a;
    }
  }
  {
    float inv[4];
#pragma unroll
    for (int r = 0; r < 4; r++) inv[r] = 1.f / rowsum[m0 + quad * 4 + r];
#pragma unroll
    for (int n = 0; n < 8; n++)
#pragma unroll
      for (int r = 0; r < 4; r++)
        R2[(m0 + quad * 4 + r) * KSTR + n * 16 + lm] = f2bf(acc2[n][r] * inv[r]);
  }
  __syncthreads();
  {
    const int row = t >> 2, seg = t & 3;
    int l = idxs[64 + row];
    unsigned int* op = oW + ((size_t)bhr * L_ + l) * 64 + seg * 16;
    const unsigned short* rp = R2 + row * KSTR + seg * 32;
#pragma unroll
    for (int u = 0; u < 4; u++) *(uint4*)(op + u * 4) = *(const uint4*)(rp + u * 8);
  }
}

// ---------------- Round-softmax merge -> bf16 aout words ----------------
__global__ __launch_bounds__(256) void comb_k(const float* __restrict__ lse,
                                              const unsigned int* __restrict__ oW,
                                              unsigned int* __restrict__ aoutW) {
  size_t g = (size_t)blockIdx.x * 256 + threadIdx.x;
  int w = (int)(g & 63);
  int l = (int)((g >> 6) & 4095);
  int bh = (int)(g >> 18);
  float ls[4];
#pragma unroll
  for (int r = 0; r < 4; r++) ls[r] = lse[((size_t)(bh * 4 + r)) * L_ + l];
  float m = fmaxf(fmaxf(ls[0], ls[1]), fmaxf(ls[2], ls[3]));
  float wsum = 0.f, a0 = 0.f, a1 = 0.f;
#pragma unroll
  for (int r = 0; r < 4; r++) {
    float e = expf(ls[r] - m);
    wsum += e;
    unsigned ow = oW[(((size_t)(bh * 4 + r)) * L_ + l) * 64 + w];
    a0 = fmaf(e, wlo(ow), a0);
    a1 = fmaf(e, whi(ow), a1);
  }
  float inv = 1.f / wsum;
  int b = bh >> 3, h = bh & 7;
  // aout bf16 row-major [m][k] as words: m*512 + h*64 + w
  aoutW[((size_t)b * L_ + l) * 512 + h * 64 + w] = packbf(a0 * inv, a1 * inv);
}

// ---------------- LayerNorm + residual + x2 passthrough ----------------
__global__ __launch_bounds__(256) void ln_k(const float* __restrict__ a,
                                            const float* __restrict__ x1,
                                            const float* __restrict__ x2,
                                            const float* __restrict__ gamma,
                                            const float* __restrict__ beta,
                                            float* __restrict__ out) {
  __shared__ float red[256];
  __shared__ float red2[256];
  const int t = threadIdx.x;
  const size_t row = blockIdx.x;
  float4 av = *(const float4*)(a + row * DM_ + t * 4);
  red[t] = av.x + av.y + av.z + av.w;
  red2[t] = av.x * av.x + av.y * av.y + av.z * av.z + av.w * av.w;
  __syncthreads();
  for (int off = 128; off > 0; off >>= 1) {
    if (t < off) { red[t] += red[t + off]; red2[t] += red2[t + off]; }
    __syncthreads();
  }
  float mu = red[0] * (1.f / 1024.f);
  float var = red2[0] * (1.f / 1024.f) - mu * mu;
  float rstd = rsqrtf(var + 1e-5f);
  float4 g4 = *(const float4*)(gamma + t * 4);
  float4 b4 = *(const float4*)(beta + t * 4);
  float4 x14 = *(const float4*)(x1 + row * DM_ + t * 4);
  float4 o4;
  o4.x = x14.x + (av.x - mu) * rstd * g4.x + b4.x;
  o4.y = x14.y + (av.y - mu) * rstd * g4.y + b4.y;
  o4.z = x14.z + (av.z - mu) * rstd * g4.z + b4.z;
  o4.w = x14.w + (av.w - mu) * rstd * g4.w + b4.w;
  *(float4*)(out + row * DM_ + t * 4) = o4;
  float4 x24 = *(const float4*)(x2 + row * DM_ + t * 4);
  *(float4*)(out + (size_t)B_ * L_ * DM_ + row * DM_ + t * 4) = x24;
}

extern "C" void kernel_launch(void* const* d_in, const int* in_sizes, int n_in,
                              void* d_out, int out_size, void* d_ws, size_t ws_size,
                              hipStream_t stream) {
  const float* x1 = (const float*)d_in[0];
  const float* x2 = (const float*)d_in[1];
  const float* wq = (const float*)d_in[2];
  const float* bq = (const float*)d_in[3];
  const float* wv = (const float*)d_in[4];
  const float* bv = (const float*)d_in[5];
  const float* wo = (const float*)d_in[6];
  const float* bo = (const float*)d_in[7];
  const float* gamma = (const float*)d_in[8];
  const float* beta = (const float*)d_in[9];
  const float* rot = (const float*)d_in[10];

  char* ws = (char*)d_ws;
  float* qbuf = (float*)ws;                                 // 64 MB f32 q (b,h,l,d)
  unsigned int* vbuf = (unsigned int*)(ws + 67108864);      // 32 MB bf16 v (b,h,l,d)
  unsigned char* hbuf = (unsigned char*)(ws + 100663296);   // 512 KB hashes
  int* sbuf = (int*)(ws + 101187584);                       // 2 MB sort_idx
  float* lbuf = (float*)(ws + 103284736);                   // 2 MB lse
  unsigned int* obuf = (unsigned int*)(ws + 105381888);     // 128 MB bf16 o
  float* abuf = (float*)(ws + 105381888);                   // 64 MB f32 (alias obuf head)
  // dead-phase buffers inside obuf range (all consumed before attn_k writes obuf):
  unsigned short* wtqh = (unsigned short*)(ws + 105381888); // 2 MB wq hi bf16 [n][k]
  unsigned short* wtql = (unsigned short*)(ws + 107479040); // 2 MB wq lo bf16 [n][k]
  float* wproj = (float*)(ws + 109576192);                  // 4 MB Wproj [h][r][n][k]
  int* flags = (int*)(ws + 113770496);                      // 2 MB flag list
  int* cntb = (int*)(ws + 115867648);                       // 4 B flag counter
  unsigned short* rthi = (unsigned short*)(ws + 115871744); // 32 KB rotT hi bf16 [n'][d]
  unsigned short* rtlo = (unsigned short*)(ws + 115904512); // 32 KB rotT lo bf16 [n'][d]
  unsigned short* wtv = (unsigned short*)(ws + 172490752);  // 2 MB (obuf tail, dead phase)
  unsigned short* wto = (unsigned short*)(ws + 174587904);  // 2 MB (obuf tail, dead phase)
  unsigned int* aoutW = (unsigned int*)ws;                  // 32 MB bf16 aout (alias qbuf)
  float* out = (float*)d_out;

  dim3 blk(256);
  cvtw2_k<<<dim3(256), blk, 0, stream>>>(wq, wtqh, wtql);
  wproj_k<<<dim3(4096), blk, 0, stream>>>(wq, rot, wproj, cntb);
  cvtrot_k<<<dim3(64), blk, 0, stream>>>(rot, rthi, rtlo);
  gemm_qs<<<dim3(1024), blk, 0, stream>>>(wtqh, wtql, x2, bq, qbuf);
  cvtw_k<<<dim3(256), blk, 0, stream>>>(wv, wtv);
  gemm_bf<2><<<dim3(1024), blk, 0, stream>>>(wtv, (const void*)x2, bv, nullptr, vbuf);
  hashg_k<<<dim3(1024), blk, 0, stream>>>(rthi, rtlo, qbuf, hbuf, cntb, flags);
  fixup_k<<<dim3(1024), blk, 0, stream>>>(cntb, flags, x2, wproj, hbuf);
  sort_k<<<dim3(128), blk, 0, stream>>>(hbuf, sbuf);
  attn_k<<<dim3(8192), blk, 0, stream>>>(qbuf, vbuf, sbuf, lbuf, obuf);
  comb_k<<<dim3(32768), blk, 0, stream>>>(lbuf, obuf, aoutW);
  cvtw_k<<<dim3(256), blk, 0, stream>>>(wo, wto);
  gemm_bf<0><<<dim3(1024), blk, 0, stream>>>((const unsigned short*)aoutW, (const void*)wto,
                                             bo, abuf, nullptr);
  ln_k<<<dim3(16384), blk, 0, stream>>>(abuf, x1, x2, gamma, beta, out);
}

// Round 5
// 802.698 us; speedup vs baseline: 1.6243x; 1.0195x over previous
//
#include <hip/hip_runtime.h>
#include <hip/hip_bf16.h>

#define B_ 4
#define L_ 4096
#define DM_ 1024
#define NH_ 8
#define DK_ 128
#define NR_ 4
#define NC_ 64
#define NEGV -1.0e9f
#define SELFP -1.0e5f
#define SQRTDK 11.313708498984761f
#define TAU 1.0e-3f
#define FCAP 524288
#define LOG2E 1.4426950408889634f
#define LN2 0.6931471805599453f

typedef __attribute__((ext_vector_type(8))) short short8;
typedef __attribute__((ext_vector_type(4))) float f32x4;

__device__ __forceinline__ unsigned short f2bf(float x) {
  unsigned u = __float_as_uint(x);
  u += 0x7FFFu + ((u >> 16) & 1u);
  return (unsigned short)(u >> 16);
}
__device__ __forceinline__ float bf2f(unsigned short h) {
  return __uint_as_float(((unsigned)h) << 16);
}
__device__ __forceinline__ float wlo(unsigned w) { return __uint_as_float(w << 16); }
__device__ __forceinline__ float whi(unsigned w) { return __uint_as_float(w & 0xFFFF0000u); }
// HW packed f32->bf16 (RNE, identical to f2bf on finite values): 1 instr vs ~11.
__device__ __forceinline__ unsigned packbf(float a, float b) {
  unsigned r;
  asm("v_cvt_pk_bf16_f32 %0, %1, %2" : "=v"(r) : "v"(a), "v"(b));
  return r;
}
__device__ __forceinline__ float fexp2(float x) {
  float r;
  asm("v_exp_f32 %0, %1" : "=v"(r) : "v"(x));
  return r;
}
__device__ __forceinline__ float flog2(float x) {
  float r;
  asm("v_log_f32 %0, %1" : "=v"(r) : "v"(x));
  return r;
}
// truncation split: hi = upper 16 bits, residual lo = x - hi (|lo| <= 2^-8|x|)
__device__ __forceinline__ unsigned packhi(float a, float b) {
  return (__float_as_uint(a) >> 16) | (__float_as_uint(b) & 0xFFFF0000u);
}
__device__ __forceinline__ float resid(float a) {
  return a - __uint_as_float(__float_as_uint(a) & 0xFFFF0000u);
}

// ---------------- weight transpose+convert: Wt[n][k] bf16 = W[k][n] ----------
__global__ __launch_bounds__(256) void cvtw_k(const float* __restrict__ W,
                                              unsigned short* __restrict__ Wt) {
  __shared__ float tile[64][65];
  const int t = threadIdx.x;
  const int bx = blockIdx.x & 15, by = blockIdx.x >> 4;
  const int c = t & 63, r4 = t >> 6;
#pragma unroll
  for (int i = 0; i < 16; i++) {
    int r = r4 * 16 + i;
    tile[r][c] = W[(size_t)(by * 64 + r) * DM_ + bx * 64 + c];
  }
  __syncthreads();
#pragma unroll
  for (int i = 0; i < 16; i++) {
    int r = r4 * 16 + i;
    Wt[(size_t)(bx * 64 + r) * DM_ + by * 64 + c] = f2bf(tile[c][r]);
  }
}

// ---------------- weight transpose+SPLIT: Whi/Wlo[n][k] bf16 ----------------
__global__ __launch_bounds__(256) void cvtw2_k(const float* __restrict__ W,
                                               unsigned short* __restrict__ Whi,
                                               unsigned short* __restrict__ Wlo) {
  __shared__ float tile[64][65];
  const int t = threadIdx.x;
  const int bx = blockIdx.x & 15, by = blockIdx.x >> 4;
  const int c = t & 63, r4 = t >> 6;
#pragma unroll
  for (int i = 0; i < 16; i++) {
    int r = r4 * 16 + i;
    tile[r][c] = W[(size_t)(by * 64 + r) * DM_ + bx * 64 + c];
  }
  __syncthreads();
#pragma unroll
  for (int i = 0; i < 16; i++) {
    int r = r4 * 16 + i;
    float v = tile[c][r];
    unsigned short h = f2bf(v);
    float lo = v - bf2f(h);
    size_t o = (size_t)(bx * 64 + r) * DM_ + by * 64 + c;
    Whi[o] = h;
    Wlo[o] = f2bf(lo);
  }
}

// ---------------- rot transpose+SPLIT: Rhi/Rlo[n'][d] bf16 = rot[d][n'] -----
__global__ __launch_bounds__(256) void cvtrot_k(const float* __restrict__ rot,
                                                unsigned short* __restrict__ Rhi,
                                                unsigned short* __restrict__ Rlo) {
  int i = blockIdx.x * 256 + threadIdx.x;  // 64 blocks x 256 = 16384
  float v = rot[i];
  unsigned short h = f2bf(v);
  float lo = v - bf2f(h);
  int d = i >> 7, np = i & 127;
  Rhi[np * 128 + d] = h;
  Rlo[np * 128 + d] = f2bf(lo);
}

// ---------------- Wproj precompute: Wp[h][r][n][k] = sum_d wq[k][h*128+d]*rot[d][r][n]
__global__ __launch_bounds__(256) void wproj_k(const float* __restrict__ W,
                                               const float* __restrict__ rot,
                                               float* __restrict__ Wp,
                                               int* __restrict__ cnt) {
  __shared__ float ws_[8][128];
  __shared__ float rs[128][33];
  const int t = threadIdx.x;
  const int hr = blockIdx.x >> 7;   // 0..31
  const int kc = blockIdx.x & 127;  // k chunk of 8
  const int h = hr >> 2, r = hr & 3;
  if (blockIdx.x == 0 && t == 0) *cnt = 0;
  for (int i = t; i < 4096; i += 256) {
    int d = i >> 5, n = i & 31;
    rs[d][n] = rot[(size_t)d * 128 + r * 32 + n];
  }
  {
    int kk = t >> 5, dd = (t & 31) * 4;
    const float* wr = W + (size_t)(kc * 8 + kk) * DM_ + h * 128 + dd;
    float4 wv = *(const float4*)wr;
    ws_[kk][dd] = wv.x; ws_[kk][dd + 1] = wv.y;
    ws_[kk][dd + 2] = wv.z; ws_[kk][dd + 3] = wv.w;
  }
  __syncthreads();
  const int n = t & 31, kk = t >> 5;
  float s0 = 0.f, s1 = 0.f, s2 = 0.f, s3 = 0.f;
#pragma unroll
  for (int d = 0; d < 128; d += 4) {
    s0 = fmaf(ws_[kk][d], rs[d][n], s0);
    s1 = fmaf(ws_[kk][d + 1], rs[d + 1][n], s1);
    s2 = fmaf(ws_[kk][d + 2], rs[d + 2][n], s2);
    s3 = fmaf(ws_[kk][d + 3], rs[d + 3][n], s3);
  }
  Wp[((size_t)(h * 4 + r) * 32 + n) * 1024 + kc * 8 + kk] = (s0 + s1) + (s2 + s3);
}

// ---------------- split-bf16 MFMA GEMM for q (3-term fp32 emulation) --------
__global__ __launch_bounds__(256) void gemm_qs(const unsigned short* __restrict__ Whi,
                                               const unsigned short* __restrict__ Wlo,
                                               const float* __restrict__ X,
                                               const float* __restrict__ bias,
                                               float* __restrict__ outF) {
  __shared__ __align__(16) unsigned short Ph[128 * 32];
  __shared__ __align__(16) unsigned short Pl[128 * 32];
  __shared__ __align__(16) unsigned short Qh[128 * 32];
  __shared__ __align__(16) unsigned short Ql[128 * 32];
  __shared__ float bias_s[128];
  const int t = threadIdx.x;
  const int bi = blockIdx.x;
  const int pb = (bi & 7) << 7;   // output-dim block (head)
  const int qb = (bi >> 3) << 7;  // token block
  if (t < 128) bias_s[t] = bias[pb + t];
  const int srow = t >> 1, shalf = t & 1;
  const unsigned short* Ph_p = Whi + (size_t)(pb + srow) * DM_ + shalf * 16;
  const unsigned short* Pl_p = Wlo + (size_t)(pb + srow) * DM_ + shalf * 16;
  const float* Xf = X + (size_t)(qb + srow) * DM_ + shalf * 16;
  const int lane = t & 63, wid = t >> 6;
  const int lm = lane & 15, quad = lane >> 4;
  const int prw = (wid & 1) << 6, qcw = (wid >> 1) << 6;
  const int sg = (quad ^ (lm & 3)) << 3;  // swizzled granule offset for frag reads
  f32x4 acc[4][4];
#pragma unroll
  for (int i = 0; i < 4; i++)
#pragma unroll
    for (int j = 0; j < 4; j++) acc[i][j] = (f32x4){0.f, 0.f, 0.f, 0.f};
  uint4 phA, phB, plA, plB, qhA, qhB, qlA, qlB;
  {
    phA = *(const uint4*)(Ph_p);
    phB = *(const uint4*)(Ph_p + 8);
    plA = *(const uint4*)(Pl_p);
    plB = *(const uint4*)(Pl_p + 8);
    float4 f0 = *(const float4*)(Xf), f1 = *(const float4*)(Xf + 4);
    float4 f2 = *(const float4*)(Xf + 8), f3 = *(const float4*)(Xf + 12);
    qhA.x = packhi(f0.x, f0.y); qhA.y = packhi(f0.z, f0.w);
    qhA.z = packhi(f1.x, f1.y); qhA.w = packhi(f1.z, f1.w);
    qhB.x = packhi(f2.x, f2.y); qhB.y = packhi(f2.z, f2.w);
    qhB.z = packhi(f3.x, f3.y); qhB.w = packhi(f3.z, f3.w);
    qlA.x = packbf(resid(f0.x), resid(f0.y)); qlA.y = packbf(resid(f0.z), resid(f0.w));
    qlA.z = packbf(resid(f1.x), resid(f1.y)); qlA.w = packbf(resid(f1.z), resid(f1.w));
    qlB.x = packbf(resid(f2.x), resid(f2.y)); qlB.y = packbf(resid(f2.z), resid(f2.w));
    qlB.z = packbf(resid(f3.x), resid(f3.y)); qlB.w = packbf(resid(f3.z), resid(f3.w));
  }
  const int sw = srow & 3, g0 = shalf * 2;
  const int d0s = srow * 32 + ((g0 ^ sw) << 3);
  const int d1s = srow * 32 + (((g0 + 1) ^ sw) << 3);
  for (int kb = 0; kb < 32; ++kb) {
    __syncthreads();
    *(uint4*)&Ph[d0s] = phA; *(uint4*)&Ph[d1s] = phB;
    *(uint4*)&Pl[d0s] = plA; *(uint4*)&Pl[d1s] = plB;
    *(uint4*)&Qh[d0s] = qhA; *(uint4*)&Qh[d1s] = qhB;
    *(uint4*)&Ql[d0s] = qlA; *(uint4*)&Ql[d1s] = qlB;
    __syncthreads();
    if (kb < 31) {
      int ko = (kb + 1) * 32;
      phA = *(const uint4*)(Ph_p + ko);
      phB = *(const uint4*)(Ph_p + ko + 8);
      plA = *(const uint4*)(Pl_p + ko);
      plB = *(const uint4*)(Pl_p + ko + 8);
      const float* xp = Xf + ko;
      float4 f0 = *(const float4*)(xp), f1 = *(const float4*)(xp + 4);
      float4 f2 = *(const float4*)(xp + 8), f3 = *(const float4*)(xp + 12);
      qhA.x = packhi(f0.x, f0.y); qhA.y = packhi(f0.z, f0.w);
      qhA.z = packhi(f1.x, f1.y); qhA.w = packhi(f1.z, f1.w);
      qhB.x = packhi(f2.x, f2.y); qhB.y = packhi(f2.z, f2.w);
      qhB.z = packhi(f3.x, f3.y); qhB.w = packhi(f3.z, f3.w);
      qlA.x = packbf(resid(f0.x), resid(f0.y)); qlA.y = packbf(resid(f0.z), resid(f0.w));
      qlA.z = packbf(resid(f1.x), resid(f1.y)); qlA.w = packbf(resid(f1.z), resid(f1.w));
      qlB.x = packbf(resid(f2.x), resid(f2.y)); qlB.y = packbf(resid(f2.z), resid(f2.w));
      qlB.z = packbf(resid(f3.x), resid(f3.y)); qlB.w = packbf(resid(f3.z), resid(f3.w));
    }
    short8 ph[4], pl[4], qh[4], ql[4];
#pragma unroll
    for (int ti = 0; ti < 4; ti++) {
      int ro = (prw + ti * 16 + lm) * 32 + sg;
      ph[ti] = *(const short8*)&Ph[ro];
      pl[ti] = *(const short8*)&Pl[ro];
    }
#pragma unroll
    for (int tj = 0; tj < 4; tj++) {
      int ro = (qcw + tj * 16 + lm) * 32 + sg;
      qh[tj] = *(const short8*)&Qh[ro];
      ql[tj] = *(const short8*)&Ql[ro];
    }
#pragma unroll
    for (int ti = 0; ti < 4; ti++)
#pragma unroll
      for (int tj = 0; tj < 4; tj++) {
        f32x4 a = acc[ti][tj];
        a = __builtin_amdgcn_mfma_f32_16x16x32_bf16(ph[ti], qh[tj], a, 0, 0, 0);
        a = __builtin_amdgcn_mfma_f32_16x16x32_bf16(ph[ti], ql[tj], a, 0, 0, 0);
        a = __builtin_amdgcn_mfma_f32_16x16x32_bf16(pl[ti], qh[tj], a, 0, 0, 0);
        acc[ti][tj] = a;
      }
  }
  const int head = bi & 7;
#pragma unroll
  for (int tj = 0; tj < 4; tj++) {
    int mm = qb + qcw + tj * 16 + lm;
    int b = mm >> 12, l = mm & 4095;
    float* op = outF + ((size_t)(b * NH_ + head) * L_ + l) * DK_;
#pragma unroll
    for (int ti = 0; ti < 4; ti++) {
      int d0 = prw + ti * 16 + quad * 4;
      float4 w;
      w.x = acc[ti][tj][0] + bias_s[d0];
      w.y = acc[ti][tj][1] + bias_s[d0 + 1];
      w.z = acc[ti][tj][2] + bias_s[d0 + 2];
      w.w = acc[ti][tj][3] + bias_s[d0 + 3];
      *(float4*)(op + d0) = w;
    }
  }
}

// ---------------- bf16 MFMA GEMM ----------------
template <int MODE>
__global__ __launch_bounds__(256) void gemm_bf(const unsigned short* __restrict__ Pm,
                                               const void* __restrict__ Qv,
                                               const float* __restrict__ bias,
                                               float* __restrict__ outF,
                                               unsigned int* __restrict__ outW) {
  __shared__ __align__(16) unsigned short Ps[128 * 32];
  __shared__ __align__(16) unsigned short Qs[128 * 32];
  __shared__ float bias_s[128];
  const int t = threadIdx.x;
  const int bi = blockIdx.x;
  const int pb = (MODE == 0) ? ((bi >> 3) << 7) : ((bi & 7) << 7);
  const int qb = (MODE == 0) ? ((bi & 7) << 7) : ((bi >> 3) << 7);
  if (t < 128) bias_s[t] = bias[((MODE == 0) ? qb : pb) + t];
  const int srow = t >> 1, shalf = t & 1;
  const unsigned short* Pp = Pm + (size_t)(pb + srow) * DM_ + shalf * 16;
  const float* Qf = (const float*)Qv + (size_t)(qb + srow) * DM_ + shalf * 16;
  const unsigned short* Qh = (const unsigned short*)Qv + (size_t)(qb + srow) * DM_ + shalf * 16;
  const int lane = t & 63, wid = t >> 6;
  const int lm = lane & 15, quad = lane >> 4;
  const int prw = (wid & 1) << 6, qcw = (wid >> 1) << 6;
  f32x4 acc[4][4];
#pragma unroll
  for (int i = 0; i < 4; i++)
#pragma unroll
    for (int j = 0; j < 4; j++) acc[i][j] = (f32x4){0.f, 0.f, 0.f, 0.f};
  uint4 pA, pB, qA, qB;
  {  // preload kb=0
    pA = *(const uint4*)(Pp);
    pB = *(const uint4*)(Pp + 8);
    if (MODE == 2) {
      float4 f0 = *(const float4*)(Qf), f1 = *(const float4*)(Qf + 4);
      float4 f2 = *(const float4*)(Qf + 8), f3 = *(const float4*)(Qf + 12);
      qA.x = packbf(f0.x, f0.y); qA.y = packbf(f0.z, f0.w);
      qA.z = packbf(f1.x, f1.y); qA.w = packbf(f1.z, f1.w);
      qB.x = packbf(f2.x, f2.y); qB.y = packbf(f2.z, f2.w);
      qB.z = packbf(f3.x, f3.y); qB.w = packbf(f3.z, f3.w);
    } else {
      qA = *(const uint4*)(Qh);
      qB = *(const uint4*)(Qh + 8);
    }
  }
  const int sdst = srow * 32 + shalf * 16;
  for (int kb = 0; kb < 32; ++kb) {
    __syncthreads();
    *(uint4*)&Ps[sdst] = pA;
    *(uint4*)&Ps[sdst + 8] = pB;
    *(uint4*)&Qs[sdst] = qA;
    *(uint4*)&Qs[sdst + 8] = qB;
    __syncthreads();
    if (kb < 31) {
      int ko = (kb + 1) * 32;
      pA = *(const uint4*)(Pp + ko);
      pB = *(const uint4*)(Pp + ko + 8);
      if (MODE == 2) {
        const float* qp = Qf + ko;
        float4 f0 = *(const float4*)(qp), f1 = *(const float4*)(qp + 4);
        float4 f2 = *(const float4*)(qp + 8), f3 = *(const float4*)(qp + 12);
        qA.x = packbf(f0.x, f0.y); qA.y = packbf(f0.z, f0.w);
        qA.z = packbf(f1.x, f1.y); qA.w = packbf(f1.z, f1.w);
        qB.x = packbf(f2.x, f2.y); qB.y = packbf(f2.z, f2.w);
        qB.z = packbf(f3.x, f3.y); qB.w = packbf(f3.z, f3.w);
      } else {
        qA = *(const uint4*)(Qh + ko);
        qB = *(const uint4*)(Qh + ko + 8);
      }
    }
    short8 pf[4], qf[4];
#pragma unroll
    for (int ti = 0; ti < 4; ti++)
      pf[ti] = *(const short8*)&Ps[(prw + ti * 16 + lm) * 32 + quad * 8];
#pragma unroll
    for (int tj = 0; tj < 4; tj++)
      qf[tj] = *(const short8*)&Qs[(qcw + tj * 16 + lm) * 32 + quad * 8];
#pragma unroll
    for (int ti = 0; ti < 4; ti++)
#pragma unroll
      for (int tj = 0; tj < 4; tj++)
        acc[ti][tj] = __builtin_amdgcn_mfma_f32_16x16x32_bf16(pf[ti], qf[tj], acc[ti][tj], 0, 0, 0);
  }
  if (MODE == 0) {
#pragma unroll
    for (int ti = 0; ti < 4; ti++) {
      int m = pb + prw + ti * 16 + quad * 4;
#pragma unroll
      for (int tj = 0; tj < 4; tj++) {
        int nn = qcw + tj * 16 + lm;
        float bn = bias_s[nn];
        float* op = outF + (size_t)m * DM_ + qb + nn;
#pragma unroll
        for (int r = 0; r < 4; r++) op[(size_t)r * DM_] = acc[ti][tj][r] + bn;
      }
    }
  } else {
    const int head = bi & 7;
#pragma unroll
    for (int tj = 0; tj < 4; tj++) {
      int mm = qb + qcw + tj * 16 + lm;
      int b = mm >> 12, l = mm & 4095;
#pragma unroll
      for (int ti = 0; ti < 4; ti++) {
        int d0 = prw + ti * 16 + quad * 4;
        uint2 ov;
        ov.x = packbf(acc[ti][tj][0] + bias_s[d0], acc[ti][tj][1] + bias_s[d0 + 1]);
        ov.y = packbf(acc[ti][tj][2] + bias_s[d0 + 2], acc[ti][tj][3] + bias_s[d0 + 3]);
        *(uint2*)(outW + ((size_t)(b * NH_ + head) * L_ + l) * 64 + (d0 >> 1)) = ov;
      }
    }
  }
}

// ---------------- Hash GEMM: proj = qbuf x rotT (split-bf16 MFMA), fused argmax
#define HSTR 132
__global__ __launch_bounds__(256) void hashg_k(const unsigned short* __restrict__ Rhi,
                                               const unsigned short* __restrict__ Rlo,
                                               const float* __restrict__ q,
                                               unsigned char* __restrict__ hout,
                                               int* __restrict__ cnt,
                                               int* __restrict__ flags) {
  __shared__ __align__(16) char smraw[128 * HSTR * 4];
  unsigned short* Ph = (unsigned short*)smraw;
  unsigned short* Pl = Ph + 4096;
  unsigned short* Qh = Ph + 8192;
  unsigned short* Ql = Ph + 12288;
  float* S = (float*)smraw;
  const int t = threadIdx.x;
  const int bi = blockIdx.x;
  const int srow = t >> 1, shalf = t & 1;
  const unsigned short* Php = Rhi + srow * 128 + shalf * 16;
  const unsigned short* Plp = Rlo + srow * 128 + shalf * 16;
  const float* Qf = q + (size_t)(bi * 128 + srow) * DK_ + shalf * 16;
  const int lane = t & 63, wid = t >> 6;
  const int lm = lane & 15, quad = lane >> 4;
  const int prw = (wid & 1) << 6, qcw = (wid >> 1) << 6;
  const int sg = (quad ^ (lm & 3)) << 3;
  f32x4 acc[4][4];
#pragma unroll
  for (int i = 0; i < 4; i++)
#pragma unroll
    for (int j = 0; j < 4; j++) acc[i][j] = (f32x4){0.f, 0.f, 0.f, 0.f};
  const int sw = srow & 3, g0 = shalf * 2;
  const int d0s = srow * 32 + ((g0 ^ sw) << 3);
  const int d1s = srow * 32 + (((g0 + 1) ^ sw) << 3);
  for (int kb = 0; kb < 4; ++kb) {
    const int ko = kb * 32;
    uint4 phA = *(const uint4*)(Php + ko);
    uint4 phB = *(const uint4*)(Php + ko + 8);
    uint4 plA = *(const uint4*)(Plp + ko);
    uint4 plB = *(const uint4*)(Plp + ko + 8);
    const float* xp = Qf + ko;
    float4 f0 = *(const float4*)(xp), f1 = *(const float4*)(xp + 4);
    float4 f2 = *(const float4*)(xp + 8), f3 = *(const float4*)(xp + 12);
    uint4 qhA, qhB, qlA, qlB;
    qhA.x = packhi(f0.x, f0.y); qhA.y = packhi(f0.z, f0.w);
    qhA.z = packhi(f1.x, f1.y); qhA.w = packhi(f1.z, f1.w);
    qhB.x = packhi(f2.x, f2.y); qhB.y = packhi(f2.z, f2.w);
    qhB.z = packhi(f3.x, f3.y); qhB.w = packhi(f3.z, f3.w);
    qlA.x = packbf(resid(f0.x), resid(f0.y)); qlA.y = packbf(resid(f0.z), resid(f0.w));
    qlA.z = packbf(resid(f1.x), resid(f1.y)); qlA.w = packbf(resid(f1.z), resid(f1.w));
    qlB.x = packbf(resid(f2.x), resid(f2.y)); qlB.y = packbf(resid(f2.z), resid(f2.w));
    qlB.z = packbf(resid(f3.x), resid(f3.y)); qlB.w = packbf(resid(f3.z), resid(f3.w));
    __syncthreads();
    *(uint4*)&Ph[d0s] = phA; *(uint4*)&Ph[d1s] = phB;
    *(uint4*)&Pl[d0s] = plA; *(uint4*)&Pl[d1s] = plB;
    *(uint4*)&Qh[d0s] = qhA; *(uint4*)&Qh[d1s] = qhB;
    *(uint4*)&Ql[d0s] = qlA; *(uint4*)&Ql[d1s] = qlB;
    __syncthreads();
    short8 ph[4], pl[4], qh[4], ql[4];
#pragma unroll
    for (int ti = 0; ti < 4; ti++) {
      int ro = (prw + ti * 16 + lm) * 32 + sg;
      ph[ti] = *(const short8*)&Ph[ro];
      pl[ti] = *(const short8*)&Pl[ro];
    }
#pragma unroll
    for (int tj = 0; tj < 4; tj++) {
      int ro = (qcw + tj * 16 + lm) * 32 + sg;
      qh[tj] = *(const short8*)&Qh[ro];
      ql[tj] = *(const short8*)&Ql[ro];
    }
#pragma unroll
    for (int ti = 0; ti < 4; ti++)
#pragma unroll
      for (int tj = 0; tj < 4; tj++) {
        f32x4 a = acc[ti][tj];
        a = __builtin_amdgcn_mfma_f32_16x16x32_bf16(ph[ti], qh[tj], a, 0, 0, 0);
        a = __builtin_amdgcn_mfma_f32_16x16x32_bf16(ph[ti], ql[tj], a, 0, 0, 0);
        a = __builtin_amdgcn_mfma_f32_16x16x32_bf16(pl[ti], qh[tj], a, 0, 0, 0);
        acc[ti][tj] = a;
      }
  }
  __syncthreads();
#pragma unroll
  for (int ti = 0; ti < 4; ti++)
#pragma unroll
    for (int tj = 0; tj < 4; tj++) {
      int nn = qcw + tj * 16 + lm;
#pragma unroll
      for (int r = 0; r < 4; r++)
        S[(prw + ti * 16 + quad * 4 + r) * HSTR + nn] = acc[ti][tj][r];
    }
  __syncthreads();
#pragma unroll
  for (int pp = t; pp < 512; pp += 256) {
    int tok = pp & 127, r = pp >> 7;
    float best = -1.f, second = -1.f;
    int bidx = 0;
#pragma unroll
    for (int n = 0; n < 32; n++) {
      float v = S[(r * 32 + n) * HSTR + tok];
      float av = fabsf(v);
      int idx = (v >= 0.f) ? n : (n + 32);
      if (av > best) {
        second = best; best = av; bidx = idx;
      } else {
        if (av == best && idx < bidx) bidx = idx;
        second = fmaxf(second, av);
      }
    }
    int mm = bi * 128 + tok;
    int bh = mm >> 12, l = mm & 4095;
    hout[((size_t)(bh * NR_ + r)) * L_ + l] = (unsigned char)bidx;
    if (best - second < TAU) {
      int slot = atomicAdd(cnt, 1);
      if (slot < FCAP) flags[slot] = (((bh << 2) | r) << 12) | l;
    }
  }
}

// ---------------- exact f32 recompute of flagged (near-tie) hashes ---------
__global__ __launch_bounds__(256) void fixup_k(const int* __restrict__ cnt,
                                               const int* __restrict__ flags,
                                               const float* __restrict__ X,
                                               const float* __restrict__ Wp,
                                               unsigned char* __restrict__ hout) {
  __shared__ float xs[1024];
  __shared__ float pv[32];
  int nflag = *cnt;
  if (nflag > FCAP) nflag = FCAP;
  const int t = threadIdx.x;
  for (int i = blockIdx.x; i < nflag; i += gridDim.x) {
    int f = flags[i];
    int l = f & 4095, r = (f >> 12) & 3, bh = f >> 14;
    int b = bh >> 3, h = bh & 7;
    __syncthreads();  // protect xs/pv from previous iteration readers
    ((float4*)xs)[t] = ((const float4*)(X + ((size_t)b * L_ + l) * DM_))[t];
    __syncthreads();
    const int nn = t >> 3, kl = t & 7;
    const float* wrow = Wp + ((size_t)(h * 4 + r) * 32 + nn) * 1024 + kl * 4;
    float s = 0.f;
#pragma unroll 8
    for (int k0 = 0; k0 < 1024; k0 += 32) {
      float4 wv = *(const float4*)(wrow + k0);
      float4 xv = *(const float4*)(xs + k0 + kl * 4);
      s = fmaf(wv.x, xv.x, fmaf(wv.y, xv.y, fmaf(wv.z, xv.z, fmaf(wv.w, xv.w, s))));
    }
    s += __shfl_xor(s, 1);
    s += __shfl_xor(s, 2);
    s += __shfl_xor(s, 4);
    if (kl == 0) pv[nn] = s;
    __syncthreads();
    if (t == 0) {
      float bestv = -1.f;
      int besti = 0;
      for (int j = 0; j < 32; j++) {
        float p = pv[j];
        float ap = fabsf(p);
        int idx = (p >= 0.f) ? j : (j + 32);
        if (ap > bestv || (ap == bestv && idx < besti)) { bestv = ap; besti = idx; }
      }
      hout[((size_t)(bh * NR_ + r)) * L_ + l] = (unsigned char)besti;
    }
  }
}

// ---------------- Stable counting sort per (b,h,r) ----------------
__global__ __launch_bounds__(256) void sort_k(const unsigned char* __restrict__ hsh,
                                              int* __restrict__ sidx) {
  __shared__ unsigned char seg[256 * 64];
  __shared__ unsigned short grp[16 * 64];
  __shared__ int offs[64];
  __shared__ int tot[64];
  const int t = threadIdx.x;
  const int bhr = blockIdx.x;
  uint4 hv = ((const uint4*)(hsh + (size_t)bhr * L_))[t];
  unsigned hb[4] = {hv.x, hv.y, hv.z, hv.w};
  unsigned int* seg32 = (unsigned int*)seg;
#pragma unroll
  for (int i = 0; i < 16; i++) seg32[t * 16 + i] = 0;
  ((unsigned int*)grp)[t * 2] = 0;
  ((unsigned int*)grp)[t * 2 + 1] = 0;
  __syncthreads();
#pragma unroll
  for (int k = 0; k < 16; k++) {
    int h = (hb[k >> 2] >> ((k & 3) * 8)) & 0xFF;
    seg[t * 64 + h] = (unsigned char)(seg[t * 64 + h] + 1);
  }
  __syncthreads();
  {
    int h = t & 63;
    for (int g = (t >> 6); g < 16; g += 4) {
      int run = 0;
      for (int s = 0; s < 16; s++) {
        int idx = ((g << 4) + s) * 64 + h;
        int c = seg[idx];
        seg[idx] = (unsigned char)run;
        run += c;
      }
      grp[g * 64 + h] = (unsigned short)run;
    }
  }
  __syncthreads();
  if (t < 64) {
    int run = 0;
    for (int g = 0; g < 16; g++) {
      int c = grp[g * 64 + t];
      grp[g * 64 + t] = (unsigned short)run;
      run += c;
    }
    tot[t] = run;
  }
  __syncthreads();
  if (t == 0) {
    int run = 0;
    for (int h = 0; h < 64; h++) { offs[h] = run; run += tot[h]; }
  }
  __syncthreads();
  const int gbase = (t >> 4) * 64;
  int* outp = sidx + (size_t)bhr * L_;
#pragma unroll
  for (int k = 0; k < 16; k++) {
    int h = (hb[k >> 2] >> ((k & 3) * 8)) & 0xFF;
    int pos = offs[h] + grp[gbase + h] + seg[t * 64 + h];
    seg[t * 64 + h] = (unsigned char)(seg[t * 64 + h] + 1);
    outp[pos] = t * 16 + k;
  }
}

// ---------------- Chunked look-back attention (MFMA, in-register softmax) ----
#define KSTR 136
__global__ __launch_bounds__(256) void attn_k(const float* __restrict__ q,
                                              const unsigned int* __restrict__ vwg,
                                              const int* __restrict__ sidx,
                                              float* __restrict__ lseG,
                                              unsigned int* __restrict__ oW) {
  __shared__ __align__(16) unsigned short R1[128 * KSTR];
  __shared__ __align__(16) unsigned short R2[64 * KSTR];
  __shared__ int idxs[128];
  const int t = threadIdx.x;
  const int c = blockIdx.x & 63;
  const int bhr = blockIdx.x >> 6;
  const int bh = bhr >> 2;
  const int pc = (c + 63) & 63;
  if (t < 128) {
    int sp = (t < 64) ? (pc * 64 + t) : (c * 64 + t - 64);
    idxs[t] = sidx[(size_t)bhr * L_ + sp];
  }
  __syncthreads();
  {
    const int row = t >> 1, half = t & 1;
    const float4* qp = (const float4*)(q + ((size_t)bh * L_ + idxs[row]) * DK_ + half * 64);
    float4 f[16];
    float ss = 0.f;
#pragma unroll
    for (int u = 0; u < 16; u++) {
      f[u] = qp[u];
      ss = fmaf(f[u].x, f[u].x, fmaf(f[u].y, f[u].y, fmaf(f[u].z, f[u].z, fmaf(f[u].w, f[u].w, ss))));
    }
    ss += __shfl_xor(ss, 1);
    float rn = 1.f / (sqrtf(ss) + 1e-9f);
    unsigned short* kr = R1 + row * KSTR + half * 64;
#pragma unroll
    for (int u = 0; u < 8; u++) {
      uint4 w4;
      w4.x = packbf(f[2 * u].x * rn, f[2 * u].y * rn);
      w4.y = packbf(f[2 * u].z * rn, f[2 * u].w * rn);
      w4.z = packbf(f[2 * u + 1].x * rn, f[2 * u + 1].y * rn);
      w4.w = packbf(f[2 * u + 1].z * rn, f[2 * u + 1].w * rn);
      *(uint4*)(kr + u * 8) = w4;
    }
    if (row >= 64) {
      unsigned short* qr = R2 + (row - 64) * KSTR + half * 64;
#pragma unroll
      for (int u = 0; u < 8; u++) {
        uint4 w4;
        w4.x = packbf(f[2 * u].x, f[2 * u].y);
        w4.y = packbf(f[2 * u].z, f[2 * u].w);
        w4.z = packbf(f[2 * u + 1].x, f[2 * u + 1].y);
        w4.w = packbf(f[2 * u + 1].z, f[2 * u + 1].w);
        *(uint4*)(qr + u * 8) = w4;
      }
    }
  }
  __syncthreads();
  const int lane = t & 63, wv = t >> 6;
  const int m0 = wv * 16;
  const int lm = lane & 15, quad = lane >> 4;
  f32x4 acc[8];
  {
    short8 af[4];
#pragma unroll
    for (int ks = 0; ks < 4; ks++)
      af[ks] = *(const short8*)(R2 + (m0 + lm) * KSTR + ks * 32 + quad * 8);
#pragma unroll
    for (int n = 0; n < 8; n++) {
      f32x4 a = {0.f, 0.f, 0.f, 0.f};
#pragma unroll
      for (int ks = 0; ks < 4; ks++) {
        short8 bf = *(const short8*)(R1 + (n * 16 + lm) * KSTR + ks * 32 + quad * 8);
        a = __builtin_amdgcn_mfma_f32_16x16x32_bf16(af[ks], bf, a, 0, 0, 0);
      }
      acc[n] = a;
    }
  }
  // mask+scale in registers
  int qp4[4];
#pragma unroll
  for (int r = 0; r < 4; r++) qp4[r] = idxs[64 + m0 + quad * 4 + r];
#pragma unroll
  for (int n = 0; n < 8; n++) {
    int kp = idxs[n * 16 + lm];
#pragma unroll
    for (int r = 0; r < 4; r++) {
      float s = acc[n][r] * (1.f / SQRTDK);
      acc[n][r] = (kp > qp4[r]) ? NEGV : ((kp == qp4[r]) ? SELFP : s);
    }
  }
  // V global load (hide latency under softmax)
  uint4 vv[8];
  {
    const int key = t >> 1, half = t & 1;
    const uint4* vp = (const uint4*)(vwg + ((size_t)bh * L_ + idxs[key]) * 64 + half * 32);
#pragma unroll
    for (int u = 0; u < 8; u++) vv[u] = vp[u];
  }
  // in-register softmax: rows m0+quad*4+r, keys spread over 8 n-regs x 16 lm-lanes
  float mrow[4], sum4[4], inv4[4];
#pragma unroll
  for (int r = 0; r < 4; r++) {
    float mx = acc[0][r];
#pragma unroll
    for (int n = 1; n < 8; n++) mx = fmaxf(mx, acc[n][r]);
    mx = fmaxf(mx, __shfl_xor(mx, 1));
    mx = fmaxf(mx, __shfl_xor(mx, 2));
    mx = fmaxf(mx, __shfl_xor(mx, 4));
    mx = fmaxf(mx, __shfl_xor(mx, 8));
    mrow[r] = mx;
    sum4[r] = 0.f;
  }
#pragma unroll
  for (int n = 0; n < 8; n++) {
#pragma unroll
    for (int r = 0; r < 4; r++) {
      float e = fexp2((acc[n][r] - mrow[r]) * LOG2E);
      unsigned pk = packbf(e, e);
      R2[(m0 + quad * 4 + r) * KSTR + n * 16 + lm] = (unsigned short)pk;
      sum4[r] += wlo(pk);
    }
  }
#pragma unroll
  for (int r = 0; r < 4; r++) {
    float s = sum4[r];
    s += __shfl_xor(s, 1);
    s += __shfl_xor(s, 2);
    s += __shfl_xor(s, 4);
    s += __shfl_xor(s, 8);
    sum4[r] = s;
    inv4[r] = 1.f / s;
  }
  if (lm == 0) {
#pragma unroll
    for (int r = 0; r < 4; r++)
      lseG[(size_t)bhr * L_ + idxs[64 + m0 + quad * 4 + r]] = mrow[r] + flog2(sum4[r]) * LN2;
  }
  __syncthreads();  // all QK reads of R1 done -> safe to overwrite with V^T
  {
    const int key = t >> 1, half = t & 1;
#pragma unroll
    for (int u = 0; u < 8; u++) {
      unsigned wd[4] = {vv[u].x, vv[u].y, vv[u].z, vv[u].w};
#pragma unroll
      for (int cc = 0; cc < 4; cc++) {
        int w = half * 32 + u * 4 + cc;
        R1[(2 * w) * KSTR + key] = (unsigned short)(wd[cc] & 0xFFFFu);
        R1[(2 * w + 1) * KSTR + key] = (unsigned short)(wd[cc] >> 16);
      }
    }
  }
  __syncthreads();
  f32x4 acc2[8];
  {
    short8 af[4];
#pragma unroll
    for (int ks = 0; ks < 4; ks++)
      af[ks] = *(const short8*)(R2 + (m0 + lm) * KSTR + ks * 32 + quad * 8);
#pragma unroll
    for (int n = 0; n < 8; n++) {
      f32x4 a = {0.f, 0.f, 0.f, 0.f};
#pragma unroll
      for (int ks = 0; ks < 4; ks++) {
        short8 bf = *(const short8*)(R1 + (n * 16 + lm) * KSTR + ks * 32 + quad * 8);
        a = __builtin_amdgcn_mfma_f32_16x16x32_bf16(af[ks], bf, a, 0, 0, 0);
      }
      acc2[n] = a;
    }
  }
#pragma unroll
  for (int n = 0; n < 8; n++) {
#pragma unroll
    for (int r = 0; r < 4; r++) {
      float o = acc2[n][r] * inv4[r];
      R2[(m0 + quad * 4 + r) * KSTR + n * 16 + lm] = (unsigned short)packbf(o, o);
    }
  }
  __syncthreads();
  {
    const int row = t >> 2, seg = t & 3;
    int l = idxs[64 + row];
    unsigned int* op = oW + ((size_t)bhr * L_ + l) * 64 + seg * 16;
    const unsigned short* rp = R2 + row * KSTR + seg * 32;
#pragma unroll
    for (int u = 0; u < 4; u++) *(uint4*)(op + u * 4) = *(const uint4*)(rp + u * 8);
  }
}

// ---------------- Round-softmax merge -> bf16 aout words ----------------
__global__ __launch_bounds__(256) void comb_k(const float* __restrict__ lse,
                                              const unsigned int* __restrict__ oW,
                                              unsigned int* __restrict__ aoutW) {
  size_t g = (size_t)blockIdx.x * 256 + threadIdx.x;
  int w = (int)(g & 63);
  int l = (int)((g >> 6) & 4095);
  int bh = (int)(g >> 18);
  float ls[4];
#pragma unroll
  for (int r = 0; r < 4; r++) ls[r] = lse[((size_t)(bh * 4 + r)) * L_ + l];
  float m = fmaxf(fmaxf(ls[0], ls[1]), fmaxf(ls[2], ls[3]));
  float wsum = 0.f, a0 = 0.f, a1 = 0.f;
#pragma unroll
  for (int r = 0; r < 4; r++) {
    float e = fexp2((ls[r] - m) * LOG2E);
    wsum += e;
    unsigned ow = oW[(((size_t)(bh * 4 + r)) * L_ + l) * 64 + w];
    a0 = fmaf(e, wlo(ow), a0);
    a1 = fmaf(e, whi(ow), a1);
  }
  float inv = 1.f / wsum;
  int b = bh >> 3, h = bh & 7;
  // aout bf16 row-major [m][k] as words: m*512 + h*64 + w
  aoutW[((size_t)b * L_ + l) * 512 + h * 64 + w] = packbf(a0 * inv, a1 * inv);
}

// ---------------- LayerNorm + residual + x2 passthrough ----------------
__global__ __launch_bounds__(256) void ln_k(const float* __restrict__ a,
                                            const float* __restrict__ x1,
                                            const float* __restrict__ x2,
                                            const float* __restrict__ gamma,
                                            const float* __restrict__ beta,
                                            float* __restrict__ out) {
  __shared__ float red[256];
  __shared__ float red2[256];
  const int t = threadIdx.x;
  const size_t row = blockIdx.x;
  float4 av = *(const float4*)(a + row * DM_ + t * 4);
  red[t] = av.x + av.y + av.z + av.w;
  red2[t] = av.x * av.x + av.y * av.y + av.z * av.z + av.w * av.w;
  __syncthreads();
  for (int off = 128; off > 0; off >>= 1) {
    if (t < off) { red[t] += red[t + off]; red2[t] += red2[t + off]; }
    __syncthreads();
  }
  float mu = red[0] * (1.f / 1024.f);
  float var = red2[0] * (1.f / 1024.f) - mu * mu;
  float rstd = rsqrtf(var + 1e-5f);
  float4 g4 = *(const float4*)(gamma + t * 4);
  float4 b4 = *(const float4*)(beta + t * 4);
  float4 x14 = *(const float4*)(x1 + row * DM_ + t * 4);
  float4 o4;
  o4.x = x14.x + (av.x - mu) * rstd * g4.x + b4.x;
  o4.y = x14.y + (av.y - mu) * rstd * g4.y + b4.y;
  o4.z = x14.z + (av.z - mu) * rstd * g4.z + b4.z;
  o4.w = x14.w + (av.w - mu) * rstd * g4.w + b4.w;
  *(float4*)(out + row * DM_ + t * 4) = o4;
  float4 x24 = *(const float4*)(x2 + row * DM_ + t * 4);
  *(float4*)(out + (size_t)B_ * L_ * DM_ + row * DM_ + t * 4) = x24;
}

extern "C" void kernel_launch(void* const* d_in, const int* in_sizes, int n_in,
                              void* d_out, int out_size, void* d_ws, size_t ws_size,
                              hipStream_t stream) {
  const float* x1 = (const float*)d_in[0];
  const float* x2 = (const float*)d_in[1];
  const float* wq = (const float*)d_in[2];
  const float* bq = (const float*)d_in[3];
  const float* wv = (const float*)d_in[4];
  const float* bv = (const float*)d_in[5];
  const float* wo = (const float*)d_in[6];
  const float* bo = (const float*)d_in[7];
  const float* gamma = (const float*)d_in[8];
  const float* beta = (const float*)d_in[9];
  const float* rot = (const float*)d_in[10];

  char* ws = (char*)d_ws;
  float* qbuf = (float*)ws;                                 // 64 MB f32 q (b,h,l,d)
  unsigned int* vbuf = (unsigned int*)(ws + 67108864);      // 32 MB bf16 v (b,h,l,d)
  unsigned char* hbuf = (unsigned char*)(ws + 100663296);   // 512 KB hashes
  int* sbuf = (int*)(ws + 101187584);                       // 2 MB sort_idx
  float* lbuf = (float*)(ws + 103284736);                   // 2 MB lse
  unsigned int* obuf = (unsigned int*)(ws + 105381888);     // 128 MB bf16 o
  float* abuf = (float*)(ws + 105381888);                   // 64 MB f32 (alias obuf head)
  // dead-phase buffers inside obuf range (all consumed before attn_k writes obuf):
  unsigned short* wtqh = (unsigned short*)(ws + 105381888); // 2 MB wq hi bf16 [n][k]
  unsigned short* wtql = (unsigned short*)(ws + 107479040); // 2 MB wq lo bf16 [n][k]
  float* wproj = (float*)(ws + 109576192);                  // 4 MB Wproj [h][r][n][k]
  int* flags = (int*)(ws + 113770496);                      // 2 MB flag list
  int* cntb = (int*)(ws + 115867648);                       // 4 B flag counter
  unsigned short* rthi = (unsigned short*)(ws + 115871744); // 32 KB rotT hi bf16 [n'][d]
  unsigned short* rtlo = (unsigned short*)(ws + 115904512); // 32 KB rotT lo bf16 [n'][d]
  unsigned short* wtv = (unsigned short*)(ws + 172490752);  // 2 MB (obuf tail, dead phase)
  unsigned short* wto = (unsigned short*)(ws + 174587904);  // 2 MB (obuf tail, dead phase)
  unsigned int* aoutW = (unsigned int*)ws;                  // 32 MB bf16 aout (alias qbuf)
  float* out = (float*)d_out;

  dim3 blk(256);
  cvtw2_k<<<dim3(256), blk, 0, stream>>>(wq, wtqh, wtql);
  wproj_k<<<dim3(4096), blk, 0, stream>>>(wq, rot, wproj, cntb);
  cvtrot_k<<<dim3(64), blk, 0, stream>>>(rot, rthi, rtlo);
  gemm_qs<<<dim3(1024), blk, 0, stream>>>(wtqh, wtql, x2, bq, qbuf);
  cvtw_k<<<dim3(256), blk, 0, stream>>>(wv, wtv);
  gemm_bf<2><<<dim3(1024), blk, 0, stream>>>(wtv, (const void*)x2, bv, nullptr, vbuf);
  hashg_k<<<dim3(1024), blk, 0, stream>>>(rthi, rtlo, qbuf, hbuf, cntb, flags);
  fixup_k<<<dim3(1024), blk, 0, stream>>>(cntb, flags, x2, wproj, hbuf);
  sort_k<<<dim3(128), blk, 0, stream>>>(hbuf, sbuf);
  attn_k<<<dim3(8192), blk, 0, stream>>>(qbuf, vbuf, sbuf, lbuf, obuf);
  comb_k<<<dim3(32768), blk, 0, stream>>>(lbuf, obuf, aoutW);
  cvtw_k<<<dim3(256), blk, 0, stream>>>(wo, wto);
  gemm_bf<0><<<dim3(1024), blk, 0, stream>>>((const unsigned short*)aoutW, (const void*)wto,
                                             bo, abuf, nullptr);
  ln_k<<<dim3(16384), blk, 0, stream>>>(abuf, x1, x2, gamma, beta, out);
}

// Round 6
// 746.533 us; speedup vs baseline: 1.7465x; 1.0752x over previous
//
#include <hip/hip_runtime.h>
#include <hip/hip_bf16.h>

#define B_ 4
#define L_ 4096
#define DM_ 1024
#define NH_ 8
#define DK_ 128
#define NR_ 4
#define NC_ 64
#define NEGV -1.0e9f
#define SELFP -1.0e5f
#define SQRTDK 11.313708498984761f
#define TAU 1.0e-3f
#define FCAP 524288
#define LOG2E 1.4426950408889634f
#define LN2 0.6931471805599453f

typedef __attribute__((ext_vector_type(8))) short short8;
typedef __attribute__((ext_vector_type(4))) float f32x4;

// async global->LDS: 16B per lane, LDS dest = uniform base + lane*16
#define GLD(gp, lp)                                                                   \
  __builtin_amdgcn_global_load_lds((const __attribute__((address_space(1))) unsigned  \
                                        int*)(gp),                                    \
                                   (__attribute__((address_space(3))) unsigned int*)( \
                                       lp),                                           \
                                   16, 0, 0)

__device__ __forceinline__ unsigned short f2bf(float x) {
  unsigned u = __float_as_uint(x);
  u += 0x7FFFu + ((u >> 16) & 1u);
  return (unsigned short)(u >> 16);
}
__device__ __forceinline__ float bf2f(unsigned short h) {
  return __uint_as_float(((unsigned)h) << 16);
}
__device__ __forceinline__ float wlo(unsigned w) { return __uint_as_float(w << 16); }
__device__ __forceinline__ float whi(unsigned w) { return __uint_as_float(w & 0xFFFF0000u); }
// HW packed f32->bf16 (RNE, identical to f2bf on finite values): 1 instr.
__device__ __forceinline__ unsigned packbf(float a, float b) {
  unsigned r;
  asm("v_cvt_pk_bf16_f32 %0, %1, %2" : "=v"(r) : "v"(a), "v"(b));
  return r;
}
__device__ __forceinline__ float fexp2(float x) {
  float r;
  asm("v_exp_f32 %0, %1" : "=v"(r) : "v"(x));
  return r;
}
__device__ __forceinline__ float flog2(float x) {
  float r;
  asm("v_log_f32 %0, %1" : "=v"(r) : "v"(x));
  return r;
}
// truncation split (used by hashg's on-the-fly path)
__device__ __forceinline__ unsigned packhi(float a, float b) {
  return (__float_as_uint(a) >> 16) | (__float_as_uint(b) & 0xFFFF0000u);
}
__device__ __forceinline__ float resid(float a) {
  return a - __uint_as_float(__float_as_uint(a) & 0xFFFF0000u);
}

// ---------------- x2 RNE hi/lo bf16 pre-split (once, shared by gemm_qs + gemm_bf<2>)
__global__ __launch_bounds__(256) void xsplit_k(const float* __restrict__ X,
                                                unsigned int* __restrict__ Xhi,
                                                unsigned int* __restrict__ Xlo) {
  size_t i = ((size_t)blockIdx.x * 256 + threadIdx.x) * 2;  // word index (2 floats/word)
  float4 v = *(const float4*)(X + i * 2);
  unsigned h0 = packbf(v.x, v.y), h1 = packbf(v.z, v.w);
  unsigned l0 = packbf(v.x - wlo(h0), v.y - whi(h0));
  unsigned l1 = packbf(v.z - wlo(h1), v.w - whi(h1));
  *(uint2*)(Xhi + i) = make_uint2(h0, h1);
  *(uint2*)(Xlo + i) = make_uint2(l0, l1);
}

// ---------------- weight transpose+convert: Wt[n][k] bf16 = W[k][n] ----------
__global__ __launch_bounds__(256) void cvtw_k(const float* __restrict__ W,
                                              unsigned short* __restrict__ Wt) {
  __shared__ float tile[64][65];
  const int t = threadIdx.x;
  const int bx = blockIdx.x & 15, by = blockIdx.x >> 4;
  const int c = t & 63, r4 = t >> 6;
#pragma unroll
  for (int i = 0; i < 16; i++) {
    int r = r4 * 16 + i;
    tile[r][c] = W[(size_t)(by * 64 + r) * DM_ + bx * 64 + c];
  }
  __syncthreads();
#pragma unroll
  for (int i = 0; i < 16; i++) {
    int r = r4 * 16 + i;
    Wt[(size_t)(bx * 64 + r) * DM_ + by * 64 + c] = f2bf(tile[c][r]);
  }
}

// ---------------- weight transpose+SPLIT: Whi/Wlo[n][k] bf16 ----------------
__global__ __launch_bounds__(256) void cvtw2_k(const float* __restrict__ W,
                                               unsigned short* __restrict__ Whi,
                                               unsigned short* __restrict__ Wlo) {
  __shared__ float tile[64][65];
  const int t = threadIdx.x;
  const int bx = blockIdx.x & 15, by = blockIdx.x >> 4;
  const int c = t & 63, r4 = t >> 6;
#pragma unroll
  for (int i = 0; i < 16; i++) {
    int r = r4 * 16 + i;
    tile[r][c] = W[(size_t)(by * 64 + r) * DM_ + bx * 64 + c];
  }
  __syncthreads();
#pragma unroll
  for (int i = 0; i < 16; i++) {
    int r = r4 * 16 + i;
    float v = tile[c][r];
    unsigned short h = f2bf(v);
    float lo = v - bf2f(h);
    size_t o = (size_t)(bx * 64 + r) * DM_ + by * 64 + c;
    Whi[o] = h;
    Wlo[o] = f2bf(lo);
  }
}

// ---------------- rot transpose+SPLIT: Rhi/Rlo[n'][d] bf16 = rot[d][n'] -----
__global__ __launch_bounds__(256) void cvtrot_k(const float* __restrict__ rot,
                                                unsigned short* __restrict__ Rhi,
                                                unsigned short* __restrict__ Rlo) {
  int i = blockIdx.x * 256 + threadIdx.x;  // 64 blocks x 256 = 16384
  float v = rot[i];
  unsigned short h = f2bf(v);
  float lo = v - bf2f(h);
  int d = i >> 7, np = i & 127;
  Rhi[np * 128 + d] = h;
  Rlo[np * 128 + d] = f2bf(lo);
}

// ---------------- Wproj precompute: Wp[h][r][n][k] = sum_d wq[k][h*128+d]*rot[d][r][n]
__global__ __launch_bounds__(256) void wproj_k(const float* __restrict__ W,
                                               const float* __restrict__ rot,
                                               float* __restrict__ Wp,
                                               int* __restrict__ cnt) {
  __shared__ float ws_[8][128];
  __shared__ float rs[128][33];
  const int t = threadIdx.x;
  const int hr = blockIdx.x >> 7;   // 0..31
  const int kc = blockIdx.x & 127;  // k chunk of 8
  const int h = hr >> 2, r = hr & 3;
  if (blockIdx.x == 0 && t == 0) *cnt = 0;
  for (int i = t; i < 4096; i += 256) {
    int d = i >> 5, n = i & 31;
    rs[d][n] = rot[(size_t)d * 128 + r * 32 + n];
  }
  {
    int kk = t >> 5, dd = (t & 31) * 4;
    const float* wr = W + (size_t)(kc * 8 + kk) * DM_ + h * 128 + dd;
    float4 wv = *(const float4*)wr;
    ws_[kk][dd] = wv.x; ws_[kk][dd + 1] = wv.y;
    ws_[kk][dd + 2] = wv.z; ws_[kk][dd + 3] = wv.w;
  }
  __syncthreads();
  const int n = t & 31, kk = t >> 5;
  float s0 = 0.f, s1 = 0.f, s2 = 0.f, s3 = 0.f;
#pragma unroll
  for (int d = 0; d < 128; d += 4) {
    s0 = fmaf(ws_[kk][d], rs[d][n], s0);
    s1 = fmaf(ws_[kk][d + 1], rs[d + 1][n], s1);
    s2 = fmaf(ws_[kk][d + 2], rs[d + 2][n], s2);
    s3 = fmaf(ws_[kk][d + 3], rs[d + 3][n], s3);
  }
  Wp[((size_t)(h * 4 + r) * 32 + n) * 1024 + kc * 8 + kk] = (s0 + s1) + (s2 + s3);
}

// ---------------- split-bf16 MFMA GEMM for q (3-term fp32 emulation) --------
// All 4 operands pre-split bf16 in global; staged via global_load_lds (m97 structure).
__global__ __launch_bounds__(256) void gemm_qs(const unsigned short* __restrict__ Whi,
                                               const unsigned short* __restrict__ Wlo,
                                               const unsigned short* __restrict__ Xhi,
                                               const unsigned short* __restrict__ Xlo,
                                               const float* __restrict__ bias,
                                               float* __restrict__ outF) {
  __shared__ __align__(16) unsigned short Ph[128 * 32];
  __shared__ __align__(16) unsigned short Pl[128 * 32];
  __shared__ __align__(16) unsigned short Qh[128 * 32];
  __shared__ __align__(16) unsigned short Ql[128 * 32];
  __shared__ float bias_s[128];
  const int t = threadIdx.x;
  const int bi = blockIdx.x;
  const int pb = (bi & 7) << 7;   // output-dim block (head)
  const int qb = (bi >> 3) << 7;  // token block
  if (t < 128) bias_s[t] = bias[pb + t];
  const int lane = t & 63, wid = t >> 6;
  const int lm = lane & 15, quad = lane >> 4;
  const int prw = (wid & 1) << 6, qcw = (wid >> 1) << 6;
  // gload_lds geometry: call j covers rows j*16..j*16+15 (lane: row=j*16+(l>>2), granule=l&3)
  const int jA = wid * 2, jB = jA + 1;
  const int rA = (jA << 4) + (lane >> 2), rB = (jB << 4) + (lane >> 2);
  const int qg = (lane & 3) << 3;
  const unsigned short* phA = Whi + (size_t)(pb + rA) * DM_ + qg;
  const unsigned short* phB = Whi + (size_t)(pb + rB) * DM_ + qg;
  const unsigned short* plA = Wlo + (size_t)(pb + rA) * DM_ + qg;
  const unsigned short* plB = Wlo + (size_t)(pb + rB) * DM_ + qg;
  const unsigned short* qhA = Xhi + (size_t)(qb + rA) * DM_ + qg;
  const unsigned short* qhB = Xhi + (size_t)(qb + rB) * DM_ + qg;
  const unsigned short* qlA = Xlo + (size_t)(qb + rA) * DM_ + qg;
  const unsigned short* qlB = Xlo + (size_t)(qb + rB) * DM_ + qg;
  f32x4 acc[4][4];
#pragma unroll
  for (int i = 0; i < 4; i++)
#pragma unroll
    for (int j = 0; j < 4; j++) acc[i][j] = (f32x4){0.f, 0.f, 0.f, 0.f};
  for (int kb = 0; kb < 32; ++kb) {
    const int ko = kb * 32;
    __syncthreads();  // prev compute done -> safe to overwrite LDS
    GLD(phA + ko, Ph + jA * 512); GLD(phB + ko, Ph + jB * 512);
    GLD(plA + ko, Pl + jA * 512); GLD(plB + ko, Pl + jB * 512);
    GLD(qhA + ko, Qh + jA * 512); GLD(qhB + ko, Qh + jB * 512);
    GLD(qlA + ko, Ql + jA * 512); GLD(qlB + ko, Ql + jB * 512);
    __syncthreads();  // vmcnt(0) drained by barrier -> data ready
    short8 ph[4], pl[4], qh[4], ql[4];
#pragma unroll
    for (int ti = 0; ti < 4; ti++) {
      int ro = (prw + ti * 16 + lm) * 32 + quad * 8;
      ph[ti] = *(const short8*)&Ph[ro];
      pl[ti] = *(const short8*)&Pl[ro];
    }
#pragma unroll
    for (int tj = 0; tj < 4; tj++) {
      int ro = (qcw + tj * 16 + lm) * 32 + quad * 8;
      qh[tj] = *(const short8*)&Qh[ro];
      ql[tj] = *(const short8*)&Ql[ro];
    }
#pragma unroll
    for (int ti = 0; ti < 4; ti++)
#pragma unroll
      for (int tj = 0; tj < 4; tj++) {
        f32x4 a = acc[ti][tj];
        a = __builtin_amdgcn_mfma_f32_16x16x32_bf16(ph[ti], qh[tj], a, 0, 0, 0);
        a = __builtin_amdgcn_mfma_f32_16x16x32_bf16(ph[ti], ql[tj], a, 0, 0, 0);
        a = __builtin_amdgcn_mfma_f32_16x16x32_bf16(pl[ti], qh[tj], a, 0, 0, 0);
        acc[ti][tj] = a;
      }
  }
  const int head = bi & 7;
#pragma unroll
  for (int tj = 0; tj < 4; tj++) {
    int mm = qb + qcw + tj * 16 + lm;
    int b = mm >> 12, l = mm & 4095;
    float* op = outF + ((size_t)(b * NH_ + head) * L_ + l) * DK_;
#pragma unroll
    for (int ti = 0; ti < 4; ti++) {
      int d0 = prw + ti * 16 + quad * 4;
      float4 w;
      w.x = acc[ti][tj][0] + bias_s[d0];
      w.y = acc[ti][tj][1] + bias_s[d0 + 1];
      w.z = acc[ti][tj][2] + bias_s[d0 + 2];
      w.w = acc[ti][tj][3] + bias_s[d0 + 3];
      *(float4*)(op + d0) = w;
    }
  }
}

// ---------------- bf16 MFMA GEMM (both operands bf16 global; gload_lds staging)
// MODE 0: P = aout rows(m), Q = Wt_o rows(n); C[m][n] f32 + bias[n] -> outF
// MODE 2: P = Wt_v rows(n=d of head), Q = Xhi rows(m); C^T -> bf16 (b,h,l,d)
template <int MODE>
__global__ __launch_bounds__(256) void gemm_bf(const unsigned short* __restrict__ Pm,
                                               const unsigned short* __restrict__ Qm,
                                               const float* __restrict__ bias,
                                               float* __restrict__ outF,
                                               unsigned int* __restrict__ outW) {
  __shared__ __align__(16) unsigned short Ps[128 * 32];
  __shared__ __align__(16) unsigned short Qs[128 * 32];
  __shared__ float bias_s[128];
  const int t = threadIdx.x;
  const int bi = blockIdx.x;
  const int pb = (MODE == 0) ? ((bi >> 3) << 7) : ((bi & 7) << 7);
  const int qb = (MODE == 0) ? ((bi & 7) << 7) : ((bi >> 3) << 7);
  if (t < 128) bias_s[t] = bias[((MODE == 0) ? qb : pb) + t];
  const int lane = t & 63, wid = t >> 6;
  const int lm = lane & 15, quad = lane >> 4;
  const int prw = (wid & 1) << 6, qcw = (wid >> 1) << 6;
  const int jA = wid * 2, jB = jA + 1;
  const int rA = (jA << 4) + (lane >> 2), rB = (jB << 4) + (lane >> 2);
  const int qg = (lane & 3) << 3;
  const unsigned short* pA_ = Pm + (size_t)(pb + rA) * DM_ + qg;
  const unsigned short* pB_ = Pm + (size_t)(pb + rB) * DM_ + qg;
  const unsigned short* qA_ = Qm + (size_t)(qb + rA) * DM_ + qg;
  const unsigned short* qB_ = Qm + (size_t)(qb + rB) * DM_ + qg;
  f32x4 acc[4][4];
#pragma unroll
  for (int i = 0; i < 4; i++)
#pragma unroll
    for (int j = 0; j < 4; j++) acc[i][j] = (f32x4){0.f, 0.f, 0.f, 0.f};
  for (int kb = 0; kb < 32; ++kb) {
    const int ko = kb * 32;
    __syncthreads();
    GLD(pA_ + ko, Ps + jA * 512); GLD(pB_ + ko, Ps + jB * 512);
    GLD(qA_ + ko, Qs + jA * 512); GLD(qB_ + ko, Qs + jB * 512);
    __syncthreads();
    short8 pf[4], qf[4];
#pragma unroll
    for (int ti = 0; ti < 4; ti++)
      pf[ti] = *(const short8*)&Ps[(prw + ti * 16 + lm) * 32 + quad * 8];
#pragma unroll
    for (int tj = 0; tj < 4; tj++)
      qf[tj] = *(const short8*)&Qs[(qcw + tj * 16 + lm) * 32 + quad * 8];
#pragma unroll
    for (int ti = 0; ti < 4; ti++)
#pragma unroll
      for (int tj = 0; tj < 4; tj++)
        acc[ti][tj] = __builtin_amdgcn_mfma_f32_16x16x32_bf16(pf[ti], qf[tj], acc[ti][tj], 0, 0, 0);
  }
  if (MODE == 0) {
#pragma unroll
    for (int ti = 0; ti < 4; ti++) {
      int m = pb + prw + ti * 16 + quad * 4;
#pragma unroll
      for (int tj = 0; tj < 4; tj++) {
        int nn = qcw + tj * 16 + lm;
        float bn = bias_s[nn];
        float* op = outF + (size_t)m * DM_ + qb + nn;
#pragma unroll
        for (int r = 0; r < 4; r++) op[(size_t)r * DM_] = acc[ti][tj][r] + bn;
      }
    }
  } else {
    const int head = bi & 7;
#pragma unroll
    for (int tj = 0; tj < 4; tj++) {
      int mm = qb + qcw + tj * 16 + lm;
      int b = mm >> 12, l = mm & 4095;
#pragma unroll
      for (int ti = 0; ti < 4; ti++) {
        int d0 = prw + ti * 16 + quad * 4;
        uint2 ov;
        ov.x = packbf(acc[ti][tj][0] + bias_s[d0], acc[ti][tj][1] + bias_s[d0 + 1]);
        ov.y = packbf(acc[ti][tj][2] + bias_s[d0 + 2], acc[ti][tj][3] + bias_s[d0 + 3]);
        *(uint2*)(outW + ((size_t)(b * NH_ + head) * L_ + l) * 64 + (d0 >> 1)) = ov;
      }
    }
  }
}

// ---------------- Hash GEMM: proj = qbuf x rotT (split-bf16 MFMA), fused argmax
#define HSTR 132
__global__ __launch_bounds__(256) void hashg_k(const unsigned short* __restrict__ Rhi,
                                               const unsigned short* __restrict__ Rlo,
                                               const float* __restrict__ q,
                                               unsigned char* __restrict__ hout,
                                               int* __restrict__ cnt,
                                               int* __restrict__ flags) {
  __shared__ __align__(16) char smraw[128 * HSTR * 4];
  unsigned short* Ph = (unsigned short*)smraw;
  unsigned short* Pl = Ph + 4096;
  unsigned short* Qh = Ph + 8192;
  unsigned short* Ql = Ph + 12288;
  float* S = (float*)smraw;
  const int t = threadIdx.x;
  const int bi = blockIdx.x;
  const int srow = t >> 1, shalf = t & 1;
  const unsigned short* Php = Rhi + srow * 128 + shalf * 16;
  const unsigned short* Plp = Rlo + srow * 128 + shalf * 16;
  const float* Qf = q + (size_t)(bi * 128 + srow) * DK_ + shalf * 16;
  const int lane = t & 63, wid = t >> 6;
  const int lm = lane & 15, quad = lane >> 4;
  const int prw = (wid & 1) << 6, qcw = (wid >> 1) << 6;
  const int sg = (quad ^ (lm & 3)) << 3;
  f32x4 acc[4][4];
#pragma unroll
  for (int i = 0; i < 4; i++)
#pragma unroll
    for (int j = 0; j < 4; j++) acc[i][j] = (f32x4){0.f, 0.f, 0.f, 0.f};
  const int sw = srow & 3, g0 = shalf * 2;
  const int d0s = srow * 32 + ((g0 ^ sw) << 3);
  const int d1s = srow * 32 + (((g0 + 1) ^ sw) << 3);
  for (int kb = 0; kb < 4; ++kb) {
    const int ko = kb * 32;
    uint4 phA = *(const uint4*)(Php + ko);
    uint4 phB = *(const uint4*)(Php + ko + 8);
    uint4 plA = *(const uint4*)(Plp + ko);
    uint4 plB = *(const uint4*)(Plp + ko + 8);
    const float* xp = Qf + ko;
    float4 f0 = *(const float4*)(xp), f1 = *(const float4*)(xp + 4);
    float4 f2 = *(const float4*)(xp + 8), f3 = *(const float4*)(xp + 12);
    uint4 qhA, qhB, qlA, qlB;
    qhA.x = packhi(f0.x, f0.y); qhA.y = packhi(f0.z, f0.w);
    qhA.z = packhi(f1.x, f1.y); qhA.w = packhi(f1.z, f1.w);
    qhB.x = packhi(f2.x, f2.y); qhB.y = packhi(f2.z, f2.w);
    qhB.z = packhi(f3.x, f3.y); qhB.w = packhi(f3.z, f3.w);
    qlA.x = packbf(resid(f0.x), resid(f0.y)); qlA.y = packbf(resid(f0.z), resid(f0.w));
    qlA.z = packbf(resid(f1.x), resid(f1.y)); qlA.w = packbf(resid(f1.z), resid(f1.w));
    qlB.x = packbf(resid(f2.x), resid(f2.y)); qlB.y = packbf(resid(f2.z), resid(f2.w));
    qlB.z = packbf(resid(f3.x), resid(f3.y)); qlB.w = packbf(resid(f3.z), resid(f3.w));
    __syncthreads();
    *(uint4*)&Ph[d0s] = phA; *(uint4*)&Ph[d1s] = phB;
    *(uint4*)&Pl[d0s] = plA; *(uint4*)&Pl[d1s] = plB;
    *(uint4*)&Qh[d0s] = qhA; *(uint4*)&Qh[d1s] = qhB;
    *(uint4*)&Ql[d0s] = qlA; *(uint4*)&Ql[d1s] = qlB;
    __syncthreads();
    short8 ph[4], pl[4], qh[4], ql[4];
#pragma unroll
    for (int ti = 0; ti < 4; ti++) {
      int ro = (prw + ti * 16 + lm) * 32 + sg;
      ph[ti] = *(const short8*)&Ph[ro];
      pl[ti] = *(const short8*)&Pl[ro];
    }
#pragma unroll
    for (int tj = 0; tj < 4; tj++) {
      int ro = (qcw + tj * 16 + lm) * 32 + sg;
      qh[tj] = *(const short8*)&Qh[ro];
      ql[tj] = *(const short8*)&Ql[ro];
    }
#pragma unroll
    for (int ti = 0; ti < 4; ti++)
#pragma unroll
      for (int tj = 0; tj < 4; tj++) {
        f32x4 a = acc[ti][tj];
        a = __builtin_amdgcn_mfma_f32_16x16x32_bf16(ph[ti], qh[tj], a, 0, 0, 0);
        a = __builtin_amdgcn_mfma_f32_16x16x32_bf16(ph[ti], ql[tj], a, 0, 0, 0);
        a = __builtin_amdgcn_mfma_f32_16x16x32_bf16(pl[ti], qh[tj], a, 0, 0, 0);
        acc[ti][tj] = a;
      }
  }
  __syncthreads();
#pragma unroll
  for (int ti = 0; ti < 4; ti++)
#pragma unroll
    for (int tj = 0; tj < 4; tj++) {
      int nn = qcw + tj * 16 + lm;
#pragma unroll
      for (int r = 0; r < 4; r++)
        S[(prw + ti * 16 + quad * 4 + r) * HSTR + nn] = acc[ti][tj][r];
    }
  __syncthreads();
#pragma unroll
  for (int pp = t; pp < 512; pp += 256) {
    int tok = pp & 127, r = pp >> 7;
    float best = -1.f, second = -1.f;
    int bidx = 0;
#pragma unroll
    for (int n = 0; n < 32; n++) {
      float v = S[(r * 32 + n) * HSTR + tok];
      float av = fabsf(v);
      int idx = (v >= 0.f) ? n : (n + 32);
      if (av > best) {
        second = best; best = av; bidx = idx;
      } else {
        if (av == best && idx < bidx) bidx = idx;
        second = fmaxf(second, av);
      }
    }
    int mm = bi * 128 + tok;
    int bh = mm >> 12, l = mm & 4095;
    hout[((size_t)(bh * NR_ + r)) * L_ + l] = (unsigned char)bidx;
    if (best - second < TAU) {
      int slot = atomicAdd(cnt, 1);
      if (slot < FCAP) flags[slot] = (((bh << 2) | r) << 12) | l;
    }
  }
}

// ---------------- exact f32 recompute of flagged (near-tie) hashes ---------
__global__ __launch_bounds__(256) void fixup_k(const int* __restrict__ cnt,
                                               const int* __restrict__ flags,
                                               const float* __restrict__ X,
                                               const float* __restrict__ Wp,
                                               unsigned char* __restrict__ hout) {
  __shared__ float xs[1024];
  __shared__ float pv[32];
  int nflag = *cnt;
  if (nflag > FCAP) nflag = FCAP;
  const int t = threadIdx.x;
  for (int i = blockIdx.x; i < nflag; i += gridDim.x) {
    int f = flags[i];
    int l = f & 4095, r = (f >> 12) & 3, bh = f >> 14;
    int b = bh >> 3, h = bh & 7;
    __syncthreads();  // protect xs/pv from previous iteration readers
    ((float4*)xs)[t] = ((const float4*)(X + ((size_t)b * L_ + l) * DM_))[t];
    __syncthreads();
    const int nn = t >> 3, kl = t & 7;
    const float* wrow = Wp + ((size_t)(h * 4 + r) * 32 + nn) * 1024 + kl * 4;
    float s = 0.f;
#pragma unroll 8
    for (int k0 = 0; k0 < 1024; k0 += 32) {
      float4 wv = *(const float4*)(wrow + k0);
      float4 xv = *(const float4*)(xs + k0 + kl * 4);
      s = fmaf(wv.x, xv.x, fmaf(wv.y, xv.y, fmaf(wv.z, xv.z, fmaf(wv.w, xv.w, s))));
    }
    s += __shfl_xor(s, 1);
    s += __shfl_xor(s, 2);
    s += __shfl_xor(s, 4);
    if (kl == 0) pv[nn] = s;
    __syncthreads();
    if (t == 0) {
      float bestv = -1.f;
      int besti = 0;
      for (int j = 0; j < 32; j++) {
        float p = pv[j];
        float ap = fabsf(p);
        int idx = (p >= 0.f) ? j : (j + 32);
        if (ap > bestv || (ap == bestv && idx < besti)) { bestv = ap; besti = idx; }
      }
      hout[((size_t)(bh * NR_ + r)) * L_ + l] = (unsigned char)besti;
    }
  }
}

// ---------------- Stable counting sort per (b,h,r) ----------------
__global__ __launch_bounds__(256) void sort_k(const unsigned char* __restrict__ hsh,
                                              int* __restrict__ sidx) {
  __shared__ unsigned char seg[256 * 64];
  __shared__ unsigned short grp[16 * 64];
  __shared__ int offs[64];
  __shared__ int tot[64];
  const int t = threadIdx.x;
  const int bhr = blockIdx.x;
  uint4 hv = ((const uint4*)(hsh + (size_t)bhr * L_))[t];
  unsigned hb[4] = {hv.x, hv.y, hv.z, hv.w};
  unsigned int* seg32 = (unsigned int*)seg;
#pragma unroll
  for (int i = 0; i < 16; i++) seg32[t * 16 + i] = 0;
  ((unsigned int*)grp)[t * 2] = 0;
  ((unsigned int*)grp)[t * 2 + 1] = 0;
  __syncthreads();
#pragma unroll
  for (int k = 0; k < 16; k++) {
    int h = (hb[k >> 2] >> ((k & 3) * 8)) & 0xFF;
    seg[t * 64 + h] = (unsigned char)(seg[t * 64 + h] + 1);
  }
  __syncthreads();
  {
    int h = t & 63;
    for (int g = (t >> 6); g < 16; g += 4) {
      int run = 0;
      for (int s = 0; s < 16; s++) {
        int idx = ((g << 4) + s) * 64 + h;
        int c = seg[idx];
        seg[idx] = (unsigned char)run;
        run += c;
      }
      grp[g * 64 + h] = (unsigned short)run;
    }
  }
  __syncthreads();
  if (t < 64) {
    int run = 0;
    for (int g = 0; g < 16; g++) {
      int c = grp[g * 64 + t];
      grp[g * 64 + t] = (unsigned short)run;
      run += c;
    }
    tot[t] = run;
  }
  __syncthreads();
  if (t == 0) {
    int run = 0;
    for (int h = 0; h < 64; h++) { offs[h] = run; run += tot[h]; }
  }
  __syncthreads();
  const int gbase = (t >> 4) * 64;
  int* outp = sidx + (size_t)bhr * L_;
#pragma unroll
  for (int k = 0; k < 16; k++) {
    int h = (hb[k >> 2] >> ((k & 3) * 8)) & 0xFF;
    int pos = offs[h] + grp[gbase + h] + seg[t * 64 + h];
    seg[t * 64 + h] = (unsigned char)(seg[t * 64 + h] + 1);
    outp[pos] = t * 16 + k;
  }
}

// ---------------- Chunked look-back attention (MFMA, in-register softmax) ----
// blockIdx XCD-swizzled: bhr pinned to one XCD so its 3MB q+v slab stays in that L2.
#define KSTR 136
__global__ __launch_bounds__(256) void attn_k(const float* __restrict__ q,
                                              const unsigned int* __restrict__ vwg,
                                              const int* __restrict__ sidx,
                                              float* __restrict__ lseG,
                                              unsigned int* __restrict__ oW) {
  __shared__ __align__(16) unsigned short R1[128 * KSTR];
  __shared__ __align__(16) unsigned short R2[64 * KSTR];
  __shared__ int idxs[128];
  const int t = threadIdx.x;
  const int bid0 = blockIdx.x;
  const int wg = ((bid0 & 7) << 10) | (bid0 >> 3);  // bijective: 8192 = 8 x 1024
  const int c = wg & 63;
  const int bhr = wg >> 6;
  const int bh = bhr >> 2;
  const int pc = (c + 63) & 63;
  if (t < 128) {
    int sp = (t < 64) ? (pc * 64 + t) : (c * 64 + t - 64);
    idxs[t] = sidx[(size_t)bhr * L_ + sp];
  }
  __syncthreads();
  {
    const int row = t >> 1, half = t & 1;
    const float4* qp = (const float4*)(q + ((size_t)bh * L_ + idxs[row]) * DK_ + half * 64);
    float4 f[16];
    float ss = 0.f;
#pragma unroll
    for (int u = 0; u < 16; u++) {
      f[u] = qp[u];
      ss = fmaf(f[u].x, f[u].x, fmaf(f[u].y, f[u].y, fmaf(f[u].z, f[u].z, fmaf(f[u].w, f[u].w, ss))));
    }
    ss += __shfl_xor(ss, 1);
    float rn = 1.f / (sqrtf(ss) + 1e-9f);
    unsigned short* kr = R1 + row * KSTR + half * 64;
#pragma unroll
    for (int u = 0; u < 8; u++) {
      uint4 w4;
      w4.x = packbf(f[2 * u].x * rn, f[2 * u].y * rn);
      w4.y = packbf(f[2 * u].z * rn, f[2 * u].w * rn);
      w4.z = packbf(f[2 * u + 1].x * rn, f[2 * u + 1].y * rn);
      w4.w = packbf(f[2 * u + 1].z * rn, f[2 * u + 1].w * rn);
      *(uint4*)(kr + u * 8) = w4;
    }
    if (row >= 64) {
      unsigned short* qr = R2 + (row - 64) * KSTR + half * 64;
#pragma unroll
      for (int u = 0; u < 8; u++) {
        uint4 w4;
        w4.x = packbf(f[2 * u].x, f[2 * u].y);
        w4.y = packbf(f[2 * u].z, f[2 * u].w);
        w4.z = packbf(f[2 * u + 1].x, f[2 * u + 1].y);
        w4.w = packbf(f[2 * u + 1].z, f[2 * u + 1].w);
        *(uint4*)(qr + u * 8) = w4;
      }
    }
  }
  __syncthreads();
  const int lane = t & 63, wv = t >> 6;
  const int m0 = wv * 16;
  const int lm = lane & 15, quad = lane >> 4;
  f32x4 acc[8];
  {
    short8 af[4];
#pragma unroll
    for (int ks = 0; ks < 4; ks++)
      af[ks] = *(const short8*)(R2 + (m0 + lm) * KSTR + ks * 32 + quad * 8);
#pragma unroll
    for (int n = 0; n < 8; n++) {
      f32x4 a = {0.f, 0.f, 0.f, 0.f};
#pragma unroll
      for (int ks = 0; ks < 4; ks++) {
        short8 bf = *(const short8*)(R1 + (n * 16 + lm) * KSTR + ks * 32 + quad * 8);
        a = __builtin_amdgcn_mfma_f32_16x16x32_bf16(af[ks], bf, a, 0, 0, 0);
      }
      acc[n] = a;
    }
  }
  // mask+scale in registers
  int qp4[4];
#pragma unroll
  for (int r = 0; r < 4; r++) qp4[r] = idxs[64 + m0 + quad * 4 + r];
#pragma unroll
  for (int n = 0; n < 8; n++) {
    int kp = idxs[n * 16 + lm];
#pragma unroll
    for (int r = 0; r < 4; r++) {
      float s = acc[n][r] * (1.f / SQRTDK);
      acc[n][r] = (kp > qp4[r]) ? NEGV : ((kp == qp4[r]) ? SELFP : s);
    }
  }
  // V global load (hide latency under softmax)
  uint4 vv[8];
  {
    const int key = t >> 1, half = t & 1;
    const uint4* vp = (const uint4*)(vwg + ((size_t)bh * L_ + idxs[key]) * 64 + half * 32);
#pragma unroll
    for (int u = 0; u < 8; u++) vv[u] = vp[u];
  }
  // in-register softmax: rows m0+quad*4+r, keys spread over 8 n-regs x 16 lm-lanes
  float mrow[4], sum4[4], inv4[4];
#pragma unroll
  for (int r = 0; r < 4; r++) {
    float mx = acc[0][r];
#pragma unroll
    for (int n = 1; n < 8; n++) mx = fmaxf(mx, acc[n][r]);
    mx = fmaxf(mx, __shfl_xor(mx, 1));
    mx = fmaxf(mx, __shfl_xor(mx, 2));
    mx = fmaxf(mx, __shfl_xor(mx, 4));
    mx = fmaxf(mx, __shfl_xor(mx, 8));
    mrow[r] = mx;
    sum4[r] = 0.f;
  }
#pragma unroll
  for (int n = 0; n < 8; n++) {
#pragma unroll
    for (int r = 0; r < 4; r++) {
      float e = fexp2((acc[n][r] - mrow[r]) * LOG2E);
      unsigned pk = packbf(e, e);
      R2[(m0 + quad * 4 + r) * KSTR + n * 16 + lm] = (unsigned short)pk;
      sum4[r] += wlo(pk);
    }
  }
#pragma unroll
  for (int r = 0; r < 4; r++) {
    float s = sum4[r];
    s += __shfl_xor(s, 1);
    s += __shfl_xor(s, 2);
    s += __shfl_xor(s, 4);
    s += __shfl_xor(s, 8);
    sum4[r] = s;
    inv4[r] = 1.f / s;
  }
  if (lm == 0) {
#pragma unroll
    for (int r = 0; r < 4; r++)
      lseG[(size_t)bhr * L_ + idxs[64 + m0 + quad * 4 + r]] = mrow[r] + flog2(sum4[r]) * LN2;
  }
  __syncthreads();  // all QK reads of R1 done -> safe to overwrite with V^T
  {
    const int key = t >> 1, half = t & 1;
#pragma unroll
    for (int u = 0; u < 8; u++) {
      unsigned wd[4] = {vv[u].x, vv[u].y, vv[u].z, vv[u].w};
#pragma unroll
      for (int cc = 0; cc < 4; cc++) {
        int w = half * 32 + u * 4 + cc;
        R1[(2 * w) * KSTR + key] = (unsigned short)(wd[cc] & 0xFFFFu);
        R1[(2 * w + 1) * KSTR + key] = (unsigned short)(wd[cc] >> 16);
      }
    }
  }
  __syncthreads();
  f32x4 acc2[8];
  {
    short8 af[4];
#pragma unroll
    for (int ks = 0; ks < 4; ks++)
      af[ks] = *(const short8*)(R2 + (m0 + lm) * KSTR + ks * 32 + quad * 8);
#pragma unroll
    for (int n = 0; n < 8; n++) {
      f32x4 a = {0.f, 0.f, 0.f, 0.f};
#pragma unroll
      for (int ks = 0; ks < 4; ks++) {
        short8 bf = *(const short8*)(R1 + (n * 16 + lm) * KSTR + ks * 32 + quad * 8);
        a = __builtin_amdgcn_mfma_f32_16x16x32_bf16(af[ks], bf, a, 0, 0, 0);
      }
      acc2[n] = a;
    }
  }
#pragma unroll
  for (int n = 0; n < 8; n++) {
#pragma unroll
    for (int r = 0; r < 4; r++) {
      float o = acc2[n][r] * inv4[r];
      R2[(m0 + quad * 4 + r) * KSTR + n * 16 + lm] = (unsigned short)packbf(o, o);
    }
  }
  __syncthreads();
  {
    const int row = t >> 2, seg = t & 3;
    int l = idxs[64 + row];
    unsigned int* op = oW + ((size_t)bhr * L_ + l) * 64 + seg * 16;
    const unsigned short* rp = R2 + row * KSTR + seg * 32;
#pragma unroll
    for (int u = 0; u < 4; u++) *(uint4*)(op + u * 4) = *(const uint4*)(rp + u * 8);
  }
}

// ---------------- Round-softmax merge -> bf16 aout words ----------------
__global__ __launch_bounds__(256) void comb_k(const float* __restrict__ lse,
                                              const unsigned int* __restrict__ oW,
                                              unsigned int* __restrict__ aoutW) {
  size_t g = (size_t)blockIdx.x * 256 + threadIdx.x;
  int w = (int)(g & 63);
  int l = (int)((g >> 6) & 4095);
  int bh = (int)(g >> 18);
  float ls[4];
#pragma unroll
  for (int r = 0; r < 4; r++) ls[r] = lse[((size_t)(bh * 4 + r)) * L_ + l];
  float m = fmaxf(fmaxf(ls[0], ls[1]), fmaxf(ls[2], ls[3]));
  float wsum = 0.f, a0 = 0.f, a1 = 0.f;
#pragma unroll
  for (int r = 0; r < 4; r++) {
    float e = fexp2((ls[r] - m) * LOG2E);
    wsum += e;
    unsigned ow = oW[(((size_t)(bh * 4 + r)) * L_ + l) * 64 + w];
    a0 = fmaf(e, wlo(ow), a0);
    a1 = fmaf(e, whi(ow), a1);
  }
  float inv = 1.f / wsum;
  int b = bh >> 3, h = bh & 7;
  // aout bf16 row-major [m][k] as words: m*512 + h*64 + w
  aoutW[((size_t)b * L_ + l) * 512 + h * 64 + w] = packbf(a0 * inv, a1 * inv);
}

// ---------------- LayerNorm + residual + x2 passthrough ----------------
__global__ __launch_bounds__(256) void ln_k(const float* __restrict__ a,
                                            const float* __restrict__ x1,
                                            const float* __restrict__ x2,
                                            const float* __restrict__ gamma,
                                            const float* __restrict__ beta,
                                            float* __restrict__ out) {
  __shared__ float red[256];
  __shared__ float red2[256];
  const int t = threadIdx.x;
  const size_t row = blockIdx.x;
  float4 av = *(const float4*)(a + row * DM_ + t * 4);
  red[t] = av.x + av.y + av.z + av.w;
  red2[t] = av.x * av.x + av.y * av.y + av.z * av.z + av.w * av.w;
  __syncthreads();
  for (int off = 128; off > 0; off >>= 1) {
    if (t < off) { red[t] += red[t + off]; red2[t] += red2[t + off]; }
    __syncthreads();
  }
  float mu = red[0] * (1.f / 1024.f);
  float var = red2[0] * (1.f / 1024.f) - mu * mu;
  float rstd = rsqrtf(var + 1e-5f);
  float4 g4 = *(const float4*)(gamma + t * 4);
  float4 b4 = *(const float4*)(beta + t * 4);
  float4 x14 = *(const float4*)(x1 + row * DM_ + t * 4);
  float4 o4;
  o4.x = x14.x + (av.x - mu) * rstd * g4.x + b4.x;
  o4.y = x14.y + (av.y - mu) * rstd * g4.y + b4.y;
  o4.z = x14.z + (av.z - mu) * rstd * g4.z + b4.z;
  o4.w = x14.w + (av.w - mu) * rstd * g4.w + b4.w;
  *(float4*)(out + row * DM_ + t * 4) = o4;
  float4 x24 = *(const float4*)(x2 + row * DM_ + t * 4);
  *(float4*)(out + (size_t)B_ * L_ * DM_ + row * DM_ + t * 4) = x24;
}

extern "C" void kernel_launch(void* const* d_in, const int* in_sizes, int n_in,
                              void* d_out, int out_size, void* d_ws, size_t ws_size,
                              hipStream_t stream) {
  const float* x1 = (const float*)d_in[0];
  const float* x2 = (const float*)d_in[1];
  const float* wq = (const float*)d_in[2];
  const float* bq = (const float*)d_in[3];
  const float* wv = (const float*)d_in[4];
  const float* bv = (const float*)d_in[5];
  const float* wo = (const float*)d_in[6];
  const float* bo = (const float*)d_in[7];
  const float* gamma = (const float*)d_in[8];
  const float* beta = (const float*)d_in[9];
  const float* rot = (const float*)d_in[10];

  char* ws = (char*)d_ws;
  float* qbuf = (float*)ws;                                 // 64 MB f32 q (b,h,l,d)
  unsigned int* vbuf = (unsigned int*)(ws + 67108864);      // 32 MB bf16 v (b,h,l,d)
  unsigned char* hbuf = (unsigned char*)(ws + 100663296);   // 512 KB hashes
  int* sbuf = (int*)(ws + 101187584);                       // 2 MB sort_idx
  float* lbuf = (float*)(ws + 103284736);                   // 2 MB lse
  unsigned int* obuf = (unsigned int*)(ws + 105381888);     // 128 MB bf16 o
  float* abuf = (float*)(ws + 105381888);                   // 64 MB f32 (alias obuf head)
  // dead-phase buffers inside obuf range (all consumed before attn_k writes obuf):
  unsigned short* wtqh = (unsigned short*)(ws + 105381888); // 2 MB wq hi bf16 [n][k]
  unsigned short* wtql = (unsigned short*)(ws + 107479040); // 2 MB wq lo bf16 [n][k]
  float* wproj = (float*)(ws + 109576192);                  // 4 MB Wproj [h][r][n][k]
  int* flags = (int*)(ws + 113770496);                      // 2 MB flag list
  int* cntb = (int*)(ws + 115867648);                       // 4 B flag counter
  unsigned short* rthi = (unsigned short*)(ws + 115871744); // 32 KB rotT hi bf16 [n'][d]
  unsigned short* rtlo = (unsigned short*)(ws + 115904512); // 32 KB rotT lo bf16 [n'][d]
  unsigned int* xhiW = (unsigned int*)(ws + 117440512);     // 32 MB x2 hi bf16 [m][k]
  unsigned int* xloW = (unsigned int*)(ws + 150994944);     // 32 MB x2 lo bf16 [m][k]
  unsigned short* wtv = (unsigned short*)(ws + 184549376);  // 2 MB (obuf tail, dead phase)
  unsigned short* wto = (unsigned short*)(ws + 186646528);  // 2 MB (obuf tail, post-comb)
  unsigned int* aoutW = (unsigned int*)ws;                  // 32 MB bf16 aout (alias qbuf)
  float* out = (float*)d_out;

  dim3 blk(256);
  xsplit_k<<<dim3(16384), blk, 0, stream>>>(x2, xhiW, xloW);
  cvtw2_k<<<dim3(256), blk, 0, stream>>>(wq, wtqh, wtql);
  wproj_k<<<dim3(4096), blk, 0, stream>>>(wq, rot, wproj, cntb);
  cvtrot_k<<<dim3(64), blk, 0, stream>>>(rot, rthi, rtlo);
  gemm_qs<<<dim3(1024), blk, 0, stream>>>(wtqh, wtql, (const unsigned short*)xhiW,
                                          (const unsigned short*)xloW, bq, qbuf);
  cvtw_k<<<dim3(256), blk, 0, stream>>>(wv, wtv);
  gemm_bf<2><<<dim3(1024), blk, 0, stream>>>(wtv, (const unsigned short*)xhiW, bv,
                                             nullptr, vbuf);
  hashg_k<<<dim3(1024), blk, 0, stream>>>(rthi, rtlo, qbuf, hbuf, cntb, flags);
  fixup_k<<<dim3(1024), blk, 0, stream>>>(cntb, flags, x2, wproj, hbuf);
  sort_k<<<dim3(128), blk, 0, stream>>>(hbuf, sbuf);
  attn_k<<<dim3(8192), blk, 0, stream>>>(qbuf, vbuf, sbuf, lbuf, obuf);
  comb_k<<<dim3(32768), blk, 0, stream>>>(lbuf, obuf, aoutW);
  cvtw_k<<<dim3(256), blk, 0, stream>>>(wo, wto);
  gemm_bf<0><<<dim3(1024), blk, 0, stream>>>((const unsigned short*)aoutW, wto, bo,
                                             abuf, nullptr);
  ln_k<<<dim3(16384), blk, 0, stream>>>(abuf, x1, x2, gamma, beta, out);
}